// Round 5
// baseline (1313.760 us; speedup 1.0000x reference)
//
#include <hip/hip_runtime.h>
#include <hip/hip_cooperative_groups.h>
#include <math.h>

namespace cg = cooperative_groups;

typedef unsigned short u16;
typedef short s16x8 __attribute__((ext_vector_type(8)));
typedef float f32x4 __attribute__((ext_vector_type(4)));

#define MFMA16(a, b, c) __builtin_amdgcn_mfma_f32_16x16x32_bf16((a), (b), (c), 0, 0, 0)

__device__ __forceinline__ u16 f2b(float f) {
  unsigned u = __float_as_uint(f);
  unsigned r = (u + 0x7fff + ((u >> 16) & 1)) >> 16;
  return (u16)r;
}
__device__ __forceinline__ float b2f(u16 h) { return __uint_as_float(((unsigned)h) << 16); }

// ---------------- LayerNorm -> bf16 ----------------
__global__ __launch_bounds__(256) void ln_kernel(const float* __restrict__ x, const float* __restrict__ w,
                          const float* __restrict__ b, u16* __restrict__ xn) {
  int row = blockIdx.x;
  const float* xr = x + (size_t)row * 512;
  int t = threadIdx.x;
  float v0 = xr[t], v1 = xr[t + 256];
  float s = v0 + v1, ss = v0*v0 + v1*v1;
  for (int o = 32; o > 0; o >>= 1) { s += __shfl_down(s, o); ss += __shfl_down(ss, o); }
  __shared__ float ls[4], lss[4];
  int wid = t >> 6, lane = t & 63;
  if (lane == 0) { ls[wid] = s; lss[wid] = ss; }
  __syncthreads();
  float tot  = ls[0]+ls[1]+ls[2]+ls[3];
  float tot2 = lss[0]+lss[1]+lss[2]+lss[3];
  float mean = tot * (1.f/512);
  float var  = tot2 * (1.f/512) - mean*mean;
  float inv = rsqrtf(var + 1e-5f);
  u16* xo = xn + (size_t)row * 512;
  xo[t]     = f2b((v0-mean)*inv*w[t]     + b[t]);
  xo[t+256] = f2b((v1-mean)*inv*w[t+256] + b[t+256]);
}

// ---------------- weight transpose + cast ----------------
__global__ __launch_bounds__(256) void wcast_T(const float* __restrict__ W, u16* __restrict__ WT, int R, int C) {
  int idx = blockIdx.x*256 + threadIdx.x;
  if (idx >= R*C) return;
  int r = idx / C, c = idx - r*C;
  WT[(size_t)c*R + r] = f2b(W[idx]);
}

// ---------------- v transpose ----------------
__global__ __launch_bounds__(256) void vtrans(const u16* __restrict__ v, u16* __restrict__ vT) {
  __shared__ u16 tile[64][72];
  int bh = blockIdx.y, n0 = blockIdx.x * 64;
  int t = threadIdx.x;
  const u16* vb = v + ((size_t)bh*4096 + n0)*64;
  #pragma unroll
  for (int p = 0; p < 2; p++) {
    int c = t + p*256;
    int r = c >> 3, col = (c & 7)*8;
    *(uint4*)&tile[r][col] = *(const uint4*)&vb[(size_t)r*64 + col];
  }
  __syncthreads();
  #pragma unroll
  for (int p = 0; p < 2; p++) {
    int c = t + p*256;
    int d = c >> 3, ncol = (c & 7)*8;
    u16 tmp[8];
    #pragma unroll
    for (int j = 0; j < 8; j++) tmp[j] = tile[ncol + j][d];
    *(uint4*)&vT[((size_t)bh*64 + d)*4096 + n0 + ncol] = *(uint4*)tmp;
  }
}

// ---------------- 128x128 MFMA GEMM core (BK=32, proven) ----------------
__device__ __forceinline__ void gemm128_core(const u16* __restrict__ A, const u16* __restrict__ BT,
    int K, int ldA, int ldBT, int row0, int col0, u16* As, u16* Bs, f32x4 acc[4][4]) {
  int t = threadIdx.x, lane = t & 63, wid = t >> 6;
  int wr = (wid >> 1) * 64, wc = (wid & 1) * 64;
  int lr = lane & 15, lg = lane >> 4;
  for (int k0 = 0; k0 < K; k0 += 32) {
    __syncthreads();
    #pragma unroll
    for (int p = 0; p < 2; p++) {
      int ch = t + p*256;
      int r = ch >> 2, c = (ch & 3) * 8;
      *(uint4*)&As[r*40 + c] = *(const uint4*)&A[(size_t)(row0 + r)*ldA + k0 + c];
      *(uint4*)&Bs[r*40 + c] = *(const uint4*)&BT[(size_t)(col0 + r)*ldBT + k0 + c];
    }
    __syncthreads();
    s16x8 af[4], bf[4];
    #pragma unroll
    for (int f = 0; f < 4; f++) {
      af[f] = *(s16x8*)&As[(wr + f*16 + lr)*40 + lg*8];
      bf[f] = *(s16x8*)&Bs[(wc + f*16 + lr)*40 + lg*8];
    }
    #pragma unroll
    for (int i = 0; i < 4; i++)
      #pragma unroll
      for (int j = 0; j < 4; j++)
        acc[i][j] = MFMA16(af[i], bf[j], acc[i][j]);
  }
}

// ---------------- QKV ----------------
__global__ __launch_bounds__(256) void qkv_mfma(const u16* __restrict__ xn, const u16* __restrict__ wT,
    u16* __restrict__ q, u16* __restrict__ k, u16* __restrict__ v) {
  __shared__ u16 As[128*40], Bs[128*40];
  f32x4 acc[4][4];
  #pragma unroll
  for (int i = 0; i < 4; i++)
    #pragma unroll
    for (int j = 0; j < 4; j++) acc[i][j] = (f32x4)0.f;
  int row0 = blockIdx.y*128, col0 = blockIdx.x*128;
  gemm128_core(xn, wT, 512, 512, 512, row0, col0, As, Bs, acc);
  int t = threadIdx.x, lane = t & 63, wid = t >> 6, lr = lane & 15, lg = lane >> 4;
  int wr = (wid >> 1)*64, wc = (wid & 1)*64;
  #pragma unroll
  for (int i = 0; i < 4; i++)
    #pragma unroll
    for (int j = 0; j < 4; j++)
      #pragma unroll
      for (int r = 0; r < 4; r++) {
        int row = row0 + wr + i*16 + lg*4 + r;
        int col = col0 + wc + j*16 + lr;
        float val = acc[i][j][r];
        int part = col >> 9, rem = col & 511, h = rem >> 6, d = rem & 63;
        int b = row >> 12, n = row & 4095;
        size_t bh = (size_t)(b*8 + h);
        size_t dst = (bh*4096 + n)*64 + d;
        if (part == 0)      q[dst] = f2b(val * 0.125f);
        else if (part == 1) k[dst] = f2b(val);
        else                v[dst] = f2b(val);
      }
}

// ---------------- out GEMM ----------------
__global__ __launch_bounds__(256) void out_mfma(const u16* __restrict__ outh, const u16* __restrict__ wT,
    const float* __restrict__ bo, const float* __restrict__ x, float* __restrict__ out) {
  __shared__ u16 As[128*40], Bs[128*40];
  f32x4 acc[4][4];
  #pragma unroll
  for (int i = 0; i < 4; i++)
    #pragma unroll
    for (int j = 0; j < 4; j++) acc[i][j] = (f32x4)0.f;
  int row0 = blockIdx.y*128, col0 = blockIdx.x*128;
  gemm128_core(outh, wT, 512, 512, 512, row0, col0, As, Bs, acc);
  int t = threadIdx.x, lane = t & 63, wid = t >> 6, lr = lane & 15, lg = lane >> 4;
  int wr = (wid >> 1)*64, wc = (wid & 1)*64;
  #pragma unroll
  for (int i = 0; i < 4; i++)
    #pragma unroll
    for (int j = 0; j < 4; j++)
      #pragma unroll
      for (int r = 0; r < 4; r++) {
        int row = row0 + wr + i*16 + lg*4 + r;
        int col = col0 + wc + j*16 + lr;
        size_t idx = (size_t)row*512 + col;
        out[idx] = x[idx] + acc[i][j][r] + bo[col];
      }
}

// ---------------- landmarks ----------------
__global__ void landmark_kernel(const u16* __restrict__ q, const u16* __restrict__ k,
                                u16* __restrict__ ql, u16* __restrict__ kl) {
  int idx = blockIdx.x;
  int d = threadIdx.x;
  size_t base = ((size_t)idx * 16) * 64 + d;
  float sq = 0.f, sk = 0.f;
  #pragma unroll
  for (int j = 0; j < 16; j++) { sq += b2f(q[base + (size_t)j*64]); sk += b2f(k[base + (size_t)j*64]); }
  ql[(size_t)idx*64 + d] = f2b(sq * (1.f/16.f));
  kl[(size_t)idx*64 + d] = f2b(sk * (1.f/16.f));
}

// ---------------- sim2: MFMA QK^T + exact softmax + colsum-max ----------------
__global__ __launch_bounds__(256) void sim2_mfma(const u16* __restrict__ ql, const u16* __restrict__ kl,
    float* __restrict__ a2, u16* __restrict__ a2h, unsigned* __restrict__ scal) {
  __shared__ u16 Qs[256*72];
  __shared__ u16 Ks2[256*72];
  __shared__ float wcol[4*256];
  __shared__ float red[256];
  int bh = blockIdx.x;
  int t = threadIdx.x, lane = t & 63, wid = t >> 6, lr = lane & 15, lg = lane >> 4;
  #pragma unroll
  for (int p = 0; p < 8; p++) {
    int c = t + p*256;
    int r = c >> 3, col = (c & 7)*8;
    *(uint4*)&Qs[r*72 + col]  = *(const uint4*)&ql[((size_t)bh*256 + r)*64 + col];
    *(uint4*)&Ks2[r*72 + col] = *(const uint4*)&kl[((size_t)bh*256 + r)*64 + col];
  }
  __syncthreads();
  float colp[16];
  #pragma unroll
  for (int cf = 0; cf < 16; cf++) colp[cf] = 0.f;
  for (int rf = 0; rf < 4; rf++) {
    int rbase = wid*64 + rf*16;
    s16x8 a0 = *(s16x8*)&Qs[(rbase + lr)*72 + lg*8];
    s16x8 a1 = *(s16x8*)&Qs[(rbase + lr)*72 + 32 + lg*8];
    f32x4 sf[16];
    #pragma unroll
    for (int cf = 0; cf < 16; cf++) {
      s16x8 b0 = *(s16x8*)&Ks2[(cf*16 + lr)*72 + lg*8];
      s16x8 b1 = *(s16x8*)&Ks2[(cf*16 + lr)*72 + 32 + lg*8];
      sf[cf] = MFMA16(a1, b1, MFMA16(a0, b0, (f32x4)0.f));
    }
    #pragma unroll
    for (int r = 0; r < 4; r++) {
      float mx = -3e38f;
      #pragma unroll
      for (int cf = 0; cf < 16; cf++) mx = fmaxf(mx, sf[cf][r]);
      #pragma unroll
      for (int o = 1; o < 16; o <<= 1) mx = fmaxf(mx, __shfl_xor(mx, o));
      float sum = 0.f;
      #pragma unroll
      for (int cf = 0; cf < 16; cf++) { sf[cf][r] = __expf(sf[cf][r] - mx); sum += sf[cf][r]; }
      #pragma unroll
      for (int o = 1; o < 16; o <<= 1) sum += __shfl_xor(sum, o);
      float inv = 1.f / sum;
      int row = rbase + lg*4 + r;
      size_t base = (size_t)bh*65536 + (size_t)row*256;
      #pragma unroll
      for (int cf = 0; cf < 16; cf++) {
        float pp = sf[cf][r] * inv;
        a2[base + cf*16 + lr] = pp;
        a2h[base + cf*16 + lr] = f2b(pp);
        colp[cf] += pp;
      }
    }
  }
  #pragma unroll
  for (int cf = 0; cf < 16; cf++) {
    colp[cf] += __shfl_xor(colp[cf], 16);
    colp[cf] += __shfl_xor(colp[cf], 32);
  }
  if (lg == 0) {
    #pragma unroll
    for (int cf = 0; cf < 16; cf++) wcol[wid*256 + cf*16 + lr] = colp[cf];
  }
  __syncthreads();
  red[t] = wcol[t] + wcol[256 + t] + wcol[512 + t] + wcol[768 + t];
  __syncthreads();
  for (int o = 128; o > 0; o >>= 1) {
    if (t < o) red[t] = fmaxf(red[t], red[t+o]);
    __syncthreads();
  }
  if (t == 0) atomicMax(scal + 1, __float_as_uint(red[0]));
}

// ---------------- split-K flash partials ----------------
__global__ __launch_bounds__(256) void flash_part(const u16* __restrict__ Q, const u16* __restrict__ Kg,
    const u16* __restrict__ VT, float* __restrict__ po, float* __restrict__ pm, float* __restrict__ pl) {
  __shared__ u16 Ks[64*72];
  __shared__ u16 Vs[64*72];
  __shared__ u16 Ps[4*16*72];
  int qt = blockIdx.x, ch = blockIdx.y, bh = blockIdx.z;
  int q0 = qt * 64;
  int t = threadIdx.x, lane = t & 63, wid = t >> 6, lr = lane & 15, lg = lane >> 4;
  const u16* Qb  = Q  + ((size_t)bh*256)*64;
  const u16* Kb  = Kg + ((size_t)bh*4096 + ch*512)*64;
  const u16* VTb = VT + ((size_t)bh*64)*4096 + ch*512;
  int qrow = q0 + wid*16 + lr;
  s16x8 aq0 = *(const s16x8*)&Qb[(size_t)qrow*64 + lg*8];
  s16x8 aq1 = *(const s16x8*)&Qb[(size_t)qrow*64 + 32 + lg*8];
  f32x4 oacc[4];
  #pragma unroll
  for (int f = 0; f < 4; f++) oacc[f] = (f32x4)0.f;
  float m_[4] = {-3e38f, -3e38f, -3e38f, -3e38f};
  float l_[4] = {0.f, 0.f, 0.f, 0.f};
  u16* Pw = Ps + wid*16*72;
  for (int k0 = 0; k0 < 512; k0 += 64) {
    __syncthreads();
    #pragma unroll
    for (int p = 0; p < 2; p++) {
      int c = t + p*256; int r = c >> 3, cc = (c & 7)*8;
      *(uint4*)&Ks[r*72 + cc] = *(const uint4*)&Kb[(size_t)(k0 + r)*64 + cc];
      *(uint4*)&Vs[r*72 + cc] = *(const uint4*)&VTb[(size_t)r*4096 + k0 + cc];
    }
    __syncthreads();
    f32x4 sf[4];
    #pragma unroll
    for (int f = 0; f < 4; f++) {
      s16x8 b0 = *(s16x8*)&Ks[(f*16 + lr)*72 + lg*8];
      s16x8 b1 = *(s16x8*)&Ks[(f*16 + lr)*72 + 32 + lg*8];
      f32x4 s = (f32x4)0.f;
      s = MFMA16(aq0, b0, s);
      s = MFMA16(aq1, b1, s);
      sf[f] = s;
    }
    #pragma unroll
    for (int r = 0; r < 4; r++) {
      float mx = fmaxf(fmaxf(sf[0][r], sf[1][r]), fmaxf(sf[2][r], sf[3][r]));
      #pragma unroll
      for (int o = 1; o < 16; o <<= 1) mx = fmaxf(mx, __shfl_xor(mx, o));
      float mn = fmaxf(m_[r], mx);
      float sum = 0.f;
      #pragma unroll
      for (int f = 0; f < 4; f++) {
        float pv = __expf(sf[f][r] - mn);
        sum += pv;
        Pw[(lg*4 + r)*72 + f*16 + lr] = f2b(pv);
      }
      #pragma unroll
      for (int o = 1; o < 16; o <<= 1) sum += __shfl_xor(sum, o);
      float sc = __expf(m_[r] - mn);
      l_[r] = l_[r]*sc + sum;
      m_[r] = mn;
      #pragma unroll
      for (int f = 0; f < 4; f++) oacc[f][r] *= sc;
    }
    __syncthreads();
    #pragma unroll
    for (int ks = 0; ks < 2; ks++) {
      s16x8 ap = *(s16x8*)&Pw[lr*72 + ks*32 + lg*8];
      #pragma unroll
      for (int df = 0; df < 4; df++) {
        s16x8 bv = *(s16x8*)&Vs[(df*16 + lr)*72 + ks*32 + lg*8];
        oacc[df] = MFMA16(ap, bv, oacc[df]);
      }
    }
  }
  int pidx = (bh*4 + qt)*8 + ch;
  #pragma unroll
  for (int r = 0; r < 4; r++) {
    int lrow = wid*16 + lg*4 + r;
    if (lr == 0) { pm[pidx*64 + lrow] = m_[r]; pl[pidx*64 + lrow] = l_[r]; }
    #pragma unroll
    for (int df = 0; df < 4; df++)
      po[((size_t)pidx*64 + lrow)*64 + df*16 + lr] = oacc[df][r];
  }
}

// ---------------- merge partials ----------------
__global__ __launch_bounds__(256) void flash_merge(const float* __restrict__ po, const float* __restrict__ pm,
    const float* __restrict__ pl, u16* __restrict__ a3vT) {
  int row = blockIdx.x*4 + (threadIdx.x >> 6);
  int d = threadIdx.x & 63;
  int bh = row >> 8, qrow = row & 255, qt = qrow >> 6, lrow = qrow & 63;
  int pbase = (bh*4 + qt)*8;
  float m = -3e38f;
  #pragma unroll
  for (int ch = 0; ch < 8; ch++) m = fmaxf(m, pm[(pbase+ch)*64 + lrow]);
  float L = 0.f, O = 0.f;
  #pragma unroll
  for (int ch = 0; ch < 8; ch++) {
    float w = __expf(pm[(pbase+ch)*64 + lrow] - m);
    L += w * pl[(pbase+ch)*64 + lrow];
    O += w * po[((size_t)(pbase+ch)*64 + lrow)*64 + d];
  }
  a3vT[((size_t)bh*64 + d)*256 + qrow] = f2b(O / L);
}

// ---------------- cooperative fused pinv: z0 + 6 Newton-Schulz iters + w2 ----------------
// One 128x64x256 tile per block per stage; grid = 256 blocks x 256 threads.
__device__ __forceinline__ void tile_gemm_128x64(
    const u16* __restrict__ Ab, const u16* __restrict__ Bb,
    u16* Cn, u16* CT, u16* CE,
    int row0, int col0, int N, float alpha, float diag,
    u16* As, u16* Bs) {
  int t = threadIdx.x, lane = t & 63, wid = t >> 6, lr = lane & 15, lg = lane >> 4;
  int wr = (wid >> 1)*64, wc = (wid & 1)*32;
  f32x4 acc[4][2];
  #pragma unroll
  for (int i = 0; i < 4; i++)
    #pragma unroll
    for (int j = 0; j < 2; j++) acc[i][j] = (f32x4)0.f;
  for (int k0 = 0; k0 < 256; k0 += 32) {
    __syncthreads();
    #pragma unroll
    for (int p = 0; p < 2; p++) {
      int ch = t + p*256, r = ch >> 2, c = (ch & 3)*8;
      *(uint4*)&As[r*40 + c] = *(const uint4*)&Ab[(size_t)(row0 + r)*256 + k0 + c];
    }
    { int r = t >> 2, c = (t & 3)*8;
      *(uint4*)&Bs[r*40 + c] = *(const uint4*)&Bb[(size_t)(col0 + r)*256 + k0 + c]; }
    __syncthreads();
    s16x8 af[4], bf[2];
    #pragma unroll
    for (int f = 0; f < 4; f++) af[f] = *(s16x8*)&As[(wr + f*16 + lr)*40 + lg*8];
    #pragma unroll
    for (int f = 0; f < 2; f++) bf[f] = *(s16x8*)&Bs[(wc + f*16 + lr)*40 + lg*8];
    #pragma unroll
    for (int i = 0; i < 4; i++)
      #pragma unroll
      for (int j = 0; j < 2; j++)
        acc[i][j] = MFMA16(af[i], bf[j], acc[i][j]);
  }
  #pragma unroll
  for (int i = 0; i < 4; i++)
    #pragma unroll
    for (int j = 0; j < 2; j++)
      #pragma unroll
      for (int r = 0; r < 4; r++) {
        int row = row0 + wr + i*16 + lg*4 + r;
        int col = col0 + wc + j*16 + lr;
        float val = alpha*acc[i][j][r] + (row == col ? diag : 0.f);
        if (Cn) Cn[(size_t)row*N + col] = f2b(val);
        if (CT) CT[(size_t)col*256 + row] = f2b(val);
        if (CE) CE[(size_t)col*256 + row] = f2b((row == col ? 7.f : 0.f) - val);
      }
}

__global__ __launch_bounds__(256) void pinv_coop(
    const float* __restrict__ a2, const u16* __restrict__ a2h, const unsigned* __restrict__ scal,
    u16* zA, u16* zAT, u16* zB, u16* zBT,
    u16* xz, u16* e1T, u16* e2T, u16* e3T,
    const u16* __restrict__ a3vT, u16* __restrict__ w2T) {
  cg::grid_group grid = cg::this_grid();
  __shared__ u16 As[128*40];
  __shared__ u16 Bs[64*40];
  int t = threadIdx.x;
  // stage 0: z0 = a2^T / colmax (rowsum max == 1 for softmax rows)
  {
    float inv = 1.f / __uint_as_float(scal[1]);
    for (int ii = 0; ii < 32; ii++) {
      size_t idx = (size_t)ii*65536 + (size_t)blockIdx.x*256 + t;
      size_t bh = idx >> 16; int rem = (int)(idx & 65535); int i = rem >> 8, j = rem & 255;
      zA[idx]  = f2b(a2[(bh<<16) + ((size_t)j<<8) + i] * inv);
      zAT[idx] = f2b(a2[idx] * inv);
    }
  }
  grid.sync();
  int job = blockIdx.x;
  int batch = job >> 3, rt = (job >> 2) & 1, ct = job & 3;
  size_t bb = (size_t)batch * 65536;
  int row0 = rt*128, col0 = ct*64;
  u16 *zc = zA, *zcT = zAT, *zn = zB, *znT = zBT;
  for (int it = 0; it < 6; it++) {
    // xz = a2 @ z ; e1T = (7I - xz)^T
    tile_gemm_128x64(a2h + bb, zcT + bb, xz + bb, nullptr, e1T + bb, row0, col0, 256, 1.f, 0.f, As, Bs);
    grid.sync();
    // e2T = (15I - xz@e1)^T
    tile_gemm_128x64(xz + bb, e1T + bb, nullptr, e2T + bb, nullptr, row0, col0, 256, -1.f, 15.f, As, Bs);
    grid.sync();
    // e3T = (13I - xz@e2)^T
    tile_gemm_128x64(xz + bb, e2T + bb, nullptr, e3T + bb, nullptr, row0, col0, 256, -1.f, 13.f, As, Bs);
    grid.sync();
    // zn = 0.25 z@e3 (normal + transposed)
    tile_gemm_128x64(zc + bb, e3T + bb, zn + bb, znT + bb, nullptr, row0, col0, 256, 0.25f, 0.f, As, Bs);
    grid.sync();
    u16* tp;
    tp = zc; zc = zn; zn = tp;
    tp = zcT; zcT = znT; znT = tp;
  }
  // final: w2T = (z @ a3v)^T  (M=256, N=64, K=256) — 64 jobs
  if (job < 64) {
    int fb = job >> 1, frt = job & 1;
    tile_gemm_128x64(zc + (size_t)fb*65536, a3vT + (size_t)fb*16384,
                     nullptr, w2T + (size_t)fb*16384, nullptr,
                     frt*128, 0, 64, 1.f, 0.f, As, Bs);
  }
}

// ---------------- exact-softmax flash: outh = softmax(q @ kl^T) @ w2 ----------------
__global__ __launch_bounds__(256) void flash_a1(const u16* __restrict__ Q, const u16* __restrict__ Kl,
    const u16* __restrict__ W2T, u16* __restrict__ outh) {
  __shared__ u16 Ks[64*72];
  __shared__ u16 Vs[64*264];
  __shared__ u16 Ps[4*16*264];
  int bh = blockIdx.y;
  int q0 = blockIdx.x * 64;
  int t = threadIdx.x, lane = t & 63, wid = t >> 6, lr = lane & 15, lg = lane >> 4;
  const u16* Qb = Q + ((size_t)bh*4096)*64;
  #pragma unroll
  for (int p = 0; p < 8; p++) {
    int c = t + p*256; int r = c >> 5, col = (c & 31)*8;
    *(uint4*)&Vs[r*264 + col] = *(const uint4*)&W2T[((size_t)bh*64 + r)*256 + col];
  }
  int qrow = q0 + wid*16 + lr;
  s16x8 aq0 = *(const s16x8*)&Qb[(size_t)qrow*64 + lg*8];
  s16x8 aq1 = *(const s16x8*)&Qb[(size_t)qrow*64 + 32 + lg*8];
  f32x4 sf[16];
  #pragma unroll
  for (int f = 0; f < 16; f++) sf[f] = (f32x4)0.f;
  #pragma unroll
  for (int kt = 0; kt < 4; kt++) {
    __syncthreads();
    #pragma unroll
    for (int p = 0; p < 2; p++) {
      int c = t + p*256; int r = c >> 3, cc = (c & 7)*8;
      *(uint4*)&Ks[r*72 + cc] = *(const uint4*)&Kl[((size_t)bh*256 + kt*64 + r)*64 + cc];
    }
    __syncthreads();
    #pragma unroll
    for (int f2 = 0; f2 < 4; f2++) {
      s16x8 b0 = *(s16x8*)&Ks[(f2*16 + lr)*72 + lg*8];
      s16x8 b1 = *(s16x8*)&Ks[(f2*16 + lr)*72 + 32 + lg*8];
      sf[kt*4 + f2] = MFMA16(aq1, b1, MFMA16(aq0, b0, sf[kt*4 + f2]));
    }
  }
  u16* Pw = Ps + wid*16*264;
  float linv[4];
  #pragma unroll
  for (int r = 0; r < 4; r++) {
    float mx = -3e38f;
    #pragma unroll
    for (int f = 0; f < 16; f++) mx = fmaxf(mx, sf[f][r]);
    #pragma unroll
    for (int o = 1; o < 16; o <<= 1) mx = fmaxf(mx, __shfl_xor(mx, o));
    float sum = 0.f;
    #pragma unroll
    for (int f = 0; f < 16; f++) {
      float pv = __expf(sf[f][r] - mx);
      sum += pv;
      Pw[(lg*4 + r)*264 + f*16 + lr] = f2b(pv);
    }
    #pragma unroll
    for (int o = 1; o < 16; o <<= 1) sum += __shfl_xor(sum, o);
    linv[r] = 1.f / sum;
  }
  f32x4 oacc[4];
  #pragma unroll
  for (int f = 0; f < 4; f++) oacc[f] = (f32x4)0.f;
  #pragma unroll
  for (int ks = 0; ks < 8; ks++) {
    s16x8 ap = *(s16x8*)&Pw[lr*264 + ks*32 + lg*8];
    #pragma unroll
    for (int df = 0; df < 4; df++) {
      s16x8 bv = *(s16x8*)&Vs[(df*16 + lr)*264 + ks*32 + lg*8];
      oacc[df] = MFMA16(ap, bv, oacc[df]);
    }
  }
  int b = bh >> 3, h = bh & 7;
  #pragma unroll
  for (int df = 0; df < 4; df++)
    #pragma unroll
    for (int r = 0; r < 4; r++) {
      int lrow = wid*16 + lg*4 + r;
      int col = df*16 + lr;
      outh[((size_t)(b*4096 + q0 + lrow))*512 + h*64 + col] = f2b(oacc[df][r] * linv[r]);
    }
}

// ---------------- LDS-tiled residual depthwise conv ----------------
__global__ __launch_bounds__(256) void conv_lds(const u16* __restrict__ v, const float* __restrict__ rw,
                                                u16* __restrict__ outh) {
  __shared__ u16 tile[160*72];
  __shared__ float wsm[33];
  int bh = blockIdx.y;
  int n0 = blockIdx.x * 128;
  int b = bh >> 3, h = bh & 7;
  int t = threadIdx.x;
  if (t < 33) wsm[t] = rw[h*33 + t];
  const u16* vb = v + ((size_t)bh*4096)*64;
  #pragma unroll
  for (int p = 0; p < 5; p++) {
    int c = t + p*256;
    int r = c >> 3, col = (c & 7)*8;
    int nn = n0 - 16 + r;
    uint4 val = make_uint4(0u,0u,0u,0u);
    if (nn >= 0 && nn < 4096) val = *(const uint4*)&vb[(size_t)nn*64 + col];
    *(uint4*)&tile[r*72 + col] = val;
  }
  __syncthreads();
  int d8 = (t & 7) * 8;
  int r0 = t >> 3;
  #pragma unroll
  for (int pass = 0; pass < 4; pass++) {
    int lrow = pass*32 + r0;
    float acc[8] = {};
    #pragma unroll
    for (int j = 0; j < 33; j++) {
      uint4 vv = *(uint4*)&tile[(lrow + j)*72 + d8];
      float w = wsm[j];
      acc[0] += b2f((u16)(vv.x & 0xffff)) * w;
      acc[1] += b2f((u16)(vv.x >> 16))    * w;
      acc[2] += b2f((u16)(vv.y & 0xffff)) * w;
      acc[3] += b2f((u16)(vv.y >> 16))    * w;
      acc[4] += b2f((u16)(vv.z & 0xffff)) * w;
      acc[5] += b2f((u16)(vv.z >> 16))    * w;
      acc[6] += b2f((u16)(vv.w & 0xffff)) * w;
      acc[7] += b2f((u16)(vv.w >> 16))    * w;
    }
    size_t oi = ((size_t)(b*4096 + n0 + lrow))*512 + h*64 + d8;
    uint4 ov = *(uint4*)&outh[oi];
    uint4 nv;
    nv.x = (unsigned)f2b(b2f((u16)(ov.x & 0xffff)) + acc[0]) | ((unsigned)f2b(b2f((u16)(ov.x >> 16)) + acc[1]) << 16);
    nv.y = (unsigned)f2b(b2f((u16)(ov.y & 0xffff)) + acc[2]) | ((unsigned)f2b(b2f((u16)(ov.y >> 16)) + acc[3]) << 16);
    nv.z = (unsigned)f2b(b2f((u16)(ov.z & 0xffff)) + acc[4]) | ((unsigned)f2b(b2f((u16)(ov.z >> 16)) + acc[5]) << 16);
    nv.w = (unsigned)f2b(b2f((u16)(ov.w & 0xffff)) + acc[6]) | ((unsigned)f2b(b2f((u16)(ov.w >> 16)) + acc[7]) << 16);
    *(uint4*)&outh[oi] = nv;
  }
}

extern "C" void kernel_launch(void* const* d_in, const int* in_sizes, int n_in,
                              void* d_out, int out_size, void* d_ws, size_t ws_size,
                              hipStream_t stream) {
  const float* x      = (const float*)d_in[0];
  const float* norm_w = (const float*)d_in[1];
  const float* norm_b = (const float*)d_in[2];
  const float* w_qkv  = (const float*)d_in[3];
  const float* w_out  = (const float*)d_in[4];
  const float* b_out  = (const float*)d_in[5];
  const float* res_w  = (const float*)d_in[6];
  float* out = (float*)d_out;
  char* ws = (char*)d_ws;

  size_t off = 0;
  u16* xn    = (u16*)(ws + off); off += 16777216;
  u16* q     = (u16*)(ws + off); off += 16777216;
  u16* k     = (u16*)(ws + off); off += 16777216;
  u16* v     = (u16*)(ws + off); off += 16777216;
  u16* vT    = (u16*)(ws + off); off += 16777216;
  u16* ql    = (u16*)(ws + off); off += 1048576;
  u16* kl    = (u16*)(ws + off); off += 1048576;
  float* a2  = (float*)(ws + off); off += 8388608;
  u16* a2h   = (u16*)(ws + off); off += 4194304;
  u16* zA    = (u16*)(ws + off); off += 4194304;
  u16* zAT   = (u16*)(ws + off); off += 4194304;
  u16* zB    = (u16*)(ws + off); off += 4194304;
  u16* zBT   = (u16*)(ws + off); off += 4194304;
  u16* xz    = (u16*)(ws + off); off += 4194304;
  u16* e1T   = (u16*)(ws + off); off += 4194304;
  u16* e2T   = (u16*)(ws + off); off += 4194304;
  u16* e3T   = (u16*)(ws + off); off += 4194304;
  u16* a3vT  = (u16*)(ws + off); off += 1048576;
  u16* w2T   = (u16*)(ws + off); off += 1048576;
  u16* wqkvT = (u16*)(ws + off); off += 1572864;
  u16* woutT = (u16*)(ws + off); off += 524288;
  u16* outh  = (u16*)(ws + off); off += 16777216;
  float* po  = (float*)(ws + off); off += 16777216;
  float* pm  = (float*)(ws + off); off += 262144;
  float* pl  = (float*)(ws + off); off += 262144;
  unsigned* scal = (unsigned*)(ws + off); off += 8;

  ln_kernel<<<16384, 256, 0, stream>>>(x, norm_w, norm_b, xn);
  wcast_T<<<3072, 256, 0, stream>>>(w_qkv, wqkvT, 512, 1536);
  wcast_T<<<1024, 256, 0, stream>>>(w_out, woutT, 512, 512);
  qkv_mfma<<<dim3(12, 128), 256, 0, stream>>>(xn, wqkvT, q, k, v);
  vtrans<<<dim3(64, 32), 256, 0, stream>>>(v, vT);
  landmark_kernel<<<8192, 64, 0, stream>>>(q, k, ql, kl);
  hipMemsetAsync(scal, 0, 8, stream);
  sim2_mfma<<<32, 256, 0, stream>>>(ql, kl, a2, a2h, scal);
  flash_part<<<dim3(4, 8, 32), 256, 0, stream>>>(ql, k, vT, po, pm, pl);
  flash_merge<<<2048, 256, 0, stream>>>(po, pm, pl, a3vT);

  void* cargs[] = { (void*)&a2, (void*)&a2h, (void*)&scal,
                    (void*)&zA, (void*)&zAT, (void*)&zB, (void*)&zBT,
                    (void*)&xz, (void*)&e1T, (void*)&e2T, (void*)&e3T,
                    (void*)&a3vT, (void*)&w2T };
  hipLaunchCooperativeKernel((const void*)pinv_coop, dim3(256), dim3(256), cargs, 0, stream);

  flash_a1<<<dim3(64, 32), 256, 0, stream>>>(q, kl, w2T, outh);
  conv_lds<<<dim3(32, 32), 256, 0, stream>>>(v, res_w, outh);
  out_mfma<<<dim3(4, 128), 256, 0, stream>>>(outh, woutT, b_out, x, out);
}

// Round 6
// 598.935 us; speedup vs baseline: 2.1935x; 2.1935x over previous
//
#include <hip/hip_runtime.h>
#include <math.h>

typedef unsigned short u16;
typedef short s16x8 __attribute__((ext_vector_type(8)));
typedef float f32x4 __attribute__((ext_vector_type(4)));

#define MFMA16(a, b, c) __builtin_amdgcn_mfma_f32_16x16x32_bf16((a), (b), (c), 0, 0, 0)

__device__ __forceinline__ u16 f2b(float f) {
  unsigned u = __float_as_uint(f);
  unsigned r = (u + 0x7fff + ((u >> 16) & 1)) >> 16;
  return (u16)r;
}
__device__ __forceinline__ float b2f(u16 h) { return __uint_as_float(((unsigned)h) << 16); }

// ---------------- LayerNorm -> bf16 ----------------
__global__ __launch_bounds__(256) void ln_kernel(const float* __restrict__ x, const float* __restrict__ w,
                          const float* __restrict__ b, u16* __restrict__ xn) {
  int row = blockIdx.x;
  const float* xr = x + (size_t)row * 512;
  int t = threadIdx.x;
  float v0 = xr[t], v1 = xr[t + 256];
  float s = v0 + v1, ss = v0*v0 + v1*v1;
  for (int o = 32; o > 0; o >>= 1) { s += __shfl_down(s, o); ss += __shfl_down(ss, o); }
  __shared__ float ls[4], lss[4];
  int wid = t >> 6, lane = t & 63;
  if (lane == 0) { ls[wid] = s; lss[wid] = ss; }
  __syncthreads();
  float tot  = ls[0]+ls[1]+ls[2]+ls[3];
  float tot2 = lss[0]+lss[1]+lss[2]+lss[3];
  float mean = tot * (1.f/512);
  float var  = tot2 * (1.f/512) - mean*mean;
  float inv = rsqrtf(var + 1e-5f);
  u16* xo = xn + (size_t)row * 512;
  xo[t]     = f2b((v0-mean)*inv*w[t]     + b[t]);
  xo[t+256] = f2b((v1-mean)*inv*w[t+256] + b[t+256]);
}

// ---------------- weight transpose + cast ----------------
__global__ __launch_bounds__(256) void wcast_T(const float* __restrict__ W, u16* __restrict__ WT, int R, int C) {
  int idx = blockIdx.x*256 + threadIdx.x;
  if (idx >= R*C) return;
  int r = idx / C, c = idx - r*C;
  WT[(size_t)c*R + r] = f2b(W[idx]);
}

// ---------------- v transpose ----------------
__global__ __launch_bounds__(256) void vtrans(const u16* __restrict__ v, u16* __restrict__ vT) {
  __shared__ u16 tile[64][72];
  int bh = blockIdx.y, n0 = blockIdx.x * 64;
  int t = threadIdx.x;
  const u16* vb = v + ((size_t)bh*4096 + n0)*64;
  #pragma unroll
  for (int p = 0; p < 2; p++) {
    int c = t + p*256;
    int r = c >> 3, col = (c & 7)*8;
    *(uint4*)&tile[r][col] = *(const uint4*)&vb[(size_t)r*64 + col];
  }
  __syncthreads();
  #pragma unroll
  for (int p = 0; p < 2; p++) {
    int c = t + p*256;
    int d = c >> 3, ncol = (c & 7)*8;
    u16 tmp[8];
    #pragma unroll
    for (int j = 0; j < 8; j++) tmp[j] = tile[ncol + j][d];
    *(uint4*)&vT[((size_t)bh*64 + d)*4096 + n0 + ncol] = *(uint4*)tmp;
  }
}

// ---------------- 128x128 MFMA GEMM core (BK=32, proven) ----------------
__device__ __forceinline__ void gemm128_core(const u16* __restrict__ A, const u16* __restrict__ BT,
    int K, int ldA, int ldBT, int row0, int col0, u16* As, u16* Bs, f32x4 acc[4][4]) {
  int t = threadIdx.x, lane = t & 63, wid = t >> 6;
  int wr = (wid >> 1) * 64, wc = (wid & 1) * 64;
  int lr = lane & 15, lg = lane >> 4;
  for (int k0 = 0; k0 < K; k0 += 32) {
    __syncthreads();
    #pragma unroll
    for (int p = 0; p < 2; p++) {
      int ch = t + p*256;
      int r = ch >> 2, c = (ch & 3) * 8;
      *(uint4*)&As[r*40 + c] = *(const uint4*)&A[(size_t)(row0 + r)*ldA + k0 + c];
      *(uint4*)&Bs[r*40 + c] = *(const uint4*)&BT[(size_t)(col0 + r)*ldBT + k0 + c];
    }
    __syncthreads();
    s16x8 af[4], bf[4];
    #pragma unroll
    for (int f = 0; f < 4; f++) {
      af[f] = *(s16x8*)&As[(wr + f*16 + lr)*40 + lg*8];
      bf[f] = *(s16x8*)&Bs[(wc + f*16 + lr)*40 + lg*8];
    }
    #pragma unroll
    for (int i = 0; i < 4; i++)
      #pragma unroll
      for (int j = 0; j < 4; j++)
        acc[i][j] = MFMA16(af[i], bf[j], acc[i][j]);
  }
}

// ---------------- QKV ----------------
__global__ __launch_bounds__(256) void qkv_mfma(const u16* __restrict__ xn, const u16* __restrict__ wT,
    u16* __restrict__ q, u16* __restrict__ k, u16* __restrict__ v) {
  __shared__ u16 As[128*40], Bs[128*40];
  f32x4 acc[4][4];
  #pragma unroll
  for (int i = 0; i < 4; i++)
    #pragma unroll
    for (int j = 0; j < 4; j++) acc[i][j] = (f32x4)0.f;
  int row0 = blockIdx.y*128, col0 = blockIdx.x*128;
  gemm128_core(xn, wT, 512, 512, 512, row0, col0, As, Bs, acc);
  int t = threadIdx.x, lane = t & 63, wid = t >> 6, lr = lane & 15, lg = lane >> 4;
  int wr = (wid >> 1)*64, wc = (wid & 1)*64;
  #pragma unroll
  for (int i = 0; i < 4; i++)
    #pragma unroll
    for (int j = 0; j < 4; j++)
      #pragma unroll
      for (int r = 0; r < 4; r++) {
        int row = row0 + wr + i*16 + lg*4 + r;
        int col = col0 + wc + j*16 + lr;
        float val = acc[i][j][r];
        int part = col >> 9, rem = col & 511, h = rem >> 6, d = rem & 63;
        int b = row >> 12, n = row & 4095;
        size_t bh = (size_t)(b*8 + h);
        size_t dst = (bh*4096 + n)*64 + d;
        if (part == 0)      q[dst] = f2b(val * 0.125f);
        else if (part == 1) k[dst] = f2b(val);
        else                v[dst] = f2b(val);
      }
}

// ---------------- out GEMM ----------------
__global__ __launch_bounds__(256) void out_mfma(const u16* __restrict__ outh, const u16* __restrict__ wT,
    const float* __restrict__ bo, const float* __restrict__ x, float* __restrict__ out) {
  __shared__ u16 As[128*40], Bs[128*40];
  f32x4 acc[4][4];
  #pragma unroll
  for (int i = 0; i < 4; i++)
    #pragma unroll
    for (int j = 0; j < 4; j++) acc[i][j] = (f32x4)0.f;
  int row0 = blockIdx.y*128, col0 = blockIdx.x*128;
  gemm128_core(outh, wT, 512, 512, 512, row0, col0, As, Bs, acc);
  int t = threadIdx.x, lane = t & 63, wid = t >> 6, lr = lane & 15, lg = lane >> 4;
  int wr = (wid >> 1)*64, wc = (wid & 1)*64;
  #pragma unroll
  for (int i = 0; i < 4; i++)
    #pragma unroll
    for (int j = 0; j < 4; j++)
      #pragma unroll
      for (int r = 0; r < 4; r++) {
        int row = row0 + wr + i*16 + lg*4 + r;
        int col = col0 + wc + j*16 + lr;
        size_t idx = (size_t)row*512 + col;
        out[idx] = x[idx] + acc[i][j][r] + bo[col];
      }
}

// ---------------- batched 128x128-tile MFMA GEMM for pinv chain (M=N=K=256) ----------------
__global__ __launch_bounds__(256) void bmm128(const u16* __restrict__ A, const u16* __restrict__ BT,
    u16* __restrict__ Cn, u16* __restrict__ CT, u16* __restrict__ CE,
    float alpha, float diag) {
  __shared__ u16 As[128*40], Bs[128*40];
  size_t bb = (size_t)blockIdx.z * 65536;
  f32x4 acc[4][4];
  #pragma unroll
  for (int i = 0; i < 4; i++)
    #pragma unroll
    for (int j = 0; j < 4; j++) acc[i][j] = (f32x4)0.f;
  int row0 = blockIdx.y*128, col0 = blockIdx.x*128;
  gemm128_core(A + bb, BT + bb, 256, 256, 256, row0, col0, As, Bs, acc);
  int t = threadIdx.x, lane = t & 63, wid = t >> 6, lr = lane & 15, lg = lane >> 4;
  int wr = (wid >> 1)*64, wc = (wid & 1)*64;
  #pragma unroll
  for (int i = 0; i < 4; i++)
    #pragma unroll
    for (int j = 0; j < 4; j++)
      #pragma unroll
      for (int r = 0; r < 4; r++) {
        int row = row0 + wr + i*16 + lg*4 + r;
        int col = col0 + wc + j*16 + lr;
        float val = alpha*acc[i][j][r] + (row == col ? diag : 0.f);
        if (Cn) Cn[bb + (size_t)row*256 + col] = f2b(val);
        if (CT) CT[bb + (size_t)col*256 + row] = f2b(val);
        if (CE) CE[bb + (size_t)col*256 + row] = f2b((row == col ? 7.f : 0.f) - val);
      }
}

// ---------------- batched 64x64-tile MFMA GEMM (final w2T) ----------------
__global__ __launch_bounds__(256) void bmm64(const u16* __restrict__ A, const u16* __restrict__ BT,
    u16* __restrict__ Cn, u16* __restrict__ CT, u16* __restrict__ CE,
    int M, int N, int K, float alpha, float diag) {
  __shared__ u16 As[64*40], Bs[64*40];
  int batch = blockIdx.z;
  const u16* Ab = A  + (size_t)batch*M*K;
  const u16* Bb = BT + (size_t)batch*N*K;
  int row0 = blockIdx.y*64, col0 = blockIdx.x*64;
  int t = threadIdx.x, lane = t & 63, wid = t >> 6, lr = lane & 15, lg = lane >> 4;
  int wr = (wid >> 1)*32, wc = (wid & 1)*32;
  f32x4 acc[2][2];
  #pragma unroll
  for (int i = 0; i < 2; i++)
    #pragma unroll
    for (int j = 0; j < 2; j++) acc[i][j] = (f32x4)0.f;
  for (int k0 = 0; k0 < K; k0 += 32) {
    __syncthreads();
    int r = t >> 2, c = (t & 3)*8;
    *(uint4*)&As[r*40 + c] = *(const uint4*)&Ab[(size_t)(row0 + r)*K + k0 + c];
    *(uint4*)&Bs[r*40 + c] = *(const uint4*)&Bb[(size_t)(col0 + r)*K + k0 + c];
    __syncthreads();
    s16x8 af[2], bf[2];
    #pragma unroll
    for (int f = 0; f < 2; f++) {
      af[f] = *(s16x8*)&As[(wr + f*16 + lr)*40 + lg*8];
      bf[f] = *(s16x8*)&Bs[(wc + f*16 + lr)*40 + lg*8];
    }
    #pragma unroll
    for (int i = 0; i < 2; i++)
      #pragma unroll
      for (int j = 0; j < 2; j++)
        acc[i][j] = MFMA16(af[i], bf[j], acc[i][j]);
  }
  size_t cb = (size_t)batch*M*N;
  #pragma unroll
  for (int i = 0; i < 2; i++)
    #pragma unroll
    for (int j = 0; j < 2; j++)
      #pragma unroll
      for (int r = 0; r < 4; r++) {
        int row = row0 + wr + i*16 + lg*4 + r;
        int col = col0 + wc + j*16 + lr;
        float val = alpha*acc[i][j][r] + (row == col ? diag : 0.f);
        if (Cn) Cn[cb + (size_t)row*N + col] = f2b(val);
        if (CT) CT[cb + (size_t)col*M + row] = f2b(val);
        if (CE) CE[cb + (size_t)col*M + row] = f2b((row == col ? 7.f : 0.f) - val);
      }
}

// ---------------- landmarks ----------------
__global__ void landmark_kernel(const u16* __restrict__ q, const u16* __restrict__ k,
                                u16* __restrict__ ql, u16* __restrict__ kl) {
  int idx = blockIdx.x;
  int d = threadIdx.x;
  size_t base = ((size_t)idx * 16) * 64 + d;
  float sq = 0.f, sk = 0.f;
  #pragma unroll
  for (int j = 0; j < 16; j++) { sq += b2f(q[base + (size_t)j*64]); sk += b2f(k[base + (size_t)j*64]); }
  ql[(size_t)idx*64 + d] = f2b(sq * (1.f/16.f));
  kl[(size_t)idx*64 + d] = f2b(sk * (1.f/16.f));
}

// ---------------- sim2: MFMA QK^T + exact softmax + colsum-max ----------------
__global__ __launch_bounds__(256) void sim2_mfma(const u16* __restrict__ ql, const u16* __restrict__ kl,
    float* __restrict__ a2, u16* __restrict__ a2h, unsigned* __restrict__ scal) {
  __shared__ u16 Qs[256*72];
  __shared__ u16 Ks2[256*72];
  __shared__ float wcol[4*256];
  __shared__ float red[256];
  int bh = blockIdx.x;
  int t = threadIdx.x, lane = t & 63, wid = t >> 6, lr = lane & 15, lg = lane >> 4;
  #pragma unroll
  for (int p = 0; p < 8; p++) {
    int c = t + p*256;
    int r = c >> 3, col = (c & 7)*8;
    *(uint4*)&Qs[r*72 + col]  = *(const uint4*)&ql[((size_t)bh*256 + r)*64 + col];
    *(uint4*)&Ks2[r*72 + col] = *(const uint4*)&kl[((size_t)bh*256 + r)*64 + col];
  }
  __syncthreads();
  float colp[16];
  #pragma unroll
  for (int cf = 0; cf < 16; cf++) colp[cf] = 0.f;
  for (int rf = 0; rf < 4; rf++) {
    int rbase = wid*64 + rf*16;
    s16x8 a0 = *(s16x8*)&Qs[(rbase + lr)*72 + lg*8];
    s16x8 a1 = *(s16x8*)&Qs[(rbase + lr)*72 + 32 + lg*8];
    f32x4 sf[16];
    #pragma unroll
    for (int cf = 0; cf < 16; cf++) {
      s16x8 b0 = *(s16x8*)&Ks2[(cf*16 + lr)*72 + lg*8];
      s16x8 b1 = *(s16x8*)&Ks2[(cf*16 + lr)*72 + 32 + lg*8];
      sf[cf] = MFMA16(a1, b1, MFMA16(a0, b0, (f32x4)0.f));
    }
    #pragma unroll
    for (int r = 0; r < 4; r++) {
      float mx = -3e38f;
      #pragma unroll
      for (int cf = 0; cf < 16; cf++) mx = fmaxf(mx, sf[cf][r]);
      #pragma unroll
      for (int o = 1; o < 16; o <<= 1) mx = fmaxf(mx, __shfl_xor(mx, o));
      float sum = 0.f;
      #pragma unroll
      for (int cf = 0; cf < 16; cf++) { sf[cf][r] = __expf(sf[cf][r] - mx); sum += sf[cf][r]; }
      #pragma unroll
      for (int o = 1; o < 16; o <<= 1) sum += __shfl_xor(sum, o);
      float inv = 1.f / sum;
      int row = rbase + lg*4 + r;
      size_t base = (size_t)bh*65536 + (size_t)row*256;
      #pragma unroll
      for (int cf = 0; cf < 16; cf++) {
        float pp = sf[cf][r] * inv;
        a2[base + cf*16 + lr] = pp;
        a2h[base + cf*16 + lr] = f2b(pp);
        colp[cf] += pp;
      }
    }
  }
  #pragma unroll
  for (int cf = 0; cf < 16; cf++) {
    colp[cf] += __shfl_xor(colp[cf], 16);
    colp[cf] += __shfl_xor(colp[cf], 32);
  }
  if (lg == 0) {
    #pragma unroll
    for (int cf = 0; cf < 16; cf++) wcol[wid*256 + cf*16 + lr] = colp[cf];
  }
  __syncthreads();
  red[t] = wcol[t] + wcol[256 + t] + wcol[512 + t] + wcol[768 + t];
  __syncthreads();
  for (int o = 128; o > 0; o >>= 1) {
    if (t < o) red[t] = fmaxf(red[t], red[t+o]);
    __syncthreads();
  }
  if (t == 0) atomicMax(scal + 1, __float_as_uint(red[0]));
}

// ---------------- z0 = a2^T / colmax ----------------
__global__ void z0_kernel(const float* __restrict__ a2, const unsigned* __restrict__ scal,
                          u16* __restrict__ zA, u16* __restrict__ zAT) {
  size_t idx = (size_t)blockIdx.x*256 + threadIdx.x;
  float inv = 1.f / __uint_as_float(scal[1]);
  size_t bh = idx >> 16; int rem = (int)(idx & 65535); int i = rem >> 8, j = rem & 255;
  zA[idx]  = f2b(a2[(bh<<16) + ((size_t)j<<8) + i] * inv);
  zAT[idx] = f2b(a2[idx] * inv);
}

// ---------------- split-K flash partials ----------------
__global__ __launch_bounds__(256) void flash_part(const u16* __restrict__ Q, const u16* __restrict__ Kg,
    const u16* __restrict__ VT, float* __restrict__ po, float* __restrict__ pm, float* __restrict__ pl) {
  __shared__ u16 Ks[64*72];
  __shared__ u16 Vs[64*72];
  __shared__ u16 Ps[4*16*72];
  int qt = blockIdx.x, ch = blockIdx.y, bh = blockIdx.z;
  int q0 = qt * 64;
  int t = threadIdx.x, lane = t & 63, wid = t >> 6, lr = lane & 15, lg = lane >> 4;
  const u16* Qb  = Q  + ((size_t)bh*256)*64;
  const u16* Kb  = Kg + ((size_t)bh*4096 + ch*512)*64;
  const u16* VTb = VT + ((size_t)bh*64)*4096 + ch*512;
  int qrow = q0 + wid*16 + lr;
  s16x8 aq0 = *(const s16x8*)&Qb[(size_t)qrow*64 + lg*8];
  s16x8 aq1 = *(const s16x8*)&Qb[(size_t)qrow*64 + 32 + lg*8];
  f32x4 oacc[4];
  #pragma unroll
  for (int f = 0; f < 4; f++) oacc[f] = (f32x4)0.f;
  float m_[4] = {-3e38f, -3e38f, -3e38f, -3e38f};
  float l_[4] = {0.f, 0.f, 0.f, 0.f};
  u16* Pw = Ps + wid*16*72;
  for (int k0 = 0; k0 < 512; k0 += 64) {
    __syncthreads();
    #pragma unroll
    for (int p = 0; p < 2; p++) {
      int c = t + p*256; int r = c >> 3, cc = (c & 7)*8;
      *(uint4*)&Ks[r*72 + cc] = *(const uint4*)&Kb[(size_t)(k0 + r)*64 + cc];
      *(uint4*)&Vs[r*72 + cc] = *(const uint4*)&VTb[(size_t)r*4096 + k0 + cc];
    }
    __syncthreads();
    f32x4 sf[4];
    #pragma unroll
    for (int f = 0; f < 4; f++) {
      s16x8 b0 = *(s16x8*)&Ks[(f*16 + lr)*72 + lg*8];
      s16x8 b1 = *(s16x8*)&Ks[(f*16 + lr)*72 + 32 + lg*8];
      f32x4 s = (f32x4)0.f;
      s = MFMA16(aq0, b0, s);
      s = MFMA16(aq1, b1, s);
      sf[f] = s;
    }
    #pragma unroll
    for (int r = 0; r < 4; r++) {
      float mx = fmaxf(fmaxf(sf[0][r], sf[1][r]), fmaxf(sf[2][r], sf[3][r]));
      #pragma unroll
      for (int o = 1; o < 16; o <<= 1) mx = fmaxf(mx, __shfl_xor(mx, o));
      float mn = fmaxf(m_[r], mx);
      float sum = 0.f;
      #pragma unroll
      for (int f = 0; f < 4; f++) {
        float pv = __expf(sf[f][r] - mn);
        sum += pv;
        Pw[(lg*4 + r)*72 + f*16 + lr] = f2b(pv);
      }
      #pragma unroll
      for (int o = 1; o < 16; o <<= 1) sum += __shfl_xor(sum, o);
      float sc = __expf(m_[r] - mn);
      l_[r] = l_[r]*sc + sum;
      m_[r] = mn;
      #pragma unroll
      for (int f = 0; f < 4; f++) oacc[f][r] *= sc;
    }
    __syncthreads();
    #pragma unroll
    for (int ks = 0; ks < 2; ks++) {
      s16x8 ap = *(s16x8*)&Pw[lr*72 + ks*32 + lg*8];
      #pragma unroll
      for (int df = 0; df < 4; df++) {
        s16x8 bv = *(s16x8*)&Vs[(df*16 + lr)*72 + ks*32 + lg*8];
        oacc[df] = MFMA16(ap, bv, oacc[df]);
      }
    }
  }
  int pidx = (bh*4 + qt)*8 + ch;
  #pragma unroll
  for (int r = 0; r < 4; r++) {
    int lrow = wid*16 + lg*4 + r;
    if (lr == 0) { pm[pidx*64 + lrow] = m_[r]; pl[pidx*64 + lrow] = l_[r]; }
    #pragma unroll
    for (int df = 0; df < 4; df++)
      po[((size_t)pidx*64 + lrow)*64 + df*16 + lr] = oacc[df][r];
  }
}

// ---------------- merge partials ----------------
__global__ __launch_bounds__(256) void flash_merge(const float* __restrict__ po, const float* __restrict__ pm,
    const float* __restrict__ pl, u16* __restrict__ a3vT) {
  int row = blockIdx.x*4 + (threadIdx.x >> 6);
  int d = threadIdx.x & 63;
  int bh = row >> 8, qrow = row & 255, qt = qrow >> 6, lrow = qrow & 63;
  int pbase = (bh*4 + qt)*8;
  float m = -3e38f;
  #pragma unroll
  for (int ch = 0; ch < 8; ch++) m = fmaxf(m, pm[(pbase+ch)*64 + lrow]);
  float L = 0.f, O = 0.f;
  #pragma unroll
  for (int ch = 0; ch < 8; ch++) {
    float w = __expf(pm[(pbase+ch)*64 + lrow] - m);
    L += w * pl[(pbase+ch)*64 + lrow];
    O += w * po[((size_t)(pbase+ch)*64 + lrow)*64 + d];
  }
  a3vT[((size_t)bh*64 + d)*256 + qrow] = f2b(O / L);
}

// ---------------- exact-softmax flash: outh = softmax(q @ kl^T) @ w2 ----------------
__global__ __launch_bounds__(256) void flash_a1(const u16* __restrict__ Q, const u16* __restrict__ Kl,
    const u16* __restrict__ W2T, u16* __restrict__ outh) {
  __shared__ u16 Ks[64*72];
  __shared__ u16 Vs[64*264];
  __shared__ u16 Ps[4*16*264];
  int bh = blockIdx.y;
  int q0 = blockIdx.x * 64;
  int t = threadIdx.x, lane = t & 63, wid = t >> 6, lr = lane & 15, lg = lane >> 4;
  const u16* Qb = Q + ((size_t)bh*4096)*64;
  #pragma unroll
  for (int p = 0; p < 8; p++) {
    int c = t + p*256; int r = c >> 5, col = (c & 31)*8;
    *(uint4*)&Vs[r*264 + col] = *(const uint4*)&W2T[((size_t)bh*64 + r)*256 + col];
  }
  int qrow = q0 + wid*16 + lr;
  s16x8 aq0 = *(const s16x8*)&Qb[(size_t)qrow*64 + lg*8];
  s16x8 aq1 = *(const s16x8*)&Qb[(size_t)qrow*64 + 32 + lg*8];
  f32x4 sf[16];
  #pragma unroll
  for (int f = 0; f < 16; f++) sf[f] = (f32x4)0.f;
  #pragma unroll
  for (int kt = 0; kt < 4; kt++) {
    __syncthreads();
    #pragma unroll
    for (int p = 0; p < 2; p++) {
      int c = t + p*256; int r = c >> 3, cc = (c & 7)*8;
      *(uint4*)&Ks[r*72 + cc] = *(const uint4*)&Kl[((size_t)bh*256 + kt*64 + r)*64 + cc];
    }
    __syncthreads();
    #pragma unroll
    for (int f2 = 0; f2 < 4; f2++) {
      s16x8 b0 = *(s16x8*)&Ks[(f2*16 + lr)*72 + lg*8];
      s16x8 b1 = *(s16x8*)&Ks[(f2*16 + lr)*72 + 32 + lg*8];
      sf[kt*4 + f2] = MFMA16(aq1, b1, MFMA16(aq0, b0, sf[kt*4 + f2]));
    }
  }
  u16* Pw = Ps + wid*16*264;
  float linv[4];
  #pragma unroll
  for (int r = 0; r < 4; r++) {
    float mx = -3e38f;
    #pragma unroll
    for (int f = 0; f < 16; f++) mx = fmaxf(mx, sf[f][r]);
    #pragma unroll
    for (int o = 1; o < 16; o <<= 1) mx = fmaxf(mx, __shfl_xor(mx, o));
    float sum = 0.f;
    #pragma unroll
    for (int f = 0; f < 16; f++) {
      float pv = __expf(sf[f][r] - mx);
      sum += pv;
      Pw[(lg*4 + r)*264 + f*16 + lr] = f2b(pv);
    }
    #pragma unroll
    for (int o = 1; o < 16; o <<= 1) sum += __shfl_xor(sum, o);
    linv[r] = 1.f / sum;
  }
  f32x4 oacc[4];
  #pragma unroll
  for (int f = 0; f < 4; f++) oacc[f] = (f32x4)0.f;
  #pragma unroll
  for (int ks = 0; ks < 8; ks++) {
    s16x8 ap = *(s16x8*)&Pw[lr*264 + ks*32 + lg*8];
    #pragma unroll
    for (int df = 0; df < 4; df++) {
      s16x8 bv = *(s16x8*)&Vs[(df*16 + lr)*264 + ks*32 + lg*8];
      oacc[df] = MFMA16(ap, bv, oacc[df]);
    }
  }
  int b = bh >> 3, h = bh & 7;
  #pragma unroll
  for (int df = 0; df < 4; df++)
    #pragma unroll
    for (int r = 0; r < 4; r++) {
      int lrow = wid*16 + lg*4 + r;
      int col = df*16 + lr;
      outh[((size_t)(b*4096 + q0 + lrow))*512 + h*64 + col] = f2b(oacc[df][r] * linv[r]);
    }
}

// ---------------- LDS-tiled residual depthwise conv ----------------
__global__ __launch_bounds__(256) void conv_lds(const u16* __restrict__ v, const float* __restrict__ rw,
                                                u16* __restrict__ outh) {
  __shared__ u16 tile[160*72];
  __shared__ float wsm[33];
  int bh = blockIdx.y;
  int n0 = blockIdx.x * 128;
  int b = bh >> 3, h = bh & 7;
  int t = threadIdx.x;
  if (t < 33) wsm[t] = rw[h*33 + t];
  const u16* vb = v + ((size_t)bh*4096)*64;
  #pragma unroll
  for (int p = 0; p < 5; p++) {
    int c = t + p*256;
    int r = c >> 3, col = (c & 7)*8;
    int nn = n0 - 16 + r;
    uint4 val = make_uint4(0u,0u,0u,0u);
    if (nn >= 0 && nn < 4096) val = *(const uint4*)&vb[(size_t)nn*64 + col];
    *(uint4*)&tile[r*72 + col] = val;
  }
  __syncthreads();
  int d8 = (t & 7) * 8;
  int r0 = t >> 3;
  #pragma unroll
  for (int pass = 0; pass < 4; pass++) {
    int lrow = pass*32 + r0;
    float acc[8] = {};
    #pragma unroll
    for (int j = 0; j < 33; j++) {
      uint4 vv = *(uint4*)&tile[(lrow + j)*72 + d8];
      float w = wsm[j];
      acc[0] += b2f((u16)(vv.x & 0xffff)) * w;
      acc[1] += b2f((u16)(vv.x >> 16))    * w;
      acc[2] += b2f((u16)(vv.y & 0xffff)) * w;
      acc[3] += b2f((u16)(vv.y >> 16))    * w;
      acc[4] += b2f((u16)(vv.z & 0xffff)) * w;
      acc[5] += b2f((u16)(vv.z >> 16))    * w;
      acc[6] += b2f((u16)(vv.w & 0xffff)) * w;
      acc[7] += b2f((u16)(vv.w >> 16))    * w;
    }
    size_t oi = ((size_t)(b*4096 + n0 + lrow))*512 + h*64 + d8;
    uint4 ov = *(uint4*)&outh[oi];
    uint4 nv;
    nv.x = (unsigned)f2b(b2f((u16)(ov.x & 0xffff)) + acc[0]) | ((unsigned)f2b(b2f((u16)(ov.x >> 16)) + acc[1]) << 16);
    nv.y = (unsigned)f2b(b2f((u16)(ov.y & 0xffff)) + acc[2]) | ((unsigned)f2b(b2f((u16)(ov.y >> 16)) + acc[3]) << 16);
    nv.z = (unsigned)f2b(b2f((u16)(ov.z & 0xffff)) + acc[4]) | ((unsigned)f2b(b2f((u16)(ov.z >> 16)) + acc[5]) << 16);
    nv.w = (unsigned)f2b(b2f((u16)(ov.w & 0xffff)) + acc[6]) | ((unsigned)f2b(b2f((u16)(ov.w >> 16)) + acc[7]) << 16);
    *(uint4*)&outh[oi] = nv;
  }
}

extern "C" void kernel_launch(void* const* d_in, const int* in_sizes, int n_in,
                              void* d_out, int out_size, void* d_ws, size_t ws_size,
                              hipStream_t stream) {
  const float* x      = (const float*)d_in[0];
  const float* norm_w = (const float*)d_in[1];
  const float* norm_b = (const float*)d_in[2];
  const float* w_qkv  = (const float*)d_in[3];
  const float* w_out  = (const float*)d_in[4];
  const float* b_out  = (const float*)d_in[5];
  const float* res_w  = (const float*)d_in[6];
  float* out = (float*)d_out;
  char* ws = (char*)d_ws;

  size_t off = 0;
  u16* xn    = (u16*)(ws + off); off += 16777216;
  u16* q     = (u16*)(ws + off); off += 16777216;
  u16* k     = (u16*)(ws + off); off += 16777216;
  u16* v     = (u16*)(ws + off); off += 16777216;
  u16* vT    = (u16*)(ws + off); off += 16777216;
  u16* ql    = (u16*)(ws + off); off += 1048576;
  u16* kl    = (u16*)(ws + off); off += 1048576;
  float* a2  = (float*)(ws + off); off += 8388608;
  u16* a2h   = (u16*)(ws + off); off += 4194304;
  u16* zA    = (u16*)(ws + off); off += 4194304;
  u16* zAT   = (u16*)(ws + off); off += 4194304;
  u16* zB    = (u16*)(ws + off); off += 4194304;
  u16* zBT   = (u16*)(ws + off); off += 4194304;
  u16* xz    = (u16*)(ws + off); off += 4194304;
  u16* e1T   = (u16*)(ws + off); off += 4194304;
  u16* e2T   = (u16*)(ws + off); off += 4194304;
  u16* e3T   = (u16*)(ws + off); off += 4194304;
  u16* a3vT  = (u16*)(ws + off); off += 1048576;
  u16* w2T   = (u16*)(ws + off); off += 1048576;
  u16* wqkvT = (u16*)(ws + off); off += 1572864;
  u16* woutT = (u16*)(ws + off); off += 524288;
  u16* outh  = (u16*)(ws + off); off += 16777216;
  float* po  = (float*)(ws + off); off += 16777216;
  float* pm  = (float*)(ws + off); off += 262144;
  float* pl  = (float*)(ws + off); off += 262144;
  unsigned* scal = (unsigned*)(ws + off); off += 8;

  ln_kernel<<<16384, 256, 0, stream>>>(x, norm_w, norm_b, xn);
  wcast_T<<<3072, 256, 0, stream>>>(w_qkv, wqkvT, 512, 1536);
  wcast_T<<<1024, 256, 0, stream>>>(w_out, woutT, 512, 512);
  qkv_mfma<<<dim3(12, 128), 256, 0, stream>>>(xn, wqkvT, q, k, v);
  vtrans<<<dim3(64, 32), 256, 0, stream>>>(v, vT);
  landmark_kernel<<<8192, 64, 0, stream>>>(q, k, ql, kl);
  hipMemsetAsync(scal, 0, 8, stream);
  sim2_mfma<<<32, 256, 0, stream>>>(ql, kl, a2, a2h, scal);
  flash_part<<<dim3(4, 8, 32), 256, 0, stream>>>(ql, k, vT, po, pm, pl);
  flash_merge<<<2048, 256, 0, stream>>>(po, pm, pl, a3vT);
  z0_kernel<<<8192, 256, 0, stream>>>(a2, scal, zA, zAT);

  u16 *zc = zA, *zcT = zAT, *zn = zB, *znT = zBT;
  for (int it = 0; it < 6; it++) {
    bmm128<<<dim3(2,2,32), 256, 0, stream>>>(a2h, zcT, xz, nullptr, e1T, 1.f, 0.f);
    bmm128<<<dim3(2,2,32), 256, 0, stream>>>(xz, e1T, nullptr, e2T, nullptr, -1.f, 15.f);
    bmm128<<<dim3(2,2,32), 256, 0, stream>>>(xz, e2T, nullptr, e3T, nullptr, -1.f, 13.f);
    bmm128<<<dim3(2,2,32), 256, 0, stream>>>(zc, e3T, zn, znT, nullptr, 0.25f, 0.f);
    u16* tp;
    tp = zc; zc = zn; zn = tp;
    tp = zcT; zcT = znT; znT = tp;
  }

  bmm64<<<dim3(1,4,32), 256, 0, stream>>>(zc, a3vT, nullptr, w2T, nullptr, 256, 64, 256, 1.f, 0.f);
  flash_a1<<<dim3(64, 32), 256, 0, stream>>>(q, kl, w2T, outh);
  conv_lds<<<dim3(32, 32), 256, 0, stream>>>(v, res_w, outh);
  out_mfma<<<dim3(4, 128), 256, 0, stream>>>(outh, woutT, b_out, x, out);
}

// Round 7
// 473.119 us; speedup vs baseline: 2.7768x; 1.2659x over previous
//
#include <hip/hip_runtime.h>
#include <math.h>

typedef unsigned short u16;
typedef short s16x8 __attribute__((ext_vector_type(8)));
typedef float f32x4 __attribute__((ext_vector_type(4)));

#define MFMA16(a, b, c) __builtin_amdgcn_mfma_f32_16x16x32_bf16((a), (b), (c), 0, 0, 0)

__device__ __forceinline__ u16 f2b(float f) {
  unsigned u = __float_as_uint(f);
  unsigned r = (u + 0x7fff + ((u >> 16) & 1)) >> 16;
  return (u16)r;
}
__device__ __forceinline__ float b2f(u16 h) { return __uint_as_float(((unsigned)h) << 16); }

// ---------------- LayerNorm -> bf16 ----------------
__global__ __launch_bounds__(256) void ln_kernel(const float* __restrict__ x, const float* __restrict__ w,
                          const float* __restrict__ b, u16* __restrict__ xn) {
  int row = blockIdx.x;
  const float* xr = x + (size_t)row * 512;
  int t = threadIdx.x;
  float v0 = xr[t], v1 = xr[t + 256];
  float s = v0 + v1, ss = v0*v0 + v1*v1;
  for (int o = 32; o > 0; o >>= 1) { s += __shfl_down(s, o); ss += __shfl_down(ss, o); }
  __shared__ float ls[4], lss[4];
  int wid = t >> 6, lane = t & 63;
  if (lane == 0) { ls[wid] = s; lss[wid] = ss; }
  __syncthreads();
  float tot  = ls[0]+ls[1]+ls[2]+ls[3];
  float tot2 = lss[0]+lss[1]+lss[2]+lss[3];
  float mean = tot * (1.f/512);
  float var  = tot2 * (1.f/512) - mean*mean;
  float inv = rsqrtf(var + 1e-5f);
  u16* xo = xn + (size_t)row * 512;
  xo[t]     = f2b((v0-mean)*inv*w[t]     + b[t]);
  xo[t+256] = f2b((v1-mean)*inv*w[t+256] + b[t+256]);
}

// ---------------- weight transpose + cast ----------------
__global__ __launch_bounds__(256) void wcast_T(const float* __restrict__ W, u16* __restrict__ WT, int R, int C) {
  int idx = blockIdx.x*256 + threadIdx.x;
  if (idx >= R*C) return;
  int r = idx / C, c = idx - r*C;
  WT[(size_t)c*R + r] = f2b(W[idx]);
}

// ---------------- v transpose ----------------
__global__ __launch_bounds__(256) void vtrans(const u16* __restrict__ v, u16* __restrict__ vT) {
  __shared__ u16 tile[64][72];
  int bh = blockIdx.y, n0 = blockIdx.x * 64;
  int t = threadIdx.x;
  const u16* vb = v + ((size_t)bh*4096 + n0)*64;
  #pragma unroll
  for (int p = 0; p < 2; p++) {
    int c = t + p*256;
    int r = c >> 3, col = (c & 7)*8;
    *(uint4*)&tile[r][col] = *(const uint4*)&vb[(size_t)r*64 + col];
  }
  __syncthreads();
  #pragma unroll
  for (int p = 0; p < 2; p++) {
    int c = t + p*256;
    int d = c >> 3, ncol = (c & 7)*8;
    u16 tmp[8];
    #pragma unroll
    for (int j = 0; j < 8; j++) tmp[j] = tile[ncol + j][d];
    *(uint4*)&vT[((size_t)bh*64 + d)*4096 + n0 + ncol] = *(uint4*)tmp;
  }
}

// ---------------- 128x128 MFMA GEMM core (BK=32, proven) ----------------
__device__ __forceinline__ void gemm128_core(const u16* __restrict__ A, const u16* __restrict__ BT,
    int K, int ldA, int ldBT, int row0, int col0, u16* As, u16* Bs, f32x4 acc[4][4]) {
  int t = threadIdx.x, lane = t & 63, wid = t >> 6;
  int wr = (wid >> 1) * 64, wc = (wid & 1) * 64;
  int lr = lane & 15, lg = lane >> 4;
  for (int k0 = 0; k0 < K; k0 += 32) {
    __syncthreads();
    #pragma unroll
    for (int p = 0; p < 2; p++) {
      int ch = t + p*256;
      int r = ch >> 2, c = (ch & 3) * 8;
      *(uint4*)&As[r*40 + c] = *(const uint4*)&A[(size_t)(row0 + r)*ldA + k0 + c];
      *(uint4*)&Bs[r*40 + c] = *(const uint4*)&BT[(size_t)(col0 + r)*ldBT + k0 + c];
    }
    __syncthreads();
    s16x8 af[4], bf[4];
    #pragma unroll
    for (int f = 0; f < 4; f++) {
      af[f] = *(s16x8*)&As[(wr + f*16 + lr)*40 + lg*8];
      bf[f] = *(s16x8*)&Bs[(wc + f*16 + lr)*40 + lg*8];
    }
    #pragma unroll
    for (int i = 0; i < 4; i++)
      #pragma unroll
      for (int j = 0; j < 4; j++)
        acc[i][j] = MFMA16(af[i], bf[j], acc[i][j]);
  }
}

// ---------------- 128x64 MFMA GEMM core (for pinv stages; 256 threads, 2x2 waves) ----------------
__device__ __forceinline__ void gemm_128x64_core(const u16* __restrict__ A, const u16* __restrict__ BT,
    int row0, int col0, u16* As, u16* Bs, f32x4 acc[4][2]) {
  int t = threadIdx.x, lane = t & 63, wid = t >> 6;
  int wr = (wid >> 1) * 64, wc = (wid & 1) * 32;
  int lr = lane & 15, lg = lane >> 4;
  for (int k0 = 0; k0 < 256; k0 += 32) {
    __syncthreads();
    #pragma unroll
    for (int p = 0; p < 2; p++) {
      int ch = t + p*256;
      int r = ch >> 2, c = (ch & 3) * 8;
      *(uint4*)&As[r*40 + c] = *(const uint4*)&A[(size_t)(row0 + r)*256 + k0 + c];
    }
    { int r = t >> 2, c = (t & 3) * 8;
      *(uint4*)&Bs[r*40 + c] = *(const uint4*)&BT[(size_t)(col0 + r)*256 + k0 + c]; }
    __syncthreads();
    s16x8 af[4], bf[2];
    #pragma unroll
    for (int f = 0; f < 4; f++) af[f] = *(s16x8*)&As[(wr + f*16 + lr)*40 + lg*8];
    #pragma unroll
    for (int f = 0; f < 2; f++) bf[f] = *(s16x8*)&Bs[(wc + f*16 + lr)*40 + lg*8];
    #pragma unroll
    for (int i = 0; i < 4; i++)
      #pragma unroll
      for (int j = 0; j < 2; j++)
        acc[i][j] = MFMA16(af[i], bf[j], acc[i][j]);
  }
}

// ---------------- QKV (XCD-swizzled 1-D grid of 1536) ----------------
__global__ __launch_bounds__(256) void qkv_mfma(const u16* __restrict__ xn, const u16* __restrict__ wT,
    u16* __restrict__ q, u16* __restrict__ k, u16* __restrict__ v) {
  __shared__ u16 As[128*40], Bs[128*40];
  f32x4 acc[4][4];
  #pragma unroll
  for (int i = 0; i < 4; i++)
    #pragma unroll
    for (int j = 0; j < 4; j++) acc[i][j] = (f32x4)0.f;
  int bI = blockIdx.x;
  int job = (bI & 7)*192 + (bI >> 3);   // XCD-chunked: 16 row-panels per XCD
  int row0 = (job / 12) * 128, col0 = (job % 12) * 128;
  gemm128_core(xn, wT, 512, 512, 512, row0, col0, As, Bs, acc);
  int t = threadIdx.x, lane = t & 63, wid = t >> 6, lr = lane & 15, lg = lane >> 4;
  int wr = (wid >> 1)*64, wc = (wid & 1)*64;
  #pragma unroll
  for (int i = 0; i < 4; i++)
    #pragma unroll
    for (int j = 0; j < 4; j++)
      #pragma unroll
      for (int r = 0; r < 4; r++) {
        int row = row0 + wr + i*16 + lg*4 + r;
        int col = col0 + wc + j*16 + lr;
        float val = acc[i][j][r];
        int part = col >> 9, rem = col & 511, h = rem >> 6, d = rem & 63;
        int b = row >> 12, n = row & 4095;
        size_t bh = (size_t)(b*8 + h);
        size_t dst = (bh*4096 + n)*64 + d;
        if (part == 0)      q[dst] = f2b(val * 0.125f);
        else if (part == 1) k[dst] = f2b(val);
        else                v[dst] = f2b(val);
      }
}

// ---------------- out GEMM (XCD-swizzled 1-D grid of 512) ----------------
__global__ __launch_bounds__(256) void out_mfma(const u16* __restrict__ outh, const u16* __restrict__ wT,
    const float* __restrict__ bo, const float* __restrict__ x, float* __restrict__ out) {
  __shared__ u16 As[128*40], Bs[128*40];
  f32x4 acc[4][4];
  #pragma unroll
  for (int i = 0; i < 4; i++)
    #pragma unroll
    for (int j = 0; j < 4; j++) acc[i][j] = (f32x4)0.f;
  int bI = blockIdx.x;
  int job = (bI & 7)*64 + (bI >> 3);
  int row0 = (job / 4) * 128, col0 = (job % 4) * 128;
  gemm128_core(outh, wT, 512, 512, 512, row0, col0, As, Bs, acc);
  int t = threadIdx.x, lane = t & 63, wid = t >> 6, lr = lane & 15, lg = lane >> 4;
  int wr = (wid >> 1)*64, wc = (wid & 1)*64;
  #pragma unroll
  for (int i = 0; i < 4; i++)
    #pragma unroll
    for (int j = 0; j < 4; j++)
      #pragma unroll
      for (int r = 0; r < 4; r++) {
        int row = row0 + wr + i*16 + lg*4 + r;
        int col = col0 + wc + j*16 + lr;
        size_t idx = (size_t)row*512 + col;
        out[idx] = x[idx] + acc[i][j][r] + bo[col];
      }
}

// ---------------- pinv stage 1: P = a2 @ z ; write P, P^T, (7I-P)^T ----------------
__global__ __launch_bounds__(256) void pinv_s1(const u16* __restrict__ a2h, const u16* __restrict__ zcT,
    u16* __restrict__ xz, u16* __restrict__ xzT, u16* __restrict__ e1T) {
  __shared__ u16 As[128*40], Bs[64*40];
  size_t bb = (size_t)blockIdx.z << 16;
  f32x4 acc[4][2];
  #pragma unroll
  for (int i = 0; i < 4; i++) { acc[i][0] = (f32x4)0.f; acc[i][1] = (f32x4)0.f; }
  int row0 = blockIdx.y*128, col0 = blockIdx.x*64;
  gemm_128x64_core(a2h + bb, zcT + bb, row0, col0, As, Bs, acc);
  int t = threadIdx.x, lane = t & 63, wid = t >> 6, lr = lane & 15, lg = lane >> 4;
  int wr = (wid >> 1)*64, wc = (wid & 1)*32;
  #pragma unroll
  for (int i = 0; i < 4; i++)
    #pragma unroll
    for (int j = 0; j < 2; j++)
      #pragma unroll
      for (int r = 0; r < 4; r++) {
        int row = row0 + wr + i*16 + lg*4 + r;
        int col = col0 + wc + j*16 + lr;
        float c = acc[i][j][r];
        xz [bb + (size_t)row*256 + col] = f2b(c);
        xzT[bb + (size_t)col*256 + row] = f2b(c);
        e1T[bb + (size_t)col*256 + row] = f2b((row == col ? 7.f : 0.f) - c);
      }
}

// ---------------- pinv stage 2: batches 0-31: e2T=(15I - P@e1)^T ; 32-63: W = z@P ----------------
__global__ __launch_bounds__(256) void pinv_s2(const u16* __restrict__ xz, const u16* __restrict__ e1T,
    const u16* __restrict__ zc, const u16* __restrict__ xzT,
    u16* __restrict__ e2T, u16* __restrict__ W) {
  __shared__ u16 As[128*40], Bs[64*40];
  int bz = blockIdx.z;
  bool isQ = bz < 32;
  size_t bb = (size_t)(isQ ? bz : bz - 32) << 16;
  const u16* Aptr = (isQ ? xz : zc) + bb;
  const u16* Bptr = (isQ ? e1T : xzT) + bb;
  f32x4 acc[4][2];
  #pragma unroll
  for (int i = 0; i < 4; i++) { acc[i][0] = (f32x4)0.f; acc[i][1] = (f32x4)0.f; }
  int row0 = blockIdx.y*128, col0 = blockIdx.x*64;
  gemm_128x64_core(Aptr, Bptr, row0, col0, As, Bs, acc);
  int t = threadIdx.x, lane = t & 63, wid = t >> 6, lr = lane & 15, lg = lane >> 4;
  int wr = (wid >> 1)*64, wc = (wid & 1)*32;
  #pragma unroll
  for (int i = 0; i < 4; i++)
    #pragma unroll
    for (int j = 0; j < 2; j++)
      #pragma unroll
      for (int r = 0; r < 4; r++) {
        int row = row0 + wr + i*16 + lg*4 + r;
        int col = col0 + wc + j*16 + lr;
        float c = acc[i][j][r];
        if (isQ) e2T[bb + (size_t)col*256 + row] = f2b((row == col ? 15.f : 0.f) - c);
        else     W  [bb + (size_t)row*256 + col] = f2b(c);
      }
}

// ---------------- pinv stage 3: zn = 3.25 z - 0.25 W@e2 ; write zn, zn^T ----------------
__global__ __launch_bounds__(256) void pinv_s3(const u16* __restrict__ W, const u16* __restrict__ e2T,
    const u16* __restrict__ zc, u16* __restrict__ zn, u16* __restrict__ znT) {
  __shared__ u16 As[128*40], Bs[64*40];
  size_t bb = (size_t)blockIdx.z << 16;
  f32x4 acc[4][2];
  #pragma unroll
  for (int i = 0; i < 4; i++) { acc[i][0] = (f32x4)0.f; acc[i][1] = (f32x4)0.f; }
  int row0 = blockIdx.y*128, col0 = blockIdx.x*64;
  gemm_128x64_core(W + bb, e2T + bb, row0, col0, As, Bs, acc);
  int t = threadIdx.x, lane = t & 63, wid = t >> 6, lr = lane & 15, lg = lane >> 4;
  int wr = (wid >> 1)*64, wc = (wid & 1)*32;
  #pragma unroll
  for (int i = 0; i < 4; i++)
    #pragma unroll
    for (int j = 0; j < 2; j++)
      #pragma unroll
      for (int r = 0; r < 4; r++) {
        int row = row0 + wr + i*16 + lg*4 + r;
        int col = col0 + wc + j*16 + lr;
        size_t idx = bb + (size_t)row*256 + col;
        float val = 3.25f*b2f(zc[idx]) - 0.25f*acc[i][j][r];
        zn [idx] = f2b(val);
        znT[bb + (size_t)col*256 + row] = f2b(val);
      }
}

// ---------------- batched 64x64-tile MFMA GEMM (final w2T) ----------------
__global__ __launch_bounds__(256) void bmm64(const u16* __restrict__ A, const u16* __restrict__ BT,
    u16* __restrict__ Cn, u16* __restrict__ CT, u16* __restrict__ CE,
    int M, int N, int K, float alpha, float diag) {
  __shared__ u16 As[64*40], Bs[64*40];
  int batch = blockIdx.z;
  const u16* Ab = A  + (size_t)batch*M*K;
  const u16* Bb = BT + (size_t)batch*N*K;
  int row0 = blockIdx.y*64, col0 = blockIdx.x*64;
  int t = threadIdx.x, lane = t & 63, wid = t >> 6, lr = lane & 15, lg = lane >> 4;
  int wr = (wid >> 1)*32, wc = (wid & 1)*32;
  f32x4 acc[2][2];
  #pragma unroll
  for (int i = 0; i < 2; i++)
    #pragma unroll
    for (int j = 0; j < 2; j++) acc[i][j] = (f32x4)0.f;
  for (int k0 = 0; k0 < K; k0 += 32) {
    __syncthreads();
    int r = t >> 2, c = (t & 3)*8;
    *(uint4*)&As[r*40 + c] = *(const uint4*)&Ab[(size_t)(row0 + r)*K + k0 + c];
    *(uint4*)&Bs[r*40 + c] = *(const uint4*)&Bb[(size_t)(col0 + r)*K + k0 + c];
    __syncthreads();
    s16x8 af[2], bf[2];
    #pragma unroll
    for (int f = 0; f < 2; f++) {
      af[f] = *(s16x8*)&As[(wr + f*16 + lr)*40 + lg*8];
      bf[f] = *(s16x8*)&Bs[(wc + f*16 + lr)*40 + lg*8];
    }
    #pragma unroll
    for (int i = 0; i < 2; i++)
      #pragma unroll
      for (int j = 0; j < 2; j++)
        acc[i][j] = MFMA16(af[i], bf[j], acc[i][j]);
  }
  size_t cb = (size_t)batch*M*N;
  #pragma unroll
  for (int i = 0; i < 2; i++)
    #pragma unroll
    for (int j = 0; j < 2; j++)
      #pragma unroll
      for (int r = 0; r < 4; r++) {
        int row = row0 + wr + i*16 + lg*4 + r;
        int col = col0 + wc + j*16 + lr;
        float val = alpha*acc[i][j][r] + (row == col ? diag : 0.f);
        if (Cn) Cn[cb + (size_t)row*N + col] = f2b(val);
        if (CT) CT[cb + (size_t)col*M + row] = f2b(val);
        if (CE) CE[cb + (size_t)col*M + row] = f2b((row == col ? 7.f : 0.f) - val);
      }
}

// ---------------- landmarks ----------------
__global__ void landmark_kernel(const u16* __restrict__ q, const u16* __restrict__ k,
                                u16* __restrict__ ql, u16* __restrict__ kl) {
  int idx = blockIdx.x;
  int d = threadIdx.x;
  size_t base = ((size_t)idx * 16) * 64 + d;
  float sq = 0.f, sk = 0.f;
  #pragma unroll
  for (int j = 0; j < 16; j++) { sq += b2f(q[base + (size_t)j*64]); sk += b2f(k[base + (size_t)j*64]); }
  ql[(size_t)idx*64 + d] = f2b(sq * (1.f/16.f));
  kl[(size_t)idx*64 + d] = f2b(sk * (1.f/16.f));
}

// ---------------- sim2: MFMA QK^T + exact softmax + colsum-max ----------------
__global__ __launch_bounds__(256) void sim2_mfma(const u16* __restrict__ ql, const u16* __restrict__ kl,
    float* __restrict__ a2, u16* __restrict__ a2h, unsigned* __restrict__ scal) {
  __shared__ u16 Qs[256*72];
  __shared__ u16 Ks2[256*72];
  __shared__ float wcol[4*256];
  __shared__ float red[256];
  int bh = blockIdx.x;
  int t = threadIdx.x, lane = t & 63, wid = t >> 6, lr = lane & 15, lg = lane >> 4;
  #pragma unroll
  for (int p = 0; p < 8; p++) {
    int c = t + p*256;
    int r = c >> 3, col = (c & 7)*8;
    *(uint4*)&Qs[r*72 + col]  = *(const uint4*)&ql[((size_t)bh*256 + r)*64 + col];
    *(uint4*)&Ks2[r*72 + col] = *(const uint4*)&kl[((size_t)bh*256 + r)*64 + col];
  }
  __syncthreads();
  float colp[16];
  #pragma unroll
  for (int cf = 0; cf < 16; cf++) colp[cf] = 0.f;
  for (int rf = 0; rf < 4; rf++) {
    int rbase = wid*64 + rf*16;
    s16x8 a0 = *(s16x8*)&Qs[(rbase + lr)*72 + lg*8];
    s16x8 a1 = *(s16x8*)&Qs[(rbase + lr)*72 + 32 + lg*8];
    f32x4 sf[16];
    #pragma unroll
    for (int cf = 0; cf < 16; cf++) {
      s16x8 b0 = *(s16x8*)&Ks2[(cf*16 + lr)*72 + lg*8];
      s16x8 b1 = *(s16x8*)&Ks2[(cf*16 + lr)*72 + 32 + lg*8];
      sf[cf] = MFMA16(a1, b1, MFMA16(a0, b0, (f32x4)0.f));
    }
    #pragma unroll
    for (int r = 0; r < 4; r++) {
      float mx = -3e38f;
      #pragma unroll
      for (int cf = 0; cf < 16; cf++) mx = fmaxf(mx, sf[cf][r]);
      #pragma unroll
      for (int o = 1; o < 16; o <<= 1) mx = fmaxf(mx, __shfl_xor(mx, o));
      float sum = 0.f;
      #pragma unroll
      for (int cf = 0; cf < 16; cf++) { sf[cf][r] = __expf(sf[cf][r] - mx); sum += sf[cf][r]; }
      #pragma unroll
      for (int o = 1; o < 16; o <<= 1) sum += __shfl_xor(sum, o);
      float inv = 1.f / sum;
      int row = rbase + lg*4 + r;
      size_t base = (size_t)bh*65536 + (size_t)row*256;
      #pragma unroll
      for (int cf = 0; cf < 16; cf++) {
        float pp = sf[cf][r] * inv;
        a2[base + cf*16 + lr] = pp;
        a2h[base + cf*16 + lr] = f2b(pp);
        colp[cf] += pp;
      }
    }
  }
  #pragma unroll
  for (int cf = 0; cf < 16; cf++) {
    colp[cf] += __shfl_xor(colp[cf], 16);
    colp[cf] += __shfl_xor(colp[cf], 32);
  }
  if (lg == 0) {
    #pragma unroll
    for (int cf = 0; cf < 16; cf++) wcol[wid*256 + cf*16 + lr] = colp[cf];
  }
  __syncthreads();
  red[t] = wcol[t] + wcol[256 + t] + wcol[512 + t] + wcol[768 + t];
  __syncthreads();
  for (int o = 128; o > 0; o >>= 1) {
    if (t < o) red[t] = fmaxf(red[t], red[t+o]);
    __syncthreads();
  }
  if (t == 0) atomicMax(scal + 1, __float_as_uint(red[0]));
}

// ---------------- z0 = a2^T / colmax ----------------
__global__ void z0_kernel(const float* __restrict__ a2, const unsigned* __restrict__ scal,
                          u16* __restrict__ zA, u16* __restrict__ zAT) {
  size_t idx = (size_t)blockIdx.x*256 + threadIdx.x;
  float inv = 1.f / __uint_as_float(scal[1]);
  size_t bh = idx >> 16; int rem = (int)(idx & 65535); int i = rem >> 8, j = rem & 255;
  zA[idx]  = f2b(a2[(bh<<16) + ((size_t)j<<8) + i] * inv);
  zAT[idx] = f2b(a2[idx] * inv);
}

// ---------------- split-K flash partials ----------------
__global__ __launch_bounds__(256) void flash_part(const u16* __restrict__ Q, const u16* __restrict__ Kg,
    const u16* __restrict__ VT, float* __restrict__ po, float* __restrict__ pm, float* __restrict__ pl) {
  __shared__ u16 Ks[64*72];
  __shared__ u16 Vs[64*72];
  __shared__ u16 Ps[4*16*72];
  int qt = blockIdx.x, ch = blockIdx.y, bh = blockIdx.z;
  int q0 = qt * 64;
  int t = threadIdx.x, lane = t & 63, wid = t >> 6, lr = lane & 15, lg = lane >> 4;
  const u16* Qb  = Q  + ((size_t)bh*256)*64;
  const u16* Kb  = Kg + ((size_t)bh*4096 + ch*512)*64;
  const u16* VTb = VT + ((size_t)bh*64)*4096 + ch*512;
  int qrow = q0 + wid*16 + lr;
  s16x8 aq0 = *(const s16x8*)&Qb[(size_t)qrow*64 + lg*8];
  s16x8 aq1 = *(const s16x8*)&Qb[(size_t)qrow*64 + 32 + lg*8];
  f32x4 oacc[4];
  #pragma unroll
  for (int f = 0; f < 4; f++) oacc[f] = (f32x4)0.f;
  float m_[4] = {-3e38f, -3e38f, -3e38f, -3e38f};
  float l_[4] = {0.f, 0.f, 0.f, 0.f};
  u16* Pw = Ps + wid*16*72;
  for (int k0 = 0; k0 < 512; k0 += 64) {
    __syncthreads();
    #pragma unroll
    for (int p = 0; p < 2; p++) {
      int c = t + p*256; int r = c >> 3, cc = (c & 7)*8;
      *(uint4*)&Ks[r*72 + cc] = *(const uint4*)&Kb[(size_t)(k0 + r)*64 + cc];
      *(uint4*)&Vs[r*72 + cc] = *(const uint4*)&VTb[(size_t)r*4096 + k0 + cc];
    }
    __syncthreads();
    f32x4 sf[4];
    #pragma unroll
    for (int f = 0; f < 4; f++) {
      s16x8 b0 = *(s16x8*)&Ks[(f*16 + lr)*72 + lg*8];
      s16x8 b1 = *(s16x8*)&Ks[(f*16 + lr)*72 + 32 + lg*8];
      f32x4 s = (f32x4)0.f;
      s = MFMA16(aq0, b0, s);
      s = MFMA16(aq1, b1, s);
      sf[f] = s;
    }
    #pragma unroll
    for (int r = 0; r < 4; r++) {
      float mx = fmaxf(fmaxf(sf[0][r], sf[1][r]), fmaxf(sf[2][r], sf[3][r]));
      #pragma unroll
      for (int o = 1; o < 16; o <<= 1) mx = fmaxf(mx, __shfl_xor(mx, o));
      float mn = fmaxf(m_[r], mx);
      float sum = 0.f;
      #pragma unroll
      for (int f = 0; f < 4; f++) {
        float pv = __expf(sf[f][r] - mn);
        sum += pv;
        Pw[(lg*4 + r)*72 + f*16 + lr] = f2b(pv);
      }
      #pragma unroll
      for (int o = 1; o < 16; o <<= 1) sum += __shfl_xor(sum, o);
      float sc = __expf(m_[r] - mn);
      l_[r] = l_[r]*sc + sum;
      m_[r] = mn;
      #pragma unroll
      for (int f = 0; f < 4; f++) oacc[f][r] *= sc;
    }
    __syncthreads();
    #pragma unroll
    for (int ks = 0; ks < 2; ks++) {
      s16x8 ap = *(s16x8*)&Pw[lr*72 + ks*32 + lg*8];
      #pragma unroll
      for (int df = 0; df < 4; df++) {
        s16x8 bv = *(s16x8*)&Vs[(df*16 + lr)*72 + ks*32 + lg*8];
        oacc[df] = MFMA16(ap, bv, oacc[df]);
      }
    }
  }
  int pidx = (bh*4 + qt)*8 + ch;
  #pragma unroll
  for (int r = 0; r < 4; r++) {
    int lrow = wid*16 + lg*4 + r;
    if (lr == 0) { pm[pidx*64 + lrow] = m_[r]; pl[pidx*64 + lrow] = l_[r]; }
    #pragma unroll
    for (int df = 0; df < 4; df++)
      po[((size_t)pidx*64 + lrow)*64 + df*16 + lr] = oacc[df][r];
  }
}

// ---------------- merge partials ----------------
__global__ __launch_bounds__(256) void flash_merge(const float* __restrict__ po, const float* __restrict__ pm,
    const float* __restrict__ pl, u16* __restrict__ a3vT) {
  int row = blockIdx.x*4 + (threadIdx.x >> 6);
  int d = threadIdx.x & 63;
  int bh = row >> 8, qrow = row & 255, qt = qrow >> 6, lrow = qrow & 63;
  int pbase = (bh*4 + qt)*8;
  float m = -3e38f;
  #pragma unroll
  for (int ch = 0; ch < 8; ch++) m = fmaxf(m, pm[(pbase+ch)*64 + lrow]);
  float L = 0.f, O = 0.f;
  #pragma unroll
  for (int ch = 0; ch < 8; ch++) {
    float w = __expf(pm[(pbase+ch)*64 + lrow] - m);
    L += w * pl[(pbase+ch)*64 + lrow];
    O += w * po[((size_t)(pbase+ch)*64 + lrow)*64 + d];
  }
  a3vT[((size_t)bh*64 + d)*256 + qrow] = f2b(O / L);
}

// ---------------- exact-softmax flash: outh = softmax(q @ kl^T) @ w2 ----------------
__global__ __launch_bounds__(256) void flash_a1(const u16* __restrict__ Q, const u16* __restrict__ Kl,
    const u16* __restrict__ W2T, u16* __restrict__ outh) {
  __shared__ u16 Ks[64*72];
  __shared__ u16 Vs[64*264];
  __shared__ u16 Ps[4*16*264];
  int bh = blockIdx.y;
  int q0 = blockIdx.x * 64;
  int t = threadIdx.x, lane = t & 63, wid = t >> 6, lr = lane & 15, lg = lane >> 4;
  const u16* Qb = Q + ((size_t)bh*4096)*64;
  #pragma unroll
  for (int p = 0; p < 8; p++) {
    int c = t + p*256; int r = c >> 5, col = (c & 31)*8;
    *(uint4*)&Vs[r*264 + col] = *(const uint4*)&W2T[((size_t)bh*64 + r)*256 + col];
  }
  int qrow = q0 + wid*16 + lr;
  s16x8 aq0 = *(const s16x8*)&Qb[(size_t)qrow*64 + lg*8];
  s16x8 aq1 = *(const s16x8*)&Qb[(size_t)qrow*64 + 32 + lg*8];
  f32x4 sf[16];
  #pragma unroll
  for (int f = 0; f < 16; f++) sf[f] = (f32x4)0.f;
  #pragma unroll
  for (int kt = 0; kt < 4; kt++) {
    __syncthreads();
    #pragma unroll
    for (int p = 0; p < 2; p++) {
      int c = t + p*256; int r = c >> 3, cc = (c & 7)*8;
      *(uint4*)&Ks[r*72 + cc] = *(const uint4*)&Kl[((size_t)bh*256 + kt*64 + r)*64 + cc];
    }
    __syncthreads();
    #pragma unroll
    for (int f2 = 0; f2 < 4; f2++) {
      s16x8 b0 = *(s16x8*)&Ks[(f2*16 + lr)*72 + lg*8];
      s16x8 b1 = *(s16x8*)&Ks[(f2*16 + lr)*72 + 32 + lg*8];
      sf[kt*4 + f2] = MFMA16(aq1, b1, MFMA16(aq0, b0, sf[kt*4 + f2]));
    }
  }
  u16* Pw = Ps + wid*16*264;
  float linv[4];
  #pragma unroll
  for (int r = 0; r < 4; r++) {
    float mx = -3e38f;
    #pragma unroll
    for (int f = 0; f < 16; f++) mx = fmaxf(mx, sf[f][r]);
    #pragma unroll
    for (int o = 1; o < 16; o <<= 1) mx = fmaxf(mx, __shfl_xor(mx, o));
    float sum = 0.f;
    #pragma unroll
    for (int f = 0; f < 16; f++) {
      float pv = __expf(sf[f][r] - mx);
      sum += pv;
      Pw[(lg*4 + r)*264 + f*16 + lr] = f2b(pv);
    }
    #pragma unroll
    for (int o = 1; o < 16; o <<= 1) sum += __shfl_xor(sum, o);
    linv[r] = 1.f / sum;
  }
  f32x4 oacc[4];
  #pragma unroll
  for (int f = 0; f < 4; f++) oacc[f] = (f32x4)0.f;
  #pragma unroll
  for (int ks = 0; ks < 8; ks++) {
    s16x8 ap = *(s16x8*)&Pw[lr*264 + ks*32 + lg*8];
    #pragma unroll
    for (int df = 0; df < 4; df++) {
      s16x8 bv = *(s16x8*)&Vs[(df*16 + lr)*264 + ks*32 + lg*8];
      oacc[df] = MFMA16(ap, bv, oacc[df]);
    }
  }
  int b = bh >> 3, h = bh & 7;
  #pragma unroll
  for (int df = 0; df < 4; df++)
    #pragma unroll
    for (int r = 0; r < 4; r++) {
      int lrow = wid*16 + lg*4 + r;
      int col = df*16 + lr;
      outh[((size_t)(b*4096 + q0 + lrow))*512 + h*64 + col] = f2b(oacc[df][r] * linv[r]);
    }
}

// ---------------- LDS-tiled residual depthwise conv ----------------
__global__ __launch_bounds__(256) void conv_lds(const u16* __restrict__ v, const float* __restrict__ rw,
                                                u16* __restrict__ outh) {
  __shared__ u16 tile[160*72];
  __shared__ float wsm[33];
  int bh = blockIdx.y;
  int n0 = blockIdx.x * 128;
  int b = bh >> 3, h = bh & 7;
  int t = threadIdx.x;
  if (t < 33) wsm[t] = rw[h*33 + t];
  const u16* vb = v + ((size_t)bh*4096)*64;
  #pragma unroll
  for (int p = 0; p < 5; p++) {
    int c = t + p*256;
    int r = c >> 3, col = (c & 7)*8;
    int nn = n0 - 16 + r;
    uint4 val = make_uint4(0u,0u,0u,0u);
    if (nn >= 0 && nn < 4096) val = *(const uint4*)&vb[(size_t)nn*64 + col];
    *(uint4*)&tile[r*72 + col] = val;
  }
  __syncthreads();
  int d8 = (t & 7) * 8;
  int r0 = t >> 3;
  #pragma unroll
  for (int pass = 0; pass < 4; pass++) {
    int lrow = pass*32 + r0;
    float acc[8] = {};
    #pragma unroll
    for (int j = 0; j < 33; j++) {
      uint4 vv = *(uint4*)&tile[(lrow + j)*72 + d8];
      float w = wsm[j];
      acc[0] += b2f((u16)(vv.x & 0xffff)) * w;
      acc[1] += b2f((u16)(vv.x >> 16))    * w;
      acc[2] += b2f((u16)(vv.y & 0xffff)) * w;
      acc[3] += b2f((u16)(vv.y >> 16))    * w;
      acc[4] += b2f((u16)(vv.z & 0xffff)) * w;
      acc[5] += b2f((u16)(vv.z >> 16))    * w;
      acc[6] += b2f((u16)(vv.w & 0xffff)) * w;
      acc[7] += b2f((u16)(vv.w >> 16))    * w;
    }
    size_t oi = ((size_t)(b*4096 + n0 + lrow))*512 + h*64 + d8;
    uint4 ov = *(uint4*)&outh[oi];
    uint4 nv;
    nv.x = (unsigned)f2b(b2f((u16)(ov.x & 0xffff)) + acc[0]) | ((unsigned)f2b(b2f((u16)(ov.x >> 16)) + acc[1]) << 16);
    nv.y = (unsigned)f2b(b2f((u16)(ov.y & 0xffff)) + acc[2]) | ((unsigned)f2b(b2f((u16)(ov.y >> 16)) + acc[3]) << 16);
    nv.z = (unsigned)f2b(b2f((u16)(ov.z & 0xffff)) + acc[4]) | ((unsigned)f2b(b2f((u16)(ov.z >> 16)) + acc[5]) << 16);
    nv.w = (unsigned)f2b(b2f((u16)(ov.w & 0xffff)) + acc[6]) | ((unsigned)f2b(b2f((u16)(ov.w >> 16)) + acc[7]) << 16);
    *(uint4*)&outh[oi] = nv;
  }
}

extern "C" void kernel_launch(void* const* d_in, const int* in_sizes, int n_in,
                              void* d_out, int out_size, void* d_ws, size_t ws_size,
                              hipStream_t stream) {
  const float* x      = (const float*)d_in[0];
  const float* norm_w = (const float*)d_in[1];
  const float* norm_b = (const float*)d_in[2];
  const float* w_qkv  = (const float*)d_in[3];
  const float* w_out  = (const float*)d_in[4];
  const float* b_out  = (const float*)d_in[5];
  const float* res_w  = (const float*)d_in[6];
  float* out = (float*)d_out;
  char* ws = (char*)d_ws;

  size_t off = 0;
  u16* xn    = (u16*)(ws + off); off += 16777216;
  u16* q     = (u16*)(ws + off); off += 16777216;
  u16* k     = (u16*)(ws + off); off += 16777216;
  u16* v     = (u16*)(ws + off); off += 16777216;
  u16* vT    = (u16*)(ws + off); off += 16777216;
  u16* ql    = (u16*)(ws + off); off += 1048576;
  u16* kl    = (u16*)(ws + off); off += 1048576;
  float* a2  = (float*)(ws + off); off += 8388608;
  u16* a2h   = (u16*)(ws + off); off += 4194304;
  u16* zA    = (u16*)(ws + off); off += 4194304;
  u16* zAT   = (u16*)(ws + off); off += 4194304;
  u16* zB    = (u16*)(ws + off); off += 4194304;
  u16* zBT   = (u16*)(ws + off); off += 4194304;
  u16* xz    = (u16*)(ws + off); off += 4194304;
  u16* xzT   = (u16*)(ws + off); off += 4194304;
  u16* e1T   = (u16*)(ws + off); off += 4194304;
  u16* e2T   = (u16*)(ws + off); off += 4194304;
  u16* Wm    = (u16*)(ws + off); off += 4194304;
  u16* a3vT  = (u16*)(ws + off); off += 1048576;
  u16* w2T   = (u16*)(ws + off); off += 1048576;
  u16* wqkvT = (u16*)(ws + off); off += 1572864;
  u16* woutT = (u16*)(ws + off); off += 524288;
  u16* outh  = (u16*)(ws + off); off += 16777216;
  float* po  = (float*)(ws + off); off += 16777216;
  float* pm  = (float*)(ws + off); off += 262144;
  float* pl  = (float*)(ws + off); off += 262144;
  unsigned* scal = (unsigned*)(ws + off); off += 8;

  ln_kernel<<<16384, 256, 0, stream>>>(x, norm_w, norm_b, xn);
  wcast_T<<<3072, 256, 0, stream>>>(w_qkv, wqkvT, 512, 1536);
  wcast_T<<<1024, 256, 0, stream>>>(w_out, woutT, 512, 512);
  qkv_mfma<<<1536, 256, 0, stream>>>(xn, wqkvT, q, k, v);
  vtrans<<<dim3(64, 32), 256, 0, stream>>>(v, vT);
  landmark_kernel<<<8192, 64, 0, stream>>>(q, k, ql, kl);
  hipMemsetAsync(scal, 0, 8, stream);
  sim2_mfma<<<32, 256, 0, stream>>>(ql, kl, a2, a2h, scal);
  flash_part<<<dim3(4, 8, 32), 256, 0, stream>>>(ql, k, vT, po, pm, pl);
  flash_merge<<<2048, 256, 0, stream>>>(po, pm, pl, a3vT);
  z0_kernel<<<8192, 256, 0, stream>>>(a2, scal, zA, zAT);

  u16 *zc = zA, *zcT = zAT, *zn = zB, *znT = zBT;
  for (int it = 0; it < 6; it++) {
    pinv_s1<<<dim3(4,2,32), 256, 0, stream>>>(a2h, zcT, xz, xzT, e1T);
    pinv_s2<<<dim3(4,2,64), 256, 0, stream>>>(xz, e1T, zc, xzT, e2T, Wm);
    pinv_s3<<<dim3(4,2,32), 256, 0, stream>>>(Wm, e2T, zc, zn, znT);
    u16* tp;
    tp = zc; zc = zn; zn = tp;
    tp = zcT; zcT = znT; znT = tp;
  }

  bmm64<<<dim3(1,4,32), 256, 0, stream>>>(zc, a3vT, nullptr, w2T, nullptr, 256, 64, 256, 1.f, 0.f);
  flash_a1<<<dim3(64, 32), 256, 0, stream>>>(q, kl, w2T, outh);
  conv_lds<<<dim3(32, 32), 256, 0, stream>>>(v, res_w, outh);
  out_mfma<<<512, 256, 0, stream>>>(outh, woutT, b_out, x, out);
}

// Round 8
// 459.676 us; speedup vs baseline: 2.8580x; 1.0292x over previous
//
#include <hip/hip_runtime.h>
#include <math.h>

typedef unsigned short u16;
typedef short s16x8 __attribute__((ext_vector_type(8)));
typedef float f32x4 __attribute__((ext_vector_type(4)));

#define MFMA16(a, b, c) __builtin_amdgcn_mfma_f32_16x16x32_bf16((a), (b), (c), 0, 0, 0)

__device__ __forceinline__ u16 f2b(float f) {
  unsigned u = __float_as_uint(f);
  unsigned r = (u + 0x7fff + ((u >> 16) & 1)) >> 16;
  return (u16)r;
}
__device__ __forceinline__ float b2f(u16 h) { return __uint_as_float(((unsigned)h) << 16); }

// ---------------- LayerNorm -> bf16 ----------------
__global__ __launch_bounds__(256) void ln_kernel(const float* __restrict__ x, const float* __restrict__ w,
                          const float* __restrict__ b, u16* __restrict__ xn) {
  int row = blockIdx.x;
  const float* xr = x + (size_t)row * 512;
  int t = threadIdx.x;
  float v0 = xr[t], v1 = xr[t + 256];
  float s = v0 + v1, ss = v0*v0 + v1*v1;
  for (int o = 32; o > 0; o >>= 1) { s += __shfl_down(s, o); ss += __shfl_down(ss, o); }
  __shared__ float ls[4], lss[4];
  int wid = t >> 6, lane = t & 63;
  if (lane == 0) { ls[wid] = s; lss[wid] = ss; }
  __syncthreads();
  float tot  = ls[0]+ls[1]+ls[2]+ls[3];
  float tot2 = lss[0]+lss[1]+lss[2]+lss[3];
  float mean = tot * (1.f/512);
  float var  = tot2 * (1.f/512) - mean*mean;
  float inv = rsqrtf(var + 1e-5f);
  u16* xo = xn + (size_t)row * 512;
  xo[t]     = f2b((v0-mean)*inv*w[t]     + b[t]);
  xo[t+256] = f2b((v1-mean)*inv*w[t+256] + b[t+256]);
}

// ---------------- weight transpose + cast ----------------
__global__ __launch_bounds__(256) void wcast_T(const float* __restrict__ W, u16* __restrict__ WT, int R, int C) {
  int idx = blockIdx.x*256 + threadIdx.x;
  if (idx >= R*C) return;
  int r = idx / C, c = idx - r*C;
  WT[(size_t)c*R + r] = f2b(W[idx]);
}

// ---------------- v transpose ----------------
__global__ __launch_bounds__(256) void vtrans(const u16* __restrict__ v, u16* __restrict__ vT) {
  __shared__ u16 tile[64][72];
  int bh = blockIdx.y, n0 = blockIdx.x * 64;
  int t = threadIdx.x;
  const u16* vb = v + ((size_t)bh*4096 + n0)*64;
  #pragma unroll
  for (int p = 0; p < 2; p++) {
    int c = t + p*256;
    int r = c >> 3, col = (c & 7)*8;
    *(uint4*)&tile[r][col] = *(const uint4*)&vb[(size_t)r*64 + col];
  }
  __syncthreads();
  #pragma unroll
  for (int p = 0; p < 2; p++) {
    int c = t + p*256;
    int d = c >> 3, ncol = (c & 7)*8;
    u16 tmp[8];
    #pragma unroll
    for (int j = 0; j < 8; j++) tmp[j] = tile[ncol + j][d];
    *(uint4*)&vT[((size_t)bh*64 + d)*4096 + n0 + ncol] = *(uint4*)tmp;
  }
}

// ---------------- 128x128 MFMA GEMM core, BK=32 + register prefetch ----------------
__device__ __forceinline__ void gemm128_pf(const u16* __restrict__ A, const u16* __restrict__ BT,
    int K, int ldA, int ldBT, int row0, int col0, u16* As, u16* Bs, f32x4 acc[4][4]) {
  int t = threadIdx.x, lane = t & 63, wid = t >> 6;
  int wr = (wid >> 1) * 64, wc = (wid & 1) * 64;
  int lr = lane & 15, lg = lane >> 4;
  int sr = t >> 2, sc = (t & 3) * 8;
  const u16* Ar0 = A  + (size_t)(row0 + sr)*ldA + sc;
  const u16* Ar1 = A  + (size_t)(row0 + sr + 64)*ldA + sc;
  const u16* Br0 = BT + (size_t)(col0 + sr)*ldBT + sc;
  const u16* Br1 = BT + (size_t)(col0 + sr + 64)*ldBT + sc;
  uint4 pa0 = *(const uint4*)Ar0, pa1 = *(const uint4*)Ar1;
  uint4 pb0 = *(const uint4*)Br0, pb1 = *(const uint4*)Br1;
  for (int k0 = 0; k0 < K; k0 += 32) {
    __syncthreads();
    *(uint4*)&As[sr*40 + sc]        = pa0;
    *(uint4*)&As[(sr + 64)*40 + sc] = pa1;
    *(uint4*)&Bs[sr*40 + sc]        = pb0;
    *(uint4*)&Bs[(sr + 64)*40 + sc] = pb1;
    __syncthreads();
    if (k0 + 32 < K) {
      pa0 = *(const uint4*)(Ar0 + k0 + 32);
      pa1 = *(const uint4*)(Ar1 + k0 + 32);
      pb0 = *(const uint4*)(Br0 + k0 + 32);
      pb1 = *(const uint4*)(Br1 + k0 + 32);
    }
    s16x8 af[4], bf[4];
    #pragma unroll
    for (int f = 0; f < 4; f++) {
      af[f] = *(s16x8*)&As[(wr + f*16 + lr)*40 + lg*8];
      bf[f] = *(s16x8*)&Bs[(wc + f*16 + lr)*40 + lg*8];
    }
    #pragma unroll
    for (int i = 0; i < 4; i++)
      #pragma unroll
      for (int j = 0; j < 4; j++)
        acc[i][j] = MFMA16(af[i], bf[j], acc[i][j]);
  }
}

// ---------------- 64x64 MFMA GEMM core (K=256) + register prefetch ----------------
__device__ __forceinline__ void gemm64_pf(const u16* __restrict__ Ab, const u16* __restrict__ Bb,
    int row0, int col0, u16* As, u16* Bs, f32x4 acc[2][2]) {
  int t = threadIdx.x, lane = t & 63, wid = t >> 6;
  int wr = (wid >> 1)*32, wc = (wid & 1)*32;
  int lr = lane & 15, lg = lane >> 4;
  int sr = t >> 2, sc = (t & 3)*8;
  const u16* Arow = Ab + (size_t)(row0 + sr)*256 + sc;
  const u16* Brow = Bb + (size_t)(col0 + sr)*256 + sc;
  uint4 pa = *(const uint4*)Arow;
  uint4 pb = *(const uint4*)Brow;
  for (int k0 = 0; k0 < 256; k0 += 32) {
    __syncthreads();
    *(uint4*)&As[sr*40 + sc] = pa;
    *(uint4*)&Bs[sr*40 + sc] = pb;
    __syncthreads();
    if (k0 + 32 < 256) {
      pa = *(const uint4*)(Arow + k0 + 32);
      pb = *(const uint4*)(Brow + k0 + 32);
    }
    s16x8 af[2], bf[2];
    #pragma unroll
    for (int f = 0; f < 2; f++) {
      af[f] = *(s16x8*)&As[(wr + f*16 + lr)*40 + lg*8];
      bf[f] = *(s16x8*)&Bs[(wc + f*16 + lr)*40 + lg*8];
    }
    #pragma unroll
    for (int i = 0; i < 2; i++)
      #pragma unroll
      for (int j = 0; j < 2; j++)
        acc[i][j] = MFMA16(af[i], bf[j], acc[i][j]);
  }
}

// ---------------- QKV (XCD-swizzled) ----------------
__global__ __launch_bounds__(256) void qkv_mfma(const u16* __restrict__ xn, const u16* __restrict__ wT,
    u16* __restrict__ q, u16* __restrict__ k, u16* __restrict__ v) {
  __shared__ u16 As[128*40], Bs[128*40];
  f32x4 acc[4][4];
  #pragma unroll
  for (int i = 0; i < 4; i++)
    #pragma unroll
    for (int j = 0; j < 4; j++) acc[i][j] = (f32x4)0.f;
  int bI = blockIdx.x;
  int job = (bI & 7)*192 + (bI >> 3);
  int row0 = (job / 12) * 128, col0 = (job % 12) * 128;
  gemm128_pf(xn, wT, 512, 512, 512, row0, col0, As, Bs, acc);
  int t = threadIdx.x, lane = t & 63, wid = t >> 6, lr = lane & 15, lg = lane >> 4;
  int wr = (wid >> 1)*64, wc = (wid & 1)*64;
  #pragma unroll
  for (int i = 0; i < 4; i++)
    #pragma unroll
    for (int j = 0; j < 4; j++)
      #pragma unroll
      for (int r = 0; r < 4; r++) {
        int row = row0 + wr + i*16 + lg*4 + r;
        int col = col0 + wc + j*16 + lr;
        float val = acc[i][j][r];
        int part = col >> 9, rem = col & 511, h = rem >> 6, d = rem & 63;
        int b = row >> 12, n = row & 4095;
        size_t bh = (size_t)(b*8 + h);
        size_t dst = (bh*4096 + n)*64 + d;
        if (part == 0)      q[dst] = f2b(val * 0.125f);
        else if (part == 1) k[dst] = f2b(val);
        else                v[dst] = f2b(val);
      }
}

// ---------------- out GEMM (XCD-swizzled) ----------------
__global__ __launch_bounds__(256) void out_mfma(const u16* __restrict__ outh, const u16* __restrict__ wT,
    const float* __restrict__ bo, const float* __restrict__ x, float* __restrict__ out) {
  __shared__ u16 As[128*40], Bs[128*40];
  f32x4 acc[4][4];
  #pragma unroll
  for (int i = 0; i < 4; i++)
    #pragma unroll
    for (int j = 0; j < 4; j++) acc[i][j] = (f32x4)0.f;
  int bI = blockIdx.x;
  int job = (bI & 7)*64 + (bI >> 3);
  int row0 = (job / 4) * 128, col0 = (job % 4) * 128;
  gemm128_pf(outh, wT, 512, 512, 512, row0, col0, As, Bs, acc);
  int t = threadIdx.x, lane = t & 63, wid = t >> 6, lr = lane & 15, lg = lane >> 4;
  int wr = (wid >> 1)*64, wc = (wid & 1)*64;
  #pragma unroll
  for (int i = 0; i < 4; i++)
    #pragma unroll
    for (int j = 0; j < 4; j++)
      #pragma unroll
      for (int r = 0; r < 4; r++) {
        int row = row0 + wr + i*16 + lg*4 + r;
        int col = col0 + wc + j*16 + lr;
        size_t idx = (size_t)row*512 + col;
        out[idx] = x[idx] + acc[i][j][r] + bo[col];
      }
}

// ---------------- pinv stage 1: P = a2 @ z ; write P, P^T, (7I-P)^T ----------------
__global__ __launch_bounds__(256) void pinv_s1(const u16* __restrict__ a2h, const u16* __restrict__ zcT,
    u16* __restrict__ xz, u16* __restrict__ xzT, u16* __restrict__ e1T) {
  __shared__ u16 As[64*40], Bs[64*40];
  size_t bb = (size_t)blockIdx.z << 16;
  f32x4 acc[2][2];
  #pragma unroll
  for (int i = 0; i < 2; i++) { acc[i][0] = (f32x4)0.f; acc[i][1] = (f32x4)0.f; }
  int row0 = blockIdx.y*64, col0 = blockIdx.x*64;
  gemm64_pf(a2h + bb, zcT + bb, row0, col0, As, Bs, acc);
  int t = threadIdx.x, lane = t & 63, wid = t >> 6, lr = lane & 15, lg = lane >> 4;
  int wr = (wid >> 1)*32, wc = (wid & 1)*32;
  #pragma unroll
  for (int i = 0; i < 2; i++)
    #pragma unroll
    for (int j = 0; j < 2; j++)
      #pragma unroll
      for (int r = 0; r < 4; r++) {
        int row = row0 + wr + i*16 + lg*4 + r;
        int col = col0 + wc + j*16 + lr;
        float c = acc[i][j][r];
        xz [bb + (size_t)row*256 + col] = f2b(c);
        xzT[bb + (size_t)col*256 + row] = f2b(c);
        e1T[bb + (size_t)col*256 + row] = f2b((row == col ? 7.f : 0.f) - c);
      }
}

// ---------------- pinv stage 2: z 0-31: e2T=(15I - P@e1)^T ; 32-63: W = z@P ----------------
__global__ __launch_bounds__(256) void pinv_s2(const u16* __restrict__ xz, const u16* __restrict__ e1T,
    const u16* __restrict__ zc, const u16* __restrict__ xzT,
    u16* __restrict__ e2T, u16* __restrict__ W) {
  __shared__ u16 As[64*40], Bs[64*40];
  int bz = blockIdx.z;
  bool isQ = bz < 32;
  size_t bb = (size_t)(isQ ? bz : bz - 32) << 16;
  const u16* Aptr = (isQ ? xz : zc) + bb;
  const u16* Bptr = (isQ ? e1T : xzT) + bb;
  f32x4 acc[2][2];
  #pragma unroll
  for (int i = 0; i < 2; i++) { acc[i][0] = (f32x4)0.f; acc[i][1] = (f32x4)0.f; }
  int row0 = blockIdx.y*64, col0 = blockIdx.x*64;
  gemm64_pf(Aptr, Bptr, row0, col0, As, Bs, acc);
  int t = threadIdx.x, lane = t & 63, wid = t >> 6, lr = lane & 15, lg = lane >> 4;
  int wr = (wid >> 1)*32, wc = (wid & 1)*32;
  #pragma unroll
  for (int i = 0; i < 2; i++)
    #pragma unroll
    for (int j = 0; j < 2; j++)
      #pragma unroll
      for (int r = 0; r < 4; r++) {
        int row = row0 + wr + i*16 + lg*4 + r;
        int col = col0 + wc + j*16 + lr;
        float c = acc[i][j][r];
        if (isQ) e2T[bb + (size_t)col*256 + row] = f2b((row == col ? 15.f : 0.f) - c);
        else     W  [bb + (size_t)row*256 + col] = f2b(c);
      }
}

// ---------------- pinv stage 3: zn = 3.25 z - 0.25 W@e2 ; write zn, zn^T ----------------
__global__ __launch_bounds__(256) void pinv_s3(const u16* __restrict__ W, const u16* __restrict__ e2T,
    const u16* __restrict__ zc, u16* __restrict__ zn, u16* __restrict__ znT) {
  __shared__ u16 As[64*40], Bs[64*40];
  size_t bb = (size_t)blockIdx.z << 16;
  f32x4 acc[2][2];
  #pragma unroll
  for (int i = 0; i < 2; i++) { acc[i][0] = (f32x4)0.f; acc[i][1] = (f32x4)0.f; }
  int row0 = blockIdx.y*64, col0 = blockIdx.x*64;
  gemm64_pf(W + bb, e2T + bb, row0, col0, As, Bs, acc);
  int t = threadIdx.x, lane = t & 63, wid = t >> 6, lr = lane & 15, lg = lane >> 4;
  int wr = (wid >> 1)*32, wc = (wid & 1)*32;
  #pragma unroll
  for (int i = 0; i < 2; i++)
    #pragma unroll
    for (int j = 0; j < 2; j++)
      #pragma unroll
      for (int r = 0; r < 4; r++) {
        int row = row0 + wr + i*16 + lg*4 + r;
        int col = col0 + wc + j*16 + lr;
        size_t idx = bb + (size_t)row*256 + col;
        float val = 3.25f*b2f(zc[idx]) - 0.25f*acc[i][j][r];
        zn [idx] = f2b(val);
        znT[bb + (size_t)col*256 + row] = f2b(val);
      }
}

// ---------------- batched 64x64-tile MFMA GEMM (final w2T), prefetch ----------------
__global__ __launch_bounds__(256) void bmm64(const u16* __restrict__ A, const u16* __restrict__ BT,
    u16* __restrict__ CT, int M, int N, int K) {
  __shared__ u16 As[64*40], Bs[64*40];
  int batch = blockIdx.z;
  const u16* Ab = A  + (size_t)batch*M*K;
  const u16* Bb = BT + (size_t)batch*N*K;
  int row0 = blockIdx.y*64, col0 = blockIdx.x*64;
  int t = threadIdx.x, lane = t & 63, wid = t >> 6, lr = lane & 15, lg = lane >> 4;
  int wr = (wid >> 1)*32, wc = (wid & 1)*32;
  int sr = t >> 2, sc = (t & 3)*8;
  const u16* Arow = Ab + (size_t)(row0 + sr)*K + sc;
  const u16* Brow = Bb + (size_t)(col0 + sr)*K + sc;
  uint4 pa = *(const uint4*)Arow;
  uint4 pb = *(const uint4*)Brow;
  f32x4 acc[2][2];
  #pragma unroll
  for (int i = 0; i < 2; i++)
    #pragma unroll
    for (int j = 0; j < 2; j++) acc[i][j] = (f32x4)0.f;
  for (int k0 = 0; k0 < K; k0 += 32) {
    __syncthreads();
    *(uint4*)&As[sr*40 + sc] = pa;
    *(uint4*)&Bs[sr*40 + sc] = pb;
    __syncthreads();
    if (k0 + 32 < K) {
      pa = *(const uint4*)(Arow + k0 + 32);
      pb = *(const uint4*)(Brow + k0 + 32);
    }
    s16x8 af[2], bf[2];
    #pragma unroll
    for (int f = 0; f < 2; f++) {
      af[f] = *(s16x8*)&As[(wr + f*16 + lr)*40 + lg*8];
      bf[f] = *(s16x8*)&Bs[(wc + f*16 + lr)*40 + lg*8];
    }
    #pragma unroll
    for (int i = 0; i < 2; i++)
      #pragma unroll
      for (int j = 0; j < 2; j++)
        acc[i][j] = MFMA16(af[i], bf[j], acc[i][j]);
  }
  size_t cb = (size_t)batch*M*N;
  #pragma unroll
  for (int i = 0; i < 2; i++)
    #pragma unroll
    for (int j = 0; j < 2; j++)
      #pragma unroll
      for (int r = 0; r < 4; r++) {
        int row = row0 + wr + i*16 + lg*4 + r;
        int col = col0 + wc + j*16 + lr;
        CT[cb + (size_t)col*M + row] = f2b(acc[i][j][r]);
      }
}

// ---------------- landmarks ----------------
__global__ void landmark_kernel(const u16* __restrict__ q, const u16* __restrict__ k,
                                u16* __restrict__ ql, u16* __restrict__ kl) {
  int idx = blockIdx.x;
  int d = threadIdx.x;
  size_t base = ((size_t)idx * 16) * 64 + d;
  float sq = 0.f, sk = 0.f;
  #pragma unroll
  for (int j = 0; j < 16; j++) { sq += b2f(q[base + (size_t)j*64]); sk += b2f(k[base + (size_t)j*64]); }
  ql[(size_t)idx*64 + d] = f2b(sq * (1.f/16.f));
  kl[(size_t)idx*64 + d] = f2b(sk * (1.f/16.f));
}

// ---------------- sim2 (split): rows rq*64..+64 of one bh; partial colsums to pcs ----------------
__global__ __launch_bounds__(256) void sim2_mfma(const u16* __restrict__ ql, const u16* __restrict__ kl,
    float* __restrict__ a2, u16* __restrict__ a2h, float* __restrict__ pcs) {
  __shared__ u16 Qs[64*72];
  __shared__ u16 Ks2[256*72];
  __shared__ float wcol[4*256];
  int rq = blockIdx.x, bh = blockIdx.y;
  int t = threadIdx.x, lane = t & 63, wid = t >> 6, lr = lane & 15, lg = lane >> 4;
  #pragma unroll
  for (int p = 0; p < 2; p++) {
    int c = t + p*256;
    int r = c >> 3, col = (c & 7)*8;
    *(uint4*)&Qs[r*72 + col] = *(const uint4*)&ql[((size_t)bh*256 + rq*64 + r)*64 + col];
  }
  #pragma unroll
  for (int p = 0; p < 8; p++) {
    int c = t + p*256;
    int r = c >> 3, col = (c & 7)*8;
    *(uint4*)&Ks2[r*72 + col] = *(const uint4*)&kl[((size_t)bh*256 + r)*64 + col];
  }
  __syncthreads();
  float colp[16];
  #pragma unroll
  for (int cf = 0; cf < 16; cf++) colp[cf] = 0.f;
  int rbase = wid*16;
  s16x8 a0 = *(s16x8*)&Qs[(rbase + lr)*72 + lg*8];
  s16x8 a1 = *(s16x8*)&Qs[(rbase + lr)*72 + 32 + lg*8];
  f32x4 sf[16];
  #pragma unroll
  for (int cf = 0; cf < 16; cf++) {
    s16x8 b0 = *(s16x8*)&Ks2[(cf*16 + lr)*72 + lg*8];
    s16x8 b1 = *(s16x8*)&Ks2[(cf*16 + lr)*72 + 32 + lg*8];
    sf[cf] = MFMA16(a1, b1, MFMA16(a0, b0, (f32x4)0.f));
  }
  #pragma unroll
  for (int r = 0; r < 4; r++) {
    float mx = -3e38f;
    #pragma unroll
    for (int cf = 0; cf < 16; cf++) mx = fmaxf(mx, sf[cf][r]);
    #pragma unroll
    for (int o = 1; o < 16; o <<= 1) mx = fmaxf(mx, __shfl_xor(mx, o));
    float sum = 0.f;
    #pragma unroll
    for (int cf = 0; cf < 16; cf++) { sf[cf][r] = __expf(sf[cf][r] - mx); sum += sf[cf][r]; }
    #pragma unroll
    for (int o = 1; o < 16; o <<= 1) sum += __shfl_xor(sum, o);
    float inv = 1.f / sum;
    int row = rq*64 + rbase + lg*4 + r;
    size_t base = (size_t)bh*65536 + (size_t)row*256;
    #pragma unroll
    for (int cf = 0; cf < 16; cf++) {
      float pp = sf[cf][r] * inv;
      a2[base + cf*16 + lr] = pp;
      a2h[base + cf*16 + lr] = f2b(pp);
      colp[cf] += pp;
    }
  }
  #pragma unroll
  for (int cf = 0; cf < 16; cf++) {
    colp[cf] += __shfl_xor(colp[cf], 16);
    colp[cf] += __shfl_xor(colp[cf], 32);
  }
  if (lg == 0) {
    #pragma unroll
    for (int cf = 0; cf < 16; cf++) wcol[wid*256 + cf*16 + lr] = colp[cf];
  }
  __syncthreads();
  pcs[((size_t)bh*4 + rq)*256 + t] = wcol[t] + wcol[256 + t] + wcol[512 + t] + wcol[768 + t];
}

// ---------------- colmax: max over column sums ----------------
__global__ __launch_bounds__(256) void colmax_kernel(const float* __restrict__ pcs, unsigned* __restrict__ scal) {
  __shared__ float red[256];
  int bh = blockIdx.x, t = threadIdx.x;
  size_t b4 = (size_t)bh*4*256;
  red[t] = pcs[b4 + t] + pcs[b4 + 256 + t] + pcs[b4 + 512 + t] + pcs[b4 + 768 + t];
  __syncthreads();
  for (int o = 128; o > 0; o >>= 1) {
    if (t < o) red[t] = fmaxf(red[t], red[t+o]);
    __syncthreads();
  }
  if (t == 0) atomicMax(scal + 1, __float_as_uint(red[0]));
}

// ---------------- z0 = a2^T / colmax ----------------
__global__ void z0_kernel(const float* __restrict__ a2, const unsigned* __restrict__ scal,
                          u16* __restrict__ zA, u16* __restrict__ zAT) {
  size_t idx = (size_t)blockIdx.x*256 + threadIdx.x;
  float inv = 1.f / __uint_as_float(scal[1]);
  size_t bh = idx >> 16; int rem = (int)(idx & 65535); int i = rem >> 8, j = rem & 255;
  zA[idx]  = f2b(a2[(bh<<16) + ((size_t)j<<8) + i] * inv);
  zAT[idx] = f2b(a2[idx] * inv);
}

// ---------------- split-K flash partials (prefetch, 2 barriers/iter) ----------------
__global__ __launch_bounds__(256) void flash_part(const u16* __restrict__ Q, const u16* __restrict__ Kg,
    const u16* __restrict__ VT, float* __restrict__ po, float* __restrict__ pm, float* __restrict__ pl) {
  __shared__ u16 Ks[64*72];
  __shared__ u16 Vs[64*72];
  __shared__ u16 Ps[4*16*72];
  int qt = blockIdx.x, ch = blockIdx.y, bh = blockIdx.z;
  int q0 = qt * 64;
  int t = threadIdx.x, lane = t & 63, wid = t >> 6, lr = lane & 15, lg = lane >> 4;
  const u16* Qb  = Q  + ((size_t)bh*256)*64;
  const u16* Kb  = Kg + ((size_t)bh*4096 + ch*512)*64;
  const u16* VTb = VT + ((size_t)bh*64)*4096 + ch*512;
  int qrow = q0 + wid*16 + lr;
  s16x8 aq0 = *(const s16x8*)&Qb[(size_t)qrow*64 + lg*8];
  s16x8 aq1 = *(const s16x8*)&Qb[(size_t)qrow*64 + 32 + lg*8];
  f32x4 oacc[4];
  #pragma unroll
  for (int f = 0; f < 4; f++) oacc[f] = (f32x4)0.f;
  float m_[4] = {-3e38f, -3e38f, -3e38f, -3e38f};
  float l_[4] = {0.f, 0.f, 0.f, 0.f};
  u16* Pw = Ps + wid*16*72;
  uint4 pk[2], pv[2];
  #pragma unroll
  for (int p = 0; p < 2; p++) {
    int c = t + p*256; int r = c >> 3, cc = (c & 7)*8;
    pk[p] = *(const uint4*)&Kb[(size_t)r*64 + cc];
    pv[p] = *(const uint4*)&VTb[(size_t)r*4096 + cc];
  }
  for (int k0 = 0; k0 < 512; k0 += 64) {
    __syncthreads();
    #pragma unroll
    for (int p = 0; p < 2; p++) {
      int c = t + p*256; int r = c >> 3, cc = (c & 7)*8;
      *(uint4*)&Ks[r*72 + cc] = pk[p];
      *(uint4*)&Vs[r*72 + cc] = pv[p];
    }
    __syncthreads();
    if (k0 + 64 < 512) {
      #pragma unroll
      for (int p = 0; p < 2; p++) {
        int c = t + p*256; int r = c >> 3, cc = (c & 7)*8;
        pk[p] = *(const uint4*)&Kb[(size_t)(k0 + 64 + r)*64 + cc];
        pv[p] = *(const uint4*)&VTb[(size_t)r*4096 + k0 + 64 + cc];
      }
    }
    f32x4 sf[4];
    #pragma unroll
    for (int f = 0; f < 4; f++) {
      s16x8 b0 = *(s16x8*)&Ks[(f*16 + lr)*72 + lg*8];
      s16x8 b1 = *(s16x8*)&Ks[(f*16 + lr)*72 + 32 + lg*8];
      f32x4 s = (f32x4)0.f;
      s = MFMA16(aq0, b0, s);
      s = MFMA16(aq1, b1, s);
      sf[f] = s;
    }
    #pragma unroll
    for (int r = 0; r < 4; r++) {
      float mx = fmaxf(fmaxf(sf[0][r], sf[1][r]), fmaxf(sf[2][r], sf[3][r]));
      #pragma unroll
      for (int o = 1; o < 16; o <<= 1) mx = fmaxf(mx, __shfl_xor(mx, o));
      float mn = fmaxf(m_[r], mx);
      float sum = 0.f;
      #pragma unroll
      for (int f = 0; f < 4; f++) {
        float pv2 = __expf(sf[f][r] - mn);
        sum += pv2;
        Pw[(lg*4 + r)*72 + f*16 + lr] = f2b(pv2);
      }
      #pragma unroll
      for (int o = 1; o < 16; o <<= 1) sum += __shfl_xor(sum, o);
      float sc = __expf(m_[r] - mn);
      l_[r] = l_[r]*sc + sum;
      m_[r] = mn;
      #pragma unroll
      for (int f = 0; f < 4; f++) oacc[f][r] *= sc;
    }
    // P is per-wave: no cross-wave barrier needed before PV
    #pragma unroll
    for (int ks = 0; ks < 2; ks++) {
      s16x8 ap = *(s16x8*)&Pw[lr*72 + ks*32 + lg*8];
      #pragma unroll
      for (int df = 0; df < 4; df++) {
        s16x8 bv = *(s16x8*)&Vs[(df*16 + lr)*72 + ks*32 + lg*8];
        oacc[df] = MFMA16(ap, bv, oacc[df]);
      }
    }
  }
  int pidx = (bh*4 + qt)*8 + ch;
  #pragma unroll
  for (int r = 0; r < 4; r++) {
    int lrow = wid*16 + lg*4 + r;
    if (lr == 0) { pm[pidx*64 + lrow] = m_[r]; pl[pidx*64 + lrow] = l_[r]; }
    #pragma unroll
    for (int df = 0; df < 4; df++)
      po[((size_t)pidx*64 + lrow)*64 + df*16 + lr] = oacc[df][r];
  }
}

// ---------------- merge partials ----------------
__global__ __launch_bounds__(256) void flash_merge(const float* __restrict__ po, const float* __restrict__ pm,
    const float* __restrict__ pl, u16* __restrict__ a3vT) {
  int row = blockIdx.x*4 + (threadIdx.x >> 6);
  int d = threadIdx.x & 63;
  int bh = row >> 8, qrow = row & 255, qt = qrow >> 6, lrow = qrow & 63;
  int pbase = (bh*4 + qt)*8;
  float m = -3e38f;
  #pragma unroll
  for (int ch = 0; ch < 8; ch++) m = fmaxf(m, pm[(pbase+ch)*64 + lrow]);
  float L = 0.f, O = 0.f;
  #pragma unroll
  for (int ch = 0; ch < 8; ch++) {
    float w = __expf(pm[(pbase+ch)*64 + lrow] - m);
    L += w * pl[(pbase+ch)*64 + lrow];
    O += w * po[((size_t)(pbase+ch)*64 + lrow)*64 + d];
  }
  a3vT[((size_t)bh*64 + d)*256 + qrow] = f2b(O / L);
}

// ---------------- exact-softmax flash: outh = softmax(q @ kl^T) @ w2 ----------------
__global__ __launch_bounds__(256) void flash_a1(const u16* __restrict__ Q, const u16* __restrict__ Kl,
    const u16* __restrict__ W2T, u16* __restrict__ outh) {
  __shared__ u16 Ks[64*72];
  __shared__ u16 Vs[64*264];
  __shared__ u16 Ps[4*16*264];
  int bh = blockIdx.y;
  int q0 = blockIdx.x * 64;
  int t = threadIdx.x, lane = t & 63, wid = t >> 6, lr = lane & 15, lg = lane >> 4;
  const u16* Qb = Q + ((size_t)bh*4096)*64;
  #pragma unroll
  for (int p = 0; p < 8; p++) {
    int c = t + p*256; int r = c >> 5, col = (c & 31)*8;
    *(uint4*)&Vs[r*264 + col] = *(const uint4*)&W2T[((size_t)bh*64 + r)*256 + col];
  }
  int qrow = q0 + wid*16 + lr;
  s16x8 aq0 = *(const s16x8*)&Qb[(size_t)qrow*64 + lg*8];
  s16x8 aq1 = *(const s16x8*)&Qb[(size_t)qrow*64 + 32 + lg*8];
  f32x4 sf[16];
  #pragma unroll
  for (int f = 0; f < 16; f++) sf[f] = (f32x4)0.f;
  #pragma unroll
  for (int kt = 0; kt < 4; kt++) {
    __syncthreads();
    #pragma unroll
    for (int p = 0; p < 2; p++) {
      int c = t + p*256; int r = c >> 3, cc = (c & 7)*8;
      *(uint4*)&Ks[r*72 + cc] = *(const uint4*)&Kl[((size_t)bh*256 + kt*64 + r)*64 + cc];
    }
    __syncthreads();
    #pragma unroll
    for (int f2 = 0; f2 < 4; f2++) {
      s16x8 b0 = *(s16x8*)&Ks[(f2*16 + lr)*72 + lg*8];
      s16x8 b1 = *(s16x8*)&Ks[(f2*16 + lr)*72 + 32 + lg*8];
      sf[kt*4 + f2] = MFMA16(aq1, b1, MFMA16(aq0, b0, sf[kt*4 + f2]));
    }
  }
  u16* Pw = Ps + wid*16*264;
  float linv[4];
  #pragma unroll
  for (int r = 0; r < 4; r++) {
    float mx = -3e38f;
    #pragma unroll
    for (int f = 0; f < 16; f++) mx = fmaxf(mx, sf[f][r]);
    #pragma unroll
    for (int o = 1; o < 16; o <<= 1) mx = fmaxf(mx, __shfl_xor(mx, o));
    float sum = 0.f;
    #pragma unroll
    for (int f = 0; f < 16; f++) {
      float pv = __expf(sf[f][r] - mx);
      sum += pv;
      Pw[(lg*4 + r)*264 + f*16 + lr] = f2b(pv);
    }
    #pragma unroll
    for (int o = 1; o < 16; o <<= 1) sum += __shfl_xor(sum, o);
    linv[r] = 1.f / sum;
  }
  f32x4 oacc[4];
  #pragma unroll
  for (int f = 0; f < 4; f++) oacc[f] = (f32x4)0.f;
  #pragma unroll
  for (int ks = 0; ks < 8; ks++) {
    s16x8 ap = *(s16x8*)&Pw[lr*264 + ks*32 + lg*8];
    #pragma unroll
    for (int df = 0; df < 4; df++) {
      s16x8 bv = *(s16x8*)&Vs[(df*16 + lr)*264 + ks*32 + lg*8];
      oacc[df] = MFMA16(ap, bv, oacc[df]);
    }
  }
  int b = bh >> 3, h = bh & 7;
  #pragma unroll
  for (int df = 0; df < 4; df++)
    #pragma unroll
    for (int r = 0; r < 4; r++) {
      int lrow = wid*16 + lg*4 + r;
      int col = df*16 + lr;
      outh[((size_t)(b*4096 + q0 + lrow))*512 + h*64 + col] = f2b(oacc[df][r] * linv[r]);
    }
}

// ---------------- LDS-tiled residual depthwise conv ----------------
__global__ __launch_bounds__(256) void conv_lds(const u16* __restrict__ v, const float* __restrict__ rw,
                                                u16* __restrict__ outh) {
  __shared__ u16 tile[160*72];
  __shared__ float wsm[33];
  int bh = blockIdx.y;
  int n0 = blockIdx.x * 128;
  int b = bh >> 3, h = bh & 7;
  int t = threadIdx.x;
  if (t < 33) wsm[t] = rw[h*33 + t];
  const u16* vb = v + ((size_t)bh*4096)*64;
  #pragma unroll
  for (int p = 0; p < 5; p++) {
    int c = t + p*256;
    int r = c >> 3, col = (c & 7)*8;
    int nn = n0 - 16 + r;
    uint4 val = make_uint4(0u,0u,0u,0u);
    if (nn >= 0 && nn < 4096) val = *(const uint4*)&vb[(size_t)nn*64 + col];
    *(uint4*)&tile[r*72 + col] = val;
  }
  __syncthreads();
  int d8 = (t & 7) * 8;
  int r0 = t >> 3;
  #pragma unroll
  for (int pass = 0; pass < 4; pass++) {
    int lrow = pass*32 + r0;
    float acc[8] = {};
    #pragma unroll
    for (int j = 0; j < 33; j++) {
      uint4 vv = *(uint4*)&tile[(lrow + j)*72 + d8];
      float w = wsm[j];
      acc[0] += b2f((u16)(vv.x & 0xffff)) * w;
      acc[1] += b2f((u16)(vv.x >> 16))    * w;
      acc[2] += b2f((u16)(vv.y & 0xffff)) * w;
      acc[3] += b2f((u16)(vv.y >> 16))    * w;
      acc[4] += b2f((u16)(vv.z & 0xffff)) * w;
      acc[5] += b2f((u16)(vv.z >> 16))    * w;
      acc[6] += b2f((u16)(vv.w & 0xffff)) * w;
      acc[7] += b2f((u16)(vv.w >> 16))    * w;
    }
    size_t oi = ((size_t)(b*4096 + n0 + lrow))*512 + h*64 + d8;
    uint4 ov = *(uint4*)&outh[oi];
    uint4 nv;
    nv.x = (unsigned)f2b(b2f((u16)(ov.x & 0xffff)) + acc[0]) | ((unsigned)f2b(b2f((u16)(ov.x >> 16)) + acc[1]) << 16);
    nv.y = (unsigned)f2b(b2f((u16)(ov.y & 0xffff)) + acc[2]) | ((unsigned)f2b(b2f((u16)(ov.y >> 16)) + acc[3]) << 16);
    nv.z = (unsigned)f2b(b2f((u16)(ov.z & 0xffff)) + acc[4]) | ((unsigned)f2b(b2f((u16)(ov.z >> 16)) + acc[5]) << 16);
    nv.w = (unsigned)f2b(b2f((u16)(ov.w & 0xffff)) + acc[6]) | ((unsigned)f2b(b2f((u16)(ov.w >> 16)) + acc[7]) << 16);
    *(uint4*)&outh[oi] = nv;
  }
}

extern "C" void kernel_launch(void* const* d_in, const int* in_sizes, int n_in,
                              void* d_out, int out_size, void* d_ws, size_t ws_size,
                              hipStream_t stream) {
  const float* x      = (const float*)d_in[0];
  const float* norm_w = (const float*)d_in[1];
  const float* norm_b = (const float*)d_in[2];
  const float* w_qkv  = (const float*)d_in[3];
  const float* w_out  = (const float*)d_in[4];
  const float* b_out  = (const float*)d_in[5];
  const float* res_w  = (const float*)d_in[6];
  float* out = (float*)d_out;
  char* ws = (char*)d_ws;

  size_t off = 0;
  u16* xn    = (u16*)(ws + off); off += 16777216;
  u16* q     = (u16*)(ws + off); off += 16777216;
  u16* k     = (u16*)(ws + off); off += 16777216;
  u16* v     = (u16*)(ws + off); off += 16777216;
  u16* vT    = (u16*)(ws + off); off += 16777216;
  u16* ql    = (u16*)(ws + off); off += 1048576;
  u16* kl    = (u16*)(ws + off); off += 1048576;
  float* a2  = (float*)(ws + off); off += 8388608;
  u16* a2h   = (u16*)(ws + off); off += 4194304;
  u16* zA    = (u16*)(ws + off); off += 4194304;
  u16* zAT   = (u16*)(ws + off); off += 4194304;
  u16* zB    = (u16*)(ws + off); off += 4194304;
  u16* zBT   = (u16*)(ws + off); off += 4194304;
  u16* xz    = (u16*)(ws + off); off += 4194304;
  u16* xzT   = (u16*)(ws + off); off += 4194304;
  u16* e1T   = (u16*)(ws + off); off += 4194304;
  u16* e2T   = (u16*)(ws + off); off += 4194304;
  u16* Wm    = (u16*)(ws + off); off += 4194304;
  u16* a3vT  = (u16*)(ws + off); off += 1048576;
  u16* w2T   = (u16*)(ws + off); off += 1048576;
  u16* wqkvT = (u16*)(ws + off); off += 1572864;
  u16* woutT = (u16*)(ws + off); off += 524288;
  u16* outh  = (u16*)(ws + off); off += 16777216;
  float* po  = (float*)(ws + off); off += 16777216;
  float* pm  = (float*)(ws + off); off += 262144;
  float* pl  = (float*)(ws + off); off += 262144;
  float* pcs = (float*)(ws + off); off += 131072;
  unsigned* scal = (unsigned*)(ws + off); off += 8;

  ln_kernel<<<16384, 256, 0, stream>>>(x, norm_w, norm_b, xn);
  wcast_T<<<3072, 256, 0, stream>>>(w_qkv, wqkvT, 512, 1536);
  wcast_T<<<1024, 256, 0, stream>>>(w_out, woutT, 512, 512);
  qkv_mfma<<<1536, 256, 0, stream>>>(xn, wqkvT, q, k, v);
  vtrans<<<dim3(64, 32), 256, 0, stream>>>(v, vT);
  landmark_kernel<<<8192, 64, 0, stream>>>(q, k, ql, kl);
  hipMemsetAsync(scal, 0, 8, stream);
  sim2_mfma<<<dim3(4, 32), 256, 0, stream>>>(ql, kl, a2, a2h, pcs);
  colmax_kernel<<<32, 256, 0, stream>>>(pcs, scal);
  flash_part<<<dim3(4, 8, 32), 256, 0, stream>>>(ql, k, vT, po, pm, pl);
  flash_merge<<<2048, 256, 0, stream>>>(po, pm, pl, a3vT);
  z0_kernel<<<8192, 256, 0, stream>>>(a2, scal, zA, zAT);

  u16 *zc = zA, *zcT = zAT, *zn = zB, *znT = zBT;
  for (int it = 0; it < 6; it++) {
    pinv_s1<<<dim3(4,4,32), 256, 0, stream>>>(a2h, zcT, xz, xzT, e1T);
    pinv_s2<<<dim3(4,4,64), 256, 0, stream>>>(xz, e1T, zc, xzT, e2T, Wm);
    pinv_s3<<<dim3(4,4,32), 256, 0, stream>>>(Wm, e2T, zc, zn, znT);
    u16* tp;
    tp = zc; zc = zn; zn = tp;
    tp = zcT; zcT = znT; znT = tp;
  }

  bmm64<<<dim3(1,4,32), 256, 0, stream>>>(zc, a3vT, w2T, 256, 64, 256);
  flash_a1<<<dim3(64, 32), 256, 0, stream>>>(q, kl, w2T, outh);
  conv_lds<<<dim3(32, 32), 256, 0, stream>>>(v, res_w, outh);
  out_mfma<<<512, 256, 0, stream>>>(outh, woutT, b_out, x, out);
}

// Round 9
// 452.242 us; speedup vs baseline: 2.9050x; 1.0164x over previous
//
#include <hip/hip_runtime.h>
#include <math.h>

typedef unsigned short u16;
typedef short s16x8 __attribute__((ext_vector_type(8)));
typedef float f32x4 __attribute__((ext_vector_type(4)));

#define MFMA16(a, b, c) __builtin_amdgcn_mfma_f32_16x16x32_bf16((a), (b), (c), 0, 0, 0)

__device__ __forceinline__ u16 f2b(float f) {
  unsigned u = __float_as_uint(f);
  unsigned r = (u + 0x7fff + ((u >> 16) & 1)) >> 16;
  return (u16)r;
}
__device__ __forceinline__ float b2f(u16 h) { return __uint_as_float(((unsigned)h) << 16); }

// ---------------- LayerNorm -> bf16 ----------------
__global__ __launch_bounds__(256) void ln_kernel(const float* __restrict__ x, const float* __restrict__ w,
                          const float* __restrict__ b, u16* __restrict__ xn) {
  int row = blockIdx.x;
  const float* xr = x + (size_t)row * 512;
  int t = threadIdx.x;
  float v0 = xr[t], v1 = xr[t + 256];
  float s = v0 + v1, ss = v0*v0 + v1*v1;
  for (int o = 32; o > 0; o >>= 1) { s += __shfl_down(s, o); ss += __shfl_down(ss, o); }
  __shared__ float ls[4], lss[4];
  int wid = t >> 6, lane = t & 63;
  if (lane == 0) { ls[wid] = s; lss[wid] = ss; }
  __syncthreads();
  float tot  = ls[0]+ls[1]+ls[2]+ls[3];
  float tot2 = lss[0]+lss[1]+lss[2]+lss[3];
  float mean = tot * (1.f/512);
  float var  = tot2 * (1.f/512) - mean*mean;
  float inv = rsqrtf(var + 1e-5f);
  u16* xo = xn + (size_t)row * 512;
  xo[t]     = f2b((v0-mean)*inv*w[t]     + b[t]);
  xo[t+256] = f2b((v1-mean)*inv*w[t+256] + b[t+256]);
}

// ---------------- weight transpose + cast ----------------
__global__ __launch_bounds__(256) void wcast_T(const float* __restrict__ W, u16* __restrict__ WT, int R, int C) {
  int idx = blockIdx.x*256 + threadIdx.x;
  if (idx >= R*C) return;
  int r = idx / C, c = idx - r*C;
  WT[(size_t)c*R + r] = f2b(W[idx]);
}

// ---------------- v transpose ----------------
__global__ __launch_bounds__(256) void vtrans(const u16* __restrict__ v, u16* __restrict__ vT) {
  __shared__ u16 tile[64][72];
  int bh = blockIdx.y, n0 = blockIdx.x * 64;
  int t = threadIdx.x;
  const u16* vb = v + ((size_t)bh*4096 + n0)*64;
  #pragma unroll
  for (int p = 0; p < 2; p++) {
    int c = t + p*256;
    int r = c >> 3, col = (c & 7)*8;
    *(uint4*)&tile[r][col] = *(const uint4*)&vb[(size_t)r*64 + col];
  }
  __syncthreads();
  #pragma unroll
  for (int p = 0; p < 2; p++) {
    int c = t + p*256;
    int d = c >> 3, ncol = (c & 7)*8;
    u16 tmp[8];
    #pragma unroll
    for (int j = 0; j < 8; j++) tmp[j] = tile[ncol + j][d];
    *(uint4*)&vT[((size_t)bh*64 + d)*4096 + n0 + ncol] = *(uint4*)tmp;
  }
}

// ---------------- 128x128 MFMA GEMM core, BK=32 + register prefetch ----------------
__device__ __forceinline__ void gemm128_pf(const u16* __restrict__ A, const u16* __restrict__ BT,
    int K, int ldA, int ldBT, int row0, int col0, u16* As, u16* Bs, f32x4 acc[4][4]) {
  int t = threadIdx.x, lane = t & 63, wid = t >> 6;
  int wr = (wid >> 1) * 64, wc = (wid & 1) * 64;
  int lr = lane & 15, lg = lane >> 4;
  int sr = t >> 2, sc = (t & 3) * 8;
  const u16* Ar0 = A  + (size_t)(row0 + sr)*ldA + sc;
  const u16* Ar1 = A  + (size_t)(row0 + sr + 64)*ldA + sc;
  const u16* Br0 = BT + (size_t)(col0 + sr)*ldBT + sc;
  const u16* Br1 = BT + (size_t)(col0 + sr + 64)*ldBT + sc;
  uint4 pa0 = *(const uint4*)Ar0, pa1 = *(const uint4*)Ar1;
  uint4 pb0 = *(const uint4*)Br0, pb1 = *(const uint4*)Br1;
  for (int k0 = 0; k0 < K; k0 += 32) {
    __syncthreads();
    *(uint4*)&As[sr*40 + sc]        = pa0;
    *(uint4*)&As[(sr + 64)*40 + sc] = pa1;
    *(uint4*)&Bs[sr*40 + sc]        = pb0;
    *(uint4*)&Bs[(sr + 64)*40 + sc] = pb1;
    __syncthreads();
    if (k0 + 32 < K) {
      pa0 = *(const uint4*)(Ar0 + k0 + 32);
      pa1 = *(const uint4*)(Ar1 + k0 + 32);
      pb0 = *(const uint4*)(Br0 + k0 + 32);
      pb1 = *(const uint4*)(Br1 + k0 + 32);
    }
    s16x8 af[4], bf[4];
    #pragma unroll
    for (int f = 0; f < 4; f++) {
      af[f] = *(s16x8*)&As[(wr + f*16 + lr)*40 + lg*8];
      bf[f] = *(s16x8*)&Bs[(wc + f*16 + lr)*40 + lg*8];
    }
    #pragma unroll
    for (int i = 0; i < 4; i++)
      #pragma unroll
      for (int j = 0; j < 4; j++)
        acc[i][j] = MFMA16(af[i], bf[j], acc[i][j]);
  }
}

// ---------------- 64x64 MFMA GEMM core (K=256) + register prefetch ----------------
__device__ __forceinline__ void gemm64_pf(const u16* __restrict__ Ab, const u16* __restrict__ Bb,
    int row0, int col0, u16* As, u16* Bs, f32x4 acc[2][2]) {
  int t = threadIdx.x, lane = t & 63, wid = t >> 6;
  int wr = (wid >> 1)*32, wc = (wid & 1)*32;
  int lr = lane & 15, lg = lane >> 4;
  int sr = t >> 2, sc = (t & 3)*8;
  const u16* Arow = Ab + (size_t)(row0 + sr)*256 + sc;
  const u16* Brow = Bb + (size_t)(col0 + sr)*256 + sc;
  uint4 pa = *(const uint4*)Arow;
  uint4 pb = *(const uint4*)Brow;
  for (int k0 = 0; k0 < 256; k0 += 32) {
    __syncthreads();
    *(uint4*)&As[sr*40 + sc] = pa;
    *(uint4*)&Bs[sr*40 + sc] = pb;
    __syncthreads();
    if (k0 + 32 < 256) {
      pa = *(const uint4*)(Arow + k0 + 32);
      pb = *(const uint4*)(Brow + k0 + 32);
    }
    s16x8 af[2], bf[2];
    #pragma unroll
    for (int f = 0; f < 2; f++) {
      af[f] = *(s16x8*)&As[(wr + f*16 + lr)*40 + lg*8];
      bf[f] = *(s16x8*)&Bs[(wc + f*16 + lr)*40 + lg*8];
    }
    #pragma unroll
    for (int i = 0; i < 2; i++)
      #pragma unroll
      for (int j = 0; j < 2; j++)
        acc[i][j] = MFMA16(af[i], bf[j], acc[i][j]);
  }
}

// ---------------- QKV (XCD-swizzled) ----------------
__global__ __launch_bounds__(256, 4) void qkv_mfma(const u16* __restrict__ xn, const u16* __restrict__ wT,
    u16* __restrict__ q, u16* __restrict__ k, u16* __restrict__ v) {
  __shared__ u16 As[128*40], Bs[128*40];
  f32x4 acc[4][4];
  #pragma unroll
  for (int i = 0; i < 4; i++)
    #pragma unroll
    for (int j = 0; j < 4; j++) acc[i][j] = (f32x4)0.f;
  int bI = blockIdx.x;
  int job = (bI & 7)*192 + (bI >> 3);
  int row0 = (job / 12) * 128, col0 = (job % 12) * 128;
  gemm128_pf(xn, wT, 512, 512, 512, row0, col0, As, Bs, acc);
  int t = threadIdx.x, lane = t & 63, wid = t >> 6, lr = lane & 15, lg = lane >> 4;
  int wr = (wid >> 1)*64, wc = (wid & 1)*64;
  #pragma unroll
  for (int i = 0; i < 4; i++)
    #pragma unroll
    for (int j = 0; j < 4; j++)
      #pragma unroll
      for (int r = 0; r < 4; r++) {
        int row = row0 + wr + i*16 + lg*4 + r;
        int col = col0 + wc + j*16 + lr;
        float val = acc[i][j][r];
        int part = col >> 9, rem = col & 511, h = rem >> 6, d = rem & 63;
        int b = row >> 12, n = row & 4095;
        size_t bh = (size_t)(b*8 + h);
        size_t dst = (bh*4096 + n)*64 + d;
        if (part == 0)      q[dst] = f2b(val * 0.125f);
        else if (part == 1) k[dst] = f2b(val);
        else                v[dst] = f2b(val);
      }
}

// ---------------- out GEMM (XCD-swizzled) ----------------
__global__ __launch_bounds__(256, 4) void out_mfma(const u16* __restrict__ outh, const u16* __restrict__ wT,
    const float* __restrict__ bo, const float* __restrict__ x, float* __restrict__ out) {
  __shared__ u16 As[128*40], Bs[128*40];
  f32x4 acc[4][4];
  #pragma unroll
  for (int i = 0; i < 4; i++)
    #pragma unroll
    for (int j = 0; j < 4; j++) acc[i][j] = (f32x4)0.f;
  int bI = blockIdx.x;
  int job = (bI & 7)*64 + (bI >> 3);
  int row0 = (job / 4) * 128, col0 = (job % 4) * 128;
  gemm128_pf(outh, wT, 512, 512, 512, row0, col0, As, Bs, acc);
  int t = threadIdx.x, lane = t & 63, wid = t >> 6, lr = lane & 15, lg = lane >> 4;
  int wr = (wid >> 1)*64, wc = (wid & 1)*64;
  #pragma unroll
  for (int i = 0; i < 4; i++)
    #pragma unroll
    for (int j = 0; j < 4; j++)
      #pragma unroll
      for (int r = 0; r < 4; r++) {
        int row = row0 + wr + i*16 + lg*4 + r;
        int col = col0 + wc + j*16 + lr;
        size_t idx = (size_t)row*512 + col;
        out[idx] = x[idx] + acc[i][j][r] + bo[col];
      }
}

// ---------------- pinv stage 1: P = a2 @ z ; write P, P^T, (7I-P)^T ----------------
__global__ __launch_bounds__(256) void pinv_s1(const u16* __restrict__ a2h, const u16* __restrict__ zcT,
    u16* __restrict__ xz, u16* __restrict__ xzT, u16* __restrict__ e1T) {
  __shared__ u16 As[64*40], Bs[64*40];
  size_t bb = (size_t)blockIdx.z << 16;
  f32x4 acc[2][2];
  #pragma unroll
  for (int i = 0; i < 2; i++) { acc[i][0] = (f32x4)0.f; acc[i][1] = (f32x4)0.f; }
  int row0 = blockIdx.y*64, col0 = blockIdx.x*64;
  gemm64_pf(a2h + bb, zcT + bb, row0, col0, As, Bs, acc);
  int t = threadIdx.x, lane = t & 63, wid = t >> 6, lr = lane & 15, lg = lane >> 4;
  int wr = (wid >> 1)*32, wc = (wid & 1)*32;
  #pragma unroll
  for (int i = 0; i < 2; i++)
    #pragma unroll
    for (int j = 0; j < 2; j++)
      #pragma unroll
      for (int r = 0; r < 4; r++) {
        int row = row0 + wr + i*16 + lg*4 + r;
        int col = col0 + wc + j*16 + lr;
        float c = acc[i][j][r];
        xz [bb + (size_t)row*256 + col] = f2b(c);
        xzT[bb + (size_t)col*256 + row] = f2b(c);
        e1T[bb + (size_t)col*256 + row] = f2b((row == col ? 7.f : 0.f) - c);
      }
}

// ---------------- pinv stage 2: z 0-31: e2T=(15I - P@e1)^T ; 32-63: W = z@P ----------------
__global__ __launch_bounds__(256) void pinv_s2(const u16* __restrict__ xz, const u16* __restrict__ e1T,
    const u16* __restrict__ zc, const u16* __restrict__ xzT,
    u16* __restrict__ e2T, u16* __restrict__ W) {
  __shared__ u16 As[64*40], Bs[64*40];
  int bz = blockIdx.z;
  bool isQ = bz < 32;
  size_t bb = (size_t)(isQ ? bz : bz - 32) << 16;
  const u16* Aptr = (isQ ? xz : zc) + bb;
  const u16* Bptr = (isQ ? e1T : xzT) + bb;
  f32x4 acc[2][2];
  #pragma unroll
  for (int i = 0; i < 2; i++) { acc[i][0] = (f32x4)0.f; acc[i][1] = (f32x4)0.f; }
  int row0 = blockIdx.y*64, col0 = blockIdx.x*64;
  gemm64_pf(Aptr, Bptr, row0, col0, As, Bs, acc);
  int t = threadIdx.x, lane = t & 63, wid = t >> 6, lr = lane & 15, lg = lane >> 4;
  int wr = (wid >> 1)*32, wc = (wid & 1)*32;
  #pragma unroll
  for (int i = 0; i < 2; i++)
    #pragma unroll
    for (int j = 0; j < 2; j++)
      #pragma unroll
      for (int r = 0; r < 4; r++) {
        int row = row0 + wr + i*16 + lg*4 + r;
        int col = col0 + wc + j*16 + lr;
        float c = acc[i][j][r];
        if (isQ) e2T[bb + (size_t)col*256 + row] = f2b((row == col ? 15.f : 0.f) - c);
        else     W  [bb + (size_t)row*256 + col] = f2b(c);
      }
}

// ---------------- pinv stage 3: zn = 3.25 z - 0.25 W@e2 ; write zn, zn^T ----------------
__global__ __launch_bounds__(256) void pinv_s3(const u16* __restrict__ W, const u16* __restrict__ e2T,
    const u16* __restrict__ zc, u16* __restrict__ zn, u16* __restrict__ znT) {
  __shared__ u16 As[64*40], Bs[64*40];
  size_t bb = (size_t)blockIdx.z << 16;
  f32x4 acc[2][2];
  #pragma unroll
  for (int i = 0; i < 2; i++) { acc[i][0] = (f32x4)0.f; acc[i][1] = (f32x4)0.f; }
  int row0 = blockIdx.y*64, col0 = blockIdx.x*64;
  gemm64_pf(W + bb, e2T + bb, row0, col0, As, Bs, acc);
  int t = threadIdx.x, lane = t & 63, wid = t >> 6, lr = lane & 15, lg = lane >> 4;
  int wr = (wid >> 1)*32, wc = (wid & 1)*32;
  #pragma unroll
  for (int i = 0; i < 2; i++)
    #pragma unroll
    for (int j = 0; j < 2; j++)
      #pragma unroll
      for (int r = 0; r < 4; r++) {
        int row = row0 + wr + i*16 + lg*4 + r;
        int col = col0 + wc + j*16 + lr;
        size_t idx = bb + (size_t)row*256 + col;
        float val = 3.25f*b2f(zc[idx]) - 0.25f*acc[i][j][r];
        zn [idx] = f2b(val);
        znT[bb + (size_t)col*256 + row] = f2b(val);
      }
}

// ---------------- batched 64x64-tile MFMA GEMM (final w2T), prefetch ----------------
__global__ __launch_bounds__(256) void bmm64(const u16* __restrict__ A, const u16* __restrict__ BT,
    u16* __restrict__ CT, int M, int N, int K) {
  __shared__ u16 As[64*40], Bs[64*40];
  int batch = blockIdx.z;
  const u16* Ab = A  + (size_t)batch*M*K;
  const u16* Bb = BT + (size_t)batch*N*K;
  int row0 = blockIdx.y*64, col0 = blockIdx.x*64;
  int t = threadIdx.x, lane = t & 63, wid = t >> 6, lr = lane & 15, lg = lane >> 4;
  int wr = (wid >> 1)*32, wc = (wid & 1)*32;
  int sr = t >> 2, sc = (t & 3)*8;
  const u16* Arow = Ab + (size_t)(row0 + sr)*K + sc;
  const u16* Brow = Bb + (size_t)(col0 + sr)*K + sc;
  uint4 pa = *(const uint4*)Arow;
  uint4 pb = *(const uint4*)Brow;
  f32x4 acc[2][2];
  #pragma unroll
  for (int i = 0; i < 2; i++)
    #pragma unroll
    for (int j = 0; j < 2; j++) acc[i][j] = (f32x4)0.f;
  for (int k0 = 0; k0 < K; k0 += 32) {
    __syncthreads();
    *(uint4*)&As[sr*40 + sc] = pa;
    *(uint4*)&Bs[sr*40 + sc] = pb;
    __syncthreads();
    if (k0 + 32 < K) {
      pa = *(const uint4*)(Arow + k0 + 32);
      pb = *(const uint4*)(Brow + k0 + 32);
    }
    s16x8 af[2], bf[2];
    #pragma unroll
    for (int f = 0; f < 2; f++) {
      af[f] = *(s16x8*)&As[(wr + f*16 + lr)*40 + lg*8];
      bf[f] = *(s16x8*)&Bs[(wc + f*16 + lr)*40 + lg*8];
    }
    #pragma unroll
    for (int i = 0; i < 2; i++)
      #pragma unroll
      for (int j = 0; j < 2; j++)
        acc[i][j] = MFMA16(af[i], bf[j], acc[i][j]);
  }
  size_t cb = (size_t)batch*M*N;
  #pragma unroll
  for (int i = 0; i < 2; i++)
    #pragma unroll
    for (int j = 0; j < 2; j++)
      #pragma unroll
      for (int r = 0; r < 4; r++) {
        int row = row0 + wr + i*16 + lg*4 + r;
        int col = col0 + wc + j*16 + lr;
        CT[cb + (size_t)col*M + row] = f2b(acc[i][j][r]);
      }
}

// ---------------- landmarks ----------------
__global__ void landmark_kernel(const u16* __restrict__ q, const u16* __restrict__ k,
                                u16* __restrict__ ql, u16* __restrict__ kl) {
  int idx = blockIdx.x;
  int d = threadIdx.x;
  size_t base = ((size_t)idx * 16) * 64 + d;
  float sq = 0.f, sk = 0.f;
  #pragma unroll
  for (int j = 0; j < 16; j++) { sq += b2f(q[base + (size_t)j*64]); sk += b2f(k[base + (size_t)j*64]); }
  ql[(size_t)idx*64 + d] = f2b(sq * (1.f/16.f));
  kl[(size_t)idx*64 + d] = f2b(sk * (1.f/16.f));
}

// ---------------- sim2 (split): rows rq*64..+64 of one bh; partial colsums to pcs ----------------
__global__ __launch_bounds__(256, 4) void sim2_mfma(const u16* __restrict__ ql, const u16* __restrict__ kl,
    float* __restrict__ a2, u16* __restrict__ a2h, float* __restrict__ pcs) {
  __shared__ u16 Qs[64*72];
  __shared__ u16 Ks2[256*72];
  __shared__ float wcol[4*256];
  int rq = blockIdx.x, bh = blockIdx.y;
  int t = threadIdx.x, lane = t & 63, wid = t >> 6, lr = lane & 15, lg = lane >> 4;
  #pragma unroll
  for (int p = 0; p < 2; p++) {
    int c = t + p*256;
    int r = c >> 3, col = (c & 7)*8;
    *(uint4*)&Qs[r*72 + col] = *(const uint4*)&ql[((size_t)bh*256 + rq*64 + r)*64 + col];
  }
  #pragma unroll
  for (int p = 0; p < 8; p++) {
    int c = t + p*256;
    int r = c >> 3, col = (c & 7)*8;
    *(uint4*)&Ks2[r*72 + col] = *(const uint4*)&kl[((size_t)bh*256 + r)*64 + col];
  }
  __syncthreads();
  float colp[16];
  #pragma unroll
  for (int cf = 0; cf < 16; cf++) colp[cf] = 0.f;
  int rbase = wid*16;
  s16x8 a0 = *(s16x8*)&Qs[(rbase + lr)*72 + lg*8];
  s16x8 a1 = *(s16x8*)&Qs[(rbase + lr)*72 + 32 + lg*8];
  f32x4 sf[16];
  #pragma unroll
  for (int cf = 0; cf < 16; cf++) {
    s16x8 b0 = *(s16x8*)&Ks2[(cf*16 + lr)*72 + lg*8];
    s16x8 b1 = *(s16x8*)&Ks2[(cf*16 + lr)*72 + 32 + lg*8];
    sf[cf] = MFMA16(a1, b1, MFMA16(a0, b0, (f32x4)0.f));
  }
  #pragma unroll
  for (int r = 0; r < 4; r++) {
    float mx = -3e38f;
    #pragma unroll
    for (int cf = 0; cf < 16; cf++) mx = fmaxf(mx, sf[cf][r]);
    #pragma unroll
    for (int o = 1; o < 16; o <<= 1) mx = fmaxf(mx, __shfl_xor(mx, o));
    float sum = 0.f;
    #pragma unroll
    for (int cf = 0; cf < 16; cf++) { sf[cf][r] = __expf(sf[cf][r] - mx); sum += sf[cf][r]; }
    #pragma unroll
    for (int o = 1; o < 16; o <<= 1) sum += __shfl_xor(sum, o);
    float inv = 1.f / sum;
    int row = rq*64 + rbase + lg*4 + r;
    size_t base = (size_t)bh*65536 + (size_t)row*256;
    #pragma unroll
    for (int cf = 0; cf < 16; cf++) {
      float pp = sf[cf][r] * inv;
      a2[base + cf*16 + lr] = pp;
      a2h[base + cf*16 + lr] = f2b(pp);
      colp[cf] += pp;
    }
  }
  #pragma unroll
  for (int cf = 0; cf < 16; cf++) {
    colp[cf] += __shfl_xor(colp[cf], 16);
    colp[cf] += __shfl_xor(colp[cf], 32);
  }
  if (lg == 0) {
    #pragma unroll
    for (int cf = 0; cf < 16; cf++) wcol[wid*256 + cf*16 + lr] = colp[cf];
  }
  __syncthreads();
  pcs[((size_t)bh*4 + rq)*256 + t] = wcol[t] + wcol[256 + t] + wcol[512 + t] + wcol[768 + t];
}

// ---------------- colmax: max over column sums ----------------
__global__ __launch_bounds__(256) void colmax_kernel(const float* __restrict__ pcs, unsigned* __restrict__ scal) {
  __shared__ float red[256];
  int bh = blockIdx.x, t = threadIdx.x;
  size_t b4 = (size_t)bh*4*256;
  red[t] = pcs[b4 + t] + pcs[b4 + 256 + t] + pcs[b4 + 512 + t] + pcs[b4 + 768 + t];
  __syncthreads();
  for (int o = 128; o > 0; o >>= 1) {
    if (t < o) red[t] = fmaxf(red[t], red[t+o]);
    __syncthreads();
  }
  if (t == 0) atomicMax(scal + 1, __float_as_uint(red[0]));
}

// ---------------- z0 = a2^T / colmax ----------------
__global__ void z0_kernel(const float* __restrict__ a2, const unsigned* __restrict__ scal,
                          u16* __restrict__ zA, u16* __restrict__ zAT) {
  size_t idx = (size_t)blockIdx.x*256 + threadIdx.x;
  float inv = 1.f / __uint_as_float(scal[1]);
  size_t bh = idx >> 16; int rem = (int)(idx & 65535); int i = rem >> 8, j = rem & 255;
  zA[idx]  = f2b(a2[(bh<<16) + ((size_t)j<<8) + i] * inv);
  zAT[idx] = f2b(a2[idx] * inv);
}

// ---------------- split-K flash partials (prefetch, bf16 partials) ----------------
__global__ __launch_bounds__(256, 4) void flash_part(const u16* __restrict__ Q, const u16* __restrict__ Kg,
    const u16* __restrict__ VT, u16* __restrict__ po, float* __restrict__ pm, float* __restrict__ pl) {
  __shared__ u16 Ks[64*72];
  __shared__ u16 Vs[64*72];
  __shared__ u16 Ps[4*16*72];
  int qt = blockIdx.x, ch = blockIdx.y, bh = blockIdx.z;
  int q0 = qt * 64;
  int t = threadIdx.x, lane = t & 63, wid = t >> 6, lr = lane & 15, lg = lane >> 4;
  const u16* Qb  = Q  + ((size_t)bh*256)*64;
  const u16* Kb  = Kg + ((size_t)bh*4096 + ch*512)*64;
  const u16* VTb = VT + ((size_t)bh*64)*4096 + ch*512;
  int qrow = q0 + wid*16 + lr;
  s16x8 aq0 = *(const s16x8*)&Qb[(size_t)qrow*64 + lg*8];
  s16x8 aq1 = *(const s16x8*)&Qb[(size_t)qrow*64 + 32 + lg*8];
  f32x4 oacc[4];
  #pragma unroll
  for (int f = 0; f < 4; f++) oacc[f] = (f32x4)0.f;
  float m_[4] = {-3e38f, -3e38f, -3e38f, -3e38f};
  float l_[4] = {0.f, 0.f, 0.f, 0.f};
  u16* Pw = Ps + wid*16*72;
  uint4 pk[2], pv[2];
  #pragma unroll
  for (int p = 0; p < 2; p++) {
    int c = t + p*256; int r = c >> 3, cc = (c & 7)*8;
    pk[p] = *(const uint4*)&Kb[(size_t)r*64 + cc];
    pv[p] = *(const uint4*)&VTb[(size_t)r*4096 + cc];
  }
  for (int k0 = 0; k0 < 512; k0 += 64) {
    __syncthreads();
    #pragma unroll
    for (int p = 0; p < 2; p++) {
      int c = t + p*256; int r = c >> 3, cc = (c & 7)*8;
      *(uint4*)&Ks[r*72 + cc] = pk[p];
      *(uint4*)&Vs[r*72 + cc] = pv[p];
    }
    __syncthreads();
    if (k0 + 64 < 512) {
      #pragma unroll
      for (int p = 0; p < 2; p++) {
        int c = t + p*256; int r = c >> 3, cc = (c & 7)*8;
        pk[p] = *(const uint4*)&Kb[(size_t)(k0 + 64 + r)*64 + cc];
        pv[p] = *(const uint4*)&VTb[(size_t)r*4096 + k0 + 64 + cc];
      }
    }
    f32x4 sf[4];
    #pragma unroll
    for (int f = 0; f < 4; f++) {
      s16x8 b0 = *(s16x8*)&Ks[(f*16 + lr)*72 + lg*8];
      s16x8 b1 = *(s16x8*)&Ks[(f*16 + lr)*72 + 32 + lg*8];
      f32x4 s = (f32x4)0.f;
      s = MFMA16(aq0, b0, s);
      s = MFMA16(aq1, b1, s);
      sf[f] = s;
    }
    #pragma unroll
    for (int r = 0; r < 4; r++) {
      float mx = fmaxf(fmaxf(sf[0][r], sf[1][r]), fmaxf(sf[2][r], sf[3][r]));
      #pragma unroll
      for (int o = 1; o < 16; o <<= 1) mx = fmaxf(mx, __shfl_xor(mx, o));
      float mn = fmaxf(m_[r], mx);
      float sum = 0.f;
      #pragma unroll
      for (int f = 0; f < 4; f++) {
        float pv2 = __expf(sf[f][r] - mn);
        sum += pv2;
        Pw[(lg*4 + r)*72 + f*16 + lr] = f2b(pv2);
      }
      #pragma unroll
      for (int o = 1; o < 16; o <<= 1) sum += __shfl_xor(sum, o);
      float sc = __expf(m_[r] - mn);
      l_[r] = l_[r]*sc + sum;
      m_[r] = mn;
      #pragma unroll
      for (int f = 0; f < 4; f++) oacc[f][r] *= sc;
    }
    #pragma unroll
    for (int ks = 0; ks < 2; ks++) {
      s16x8 ap = *(s16x8*)&Pw[lr*72 + ks*32 + lg*8];
      #pragma unroll
      for (int df = 0; df < 4; df++) {
        s16x8 bv = *(s16x8*)&Vs[(df*16 + lr)*72 + ks*32 + lg*8];
        oacc[df] = MFMA16(ap, bv, oacc[df]);
      }
    }
  }
  int pidx = (bh*4 + qt)*8 + ch;
  #pragma unroll
  for (int r = 0; r < 4; r++) {
    int lrow = wid*16 + lg*4 + r;
    if (lr == 0) { pm[pidx*64 + lrow] = m_[r]; pl[pidx*64 + lrow] = l_[r]; }
    #pragma unroll
    for (int df = 0; df < 4; df++)
      po[((size_t)pidx*64 + lrow)*64 + df*16 + lr] = f2b(oacc[df][r]);
  }
}

// ---------------- merge partials (bf16 po, fp32 accumulate) ----------------
__global__ __launch_bounds__(256) void flash_merge(const u16* __restrict__ po, const float* __restrict__ pm,
    const float* __restrict__ pl, u16* __restrict__ a3vT) {
  int row = blockIdx.x*4 + (threadIdx.x >> 6);
  int d = threadIdx.x & 63;
  int bh = row >> 8, qrow = row & 255, qt = qrow >> 6, lrow = qrow & 63;
  int pbase = (bh*4 + qt)*8;
  float m = -3e38f;
  #pragma unroll
  for (int ch = 0; ch < 8; ch++) m = fmaxf(m, pm[(pbase+ch)*64 + lrow]);
  float L = 0.f, O = 0.f;
  #pragma unroll
  for (int ch = 0; ch < 8; ch++) {
    float w = __expf(pm[(pbase+ch)*64 + lrow] - m);
    L += w * pl[(pbase+ch)*64 + lrow];
    O += w * b2f(po[((size_t)(pbase+ch)*64 + lrow)*64 + d]);
  }
  a3vT[((size_t)bh*64 + d)*256 + qrow] = f2b(O / L);
}

// ---------------- exact-softmax flash: outh = softmax(q @ kl^T) @ w2 ----------------
__global__ __launch_bounds__(256, 4) void flash_a1(const u16* __restrict__ Q, const u16* __restrict__ Kl,
    const u16* __restrict__ W2T, u16* __restrict__ outh) {
  __shared__ u16 Ks[64*72];
  __shared__ u16 Vs[64*264];
  __shared__ u16 Ps[4*16*264];
  int bh = blockIdx.y;
  int q0 = blockIdx.x * 64;
  int t = threadIdx.x, lane = t & 63, wid = t >> 6, lr = lane & 15, lg = lane >> 4;
  const u16* Qb = Q + ((size_t)bh*4096)*64;
  #pragma unroll
  for (int p = 0; p < 8; p++) {
    int c = t + p*256; int r = c >> 5, col = (c & 31)*8;
    *(uint4*)&Vs[r*264 + col] = *(const uint4*)&W2T[((size_t)bh*64 + r)*256 + col];
  }
  int qrow = q0 + wid*16 + lr;
  s16x8 aq0 = *(const s16x8*)&Qb[(size_t)qrow*64 + lg*8];
  s16x8 aq1 = *(const s16x8*)&Qb[(size_t)qrow*64 + 32 + lg*8];
  f32x4 sf[16];
  #pragma unroll
  for (int f = 0; f < 16; f++) sf[f] = (f32x4)0.f;
  #pragma unroll
  for (int kt = 0; kt < 4; kt++) {
    __syncthreads();
    #pragma unroll
    for (int p = 0; p < 2; p++) {
      int c = t + p*256; int r = c >> 3, cc = (c & 7)*8;
      *(uint4*)&Ks[r*72 + cc] = *(const uint4*)&Kl[((size_t)bh*256 + kt*64 + r)*64 + cc];
    }
    __syncthreads();
    #pragma unroll
    for (int f2 = 0; f2 < 4; f2++) {
      s16x8 b0 = *(s16x8*)&Ks[(f2*16 + lr)*72 + lg*8];
      s16x8 b1 = *(s16x8*)&Ks[(f2*16 + lr)*72 + 32 + lg*8];
      sf[kt*4 + f2] = MFMA16(aq1, b1, MFMA16(aq0, b0, sf[kt*4 + f2]));
    }
  }
  u16* Pw = Ps + wid*16*264;
  float linv[4];
  #pragma unroll
  for (int r = 0; r < 4; r++) {
    float mx = -3e38f;
    #pragma unroll
    for (int f = 0; f < 16; f++) mx = fmaxf(mx, sf[f][r]);
    #pragma unroll
    for (int o = 1; o < 16; o <<= 1) mx = fmaxf(mx, __shfl_xor(mx, o));
    float sum = 0.f;
    #pragma unroll
    for (int f = 0; f < 16; f++) {
      float pv = __expf(sf[f][r] - mx);
      sum += pv;
      Pw[(lg*4 + r)*264 + f*16 + lr] = f2b(pv);
    }
    #pragma unroll
    for (int o = 1; o < 16; o <<= 1) sum += __shfl_xor(sum, o);
    linv[r] = 1.f / sum;
  }
  f32x4 oacc[4];
  #pragma unroll
  for (int f = 0; f < 4; f++) oacc[f] = (f32x4)0.f;
  #pragma unroll
  for (int ks = 0; ks < 8; ks++) {
    s16x8 ap = *(s16x8*)&Pw[lr*264 + ks*32 + lg*8];
    #pragma unroll
    for (int df = 0; df < 4; df++) {
      s16x8 bv = *(s16x8*)&Vs[(df*16 + lr)*264 + ks*32 + lg*8];
      oacc[df] = MFMA16(ap, bv, oacc[df]);
    }
  }
  int b = bh >> 3, h = bh & 7;
  #pragma unroll
  for (int df = 0; df < 4; df++)
    #pragma unroll
    for (int r = 0; r < 4; r++) {
      int lrow = wid*16 + lg*4 + r;
      int col = df*16 + lr;
      outh[((size_t)(b*4096 + q0 + lrow))*512 + h*64 + col] = f2b(oacc[df][r] * linv[r]);
    }
}

// ---------------- LDS-tiled residual depthwise conv ----------------
__global__ __launch_bounds__(256) void conv_lds(const u16* __restrict__ v, const float* __restrict__ rw,
                                                u16* __restrict__ outh) {
  __shared__ u16 tile[160*72];
  __shared__ float wsm[33];
  int bh = blockIdx.y;
  int n0 = blockIdx.x * 128;
  int b = bh >> 3, h = bh & 7;
  int t = threadIdx.x;
  if (t < 33) wsm[t] = rw[h*33 + t];
  const u16* vb = v + ((size_t)bh*4096)*64;
  #pragma unroll
  for (int p = 0; p < 5; p++) {
    int c = t + p*256;
    int r = c >> 3, col = (c & 7)*8;
    int nn = n0 - 16 + r;
    uint4 val = make_uint4(0u,0u,0u,0u);
    if (nn >= 0 && nn < 4096) val = *(const uint4*)&vb[(size_t)nn*64 + col];
    *(uint4*)&tile[r*72 + col] = val;
  }
  __syncthreads();
  int d8 = (t & 7) * 8;
  int r0 = t >> 3;
  #pragma unroll
  for (int pass = 0; pass < 4; pass++) {
    int lrow = pass*32 + r0;
    float acc[8] = {};
    #pragma unroll
    for (int j = 0; j < 33; j++) {
      uint4 vv = *(uint4*)&tile[(lrow + j)*72 + d8];
      float w = wsm[j];
      acc[0] += b2f((u16)(vv.x & 0xffff)) * w;
      acc[1] += b2f((u16)(vv.x >> 16))    * w;
      acc[2] += b2f((u16)(vv.y & 0xffff)) * w;
      acc[3] += b2f((u16)(vv.y >> 16))    * w;
      acc[4] += b2f((u16)(vv.z & 0xffff)) * w;
      acc[5] += b2f((u16)(vv.z >> 16))    * w;
      acc[6] += b2f((u16)(vv.w & 0xffff)) * w;
      acc[7] += b2f((u16)(vv.w >> 16))    * w;
    }
    size_t oi = ((size_t)(b*4096 + n0 + lrow))*512 + h*64 + d8;
    uint4 ov = *(uint4*)&outh[oi];
    uint4 nv;
    nv.x = (unsigned)f2b(b2f((u16)(ov.x & 0xffff)) + acc[0]) | ((unsigned)f2b(b2f((u16)(ov.x >> 16)) + acc[1]) << 16);
    nv.y = (unsigned)f2b(b2f((u16)(ov.y & 0xffff)) + acc[2]) | ((unsigned)f2b(b2f((u16)(ov.y >> 16)) + acc[3]) << 16);
    nv.z = (unsigned)f2b(b2f((u16)(ov.z & 0xffff)) + acc[4]) | ((unsigned)f2b(b2f((u16)(ov.z >> 16)) + acc[5]) << 16);
    nv.w = (unsigned)f2b(b2f((u16)(ov.w & 0xffff)) + acc[6]) | ((unsigned)f2b(b2f((u16)(ov.w >> 16)) + acc[7]) << 16);
    *(uint4*)&outh[oi] = nv;
  }
}

extern "C" void kernel_launch(void* const* d_in, const int* in_sizes, int n_in,
                              void* d_out, int out_size, void* d_ws, size_t ws_size,
                              hipStream_t stream) {
  const float* x      = (const float*)d_in[0];
  const float* norm_w = (const float*)d_in[1];
  const float* norm_b = (const float*)d_in[2];
  const float* w_qkv  = (const float*)d_in[3];
  const float* w_out  = (const float*)d_in[4];
  const float* b_out  = (const float*)d_in[5];
  const float* res_w  = (const float*)d_in[6];
  float* out = (float*)d_out;
  char* ws = (char*)d_ws;

  size_t off = 0;
  u16* xn    = (u16*)(ws + off); off += 16777216;
  u16* q     = (u16*)(ws + off); off += 16777216;
  u16* k     = (u16*)(ws + off); off += 16777216;
  u16* v     = (u16*)(ws + off); off += 16777216;
  u16* vT    = (u16*)(ws + off); off += 16777216;
  u16* ql    = (u16*)(ws + off); off += 1048576;
  u16* kl    = (u16*)(ws + off); off += 1048576;
  float* a2  = (float*)(ws + off); off += 8388608;
  u16* a2h   = (u16*)(ws + off); off += 4194304;
  u16* zA    = (u16*)(ws + off); off += 4194304;
  u16* zAT   = (u16*)(ws + off); off += 4194304;
  u16* zB    = (u16*)(ws + off); off += 4194304;
  u16* zBT   = (u16*)(ws + off); off += 4194304;
  u16* xz    = (u16*)(ws + off); off += 4194304;
  u16* xzT   = (u16*)(ws + off); off += 4194304;
  u16* e1T   = (u16*)(ws + off); off += 4194304;
  u16* e2T   = (u16*)(ws + off); off += 4194304;
  u16* Wm    = (u16*)(ws + off); off += 4194304;
  u16* a3vT  = (u16*)(ws + off); off += 1048576;
  u16* w2T   = (u16*)(ws + off); off += 1048576;
  u16* wqkvT = (u16*)(ws + off); off += 1572864;
  u16* woutT = (u16*)(ws + off); off += 524288;
  u16* outh  = (u16*)(ws + off); off += 16777216;
  u16* po    = (u16*)(ws + off); off += 8388608;   // bf16 partials now
  float* pm  = (float*)(ws + off); off += 262144;
  float* pl  = (float*)(ws + off); off += 262144;
  float* pcs = (float*)(ws + off); off += 131072;
  unsigned* scal = (unsigned*)(ws + off); off += 8;

  ln_kernel<<<16384, 256, 0, stream>>>(x, norm_w, norm_b, xn);
  wcast_T<<<3072, 256, 0, stream>>>(w_qkv, wqkvT, 512, 1536);
  wcast_T<<<1024, 256, 0, stream>>>(w_out, woutT, 512, 512);
  qkv_mfma<<<1536, 256, 0, stream>>>(xn, wqkvT, q, k, v);
  vtrans<<<dim3(64, 32), 256, 0, stream>>>(v, vT);
  landmark_kernel<<<8192, 64, 0, stream>>>(q, k, ql, kl);
  hipMemsetAsync(scal, 0, 8, stream);
  sim2_mfma<<<dim3(4, 32), 256, 0, stream>>>(ql, kl, a2, a2h, pcs);
  colmax_kernel<<<32, 256, 0, stream>>>(pcs, scal);
  flash_part<<<dim3(4, 8, 32), 256, 0, stream>>>(ql, k, vT, po, pm, pl);
  flash_merge<<<2048, 256, 0, stream>>>(po, pm, pl, a3vT);
  z0_kernel<<<8192, 256, 0, stream>>>(a2, scal, zA, zAT);

  u16 *zc = zA, *zcT = zAT, *zn = zB, *znT = zBT;
  for (int it = 0; it < 6; it++) {
    pinv_s1<<<dim3(4,4,32), 256, 0, stream>>>(a2h, zcT, xz, xzT, e1T);
    pinv_s2<<<dim3(4,4,64), 256, 0, stream>>>(xz, e1T, zc, xzT, e2T, Wm);
    pinv_s3<<<dim3(4,4,32), 256, 0, stream>>>(Wm, e2T, zc, zn, znT);
    u16* tp;
    tp = zc; zc = zn; zn = tp;
    tp = zcT; zcT = znT; znT = tp;
  }

  bmm64<<<dim3(1,4,32), 256, 0, stream>>>(zc, a3vT, w2T, 256, 64, 256);
  flash_a1<<<dim3(64, 32), 256, 0, stream>>>(q, kl, w2T, outh);
  conv_lds<<<dim3(32, 32), 256, 0, stream>>>(v, res_w, outh);
  out_mfma<<<512, 256, 0, stream>>>(outh, woutT, b_out, x, out);
}

// Round 10
// 442.726 us; speedup vs baseline: 2.9674x; 1.0215x over previous
//
#include <hip/hip_runtime.h>
#include <math.h>

typedef unsigned short u16;
typedef short s16x8 __attribute__((ext_vector_type(8)));
typedef float f32x4 __attribute__((ext_vector_type(4)));

#define MFMA16(a, b, c) __builtin_amdgcn_mfma_f32_16x16x32_bf16((a), (b), (c), 0, 0, 0)

__device__ __forceinline__ u16 f2b(float f) {
  unsigned u = __float_as_uint(f);
  unsigned r = (u + 0x7fff + ((u >> 16) & 1)) >> 16;
  return (u16)r;
}
__device__ __forceinline__ float b2f(u16 h) { return __uint_as_float(((unsigned)h) << 16); }

// ---------------- LayerNorm -> bf16 ----------------
__global__ __launch_bounds__(256) void ln_kernel(const float* __restrict__ x, const float* __restrict__ w,
                          const float* __restrict__ b, u16* __restrict__ xn) {
  int row = blockIdx.x;
  const float* xr = x + (size_t)row * 512;
  int t = threadIdx.x;
  float v0 = xr[t], v1 = xr[t + 256];
  float s = v0 + v1, ss = v0*v0 + v1*v1;
  for (int o = 32; o > 0; o >>= 1) { s += __shfl_down(s, o); ss += __shfl_down(ss, o); }
  __shared__ float ls[4], lss[4];
  int wid = t >> 6, lane = t & 63;
  if (lane == 0) { ls[wid] = s; lss[wid] = ss; }
  __syncthreads();
  float tot  = ls[0]+ls[1]+ls[2]+ls[3];
  float tot2 = lss[0]+lss[1]+lss[2]+lss[3];
  float mean = tot * (1.f/512);
  float var  = tot2 * (1.f/512) - mean*mean;
  float inv = rsqrtf(var + 1e-5f);
  u16* xo = xn + (size_t)row * 512;
  xo[t]     = f2b((v0-mean)*inv*w[t]     + b[t]);
  xo[t+256] = f2b((v1-mean)*inv*w[t+256] + b[t+256]);
}

// ---------------- weight transpose + cast ----------------
__global__ __launch_bounds__(256) void wcast_T(const float* __restrict__ W, u16* __restrict__ WT, int R, int C) {
  int idx = blockIdx.x*256 + threadIdx.x;
  if (idx >= R*C) return;
  int r = idx / C, c = idx - r*C;
  WT[(size_t)c*R + r] = f2b(W[idx]);
}

// ---------------- v transpose ----------------
__global__ __launch_bounds__(256) void vtrans(const u16* __restrict__ v, u16* __restrict__ vT) {
  __shared__ u16 tile[64][72];
  int bh = blockIdx.y, n0 = blockIdx.x * 64;
  int t = threadIdx.x;
  const u16* vb = v + ((size_t)bh*4096 + n0)*64;
  #pragma unroll
  for (int p = 0; p < 2; p++) {
    int c = t + p*256;
    int r = c >> 3, col = (c & 7)*8;
    *(uint4*)&tile[r][col] = *(const uint4*)&vb[(size_t)r*64 + col];
  }
  __syncthreads();
  #pragma unroll
  for (int p = 0; p < 2; p++) {
    int c = t + p*256;
    int d = c >> 3, ncol = (c & 7)*8;
    u16 tmp[8];
    #pragma unroll
    for (int j = 0; j < 8; j++) tmp[j] = tile[ncol + j][d];
    *(uint4*)&vT[((size_t)bh*64 + d)*4096 + n0 + ncol] = *(uint4*)tmp;
  }
}

// ---------------- 128x128 MFMA GEMM core, BK=32 + register prefetch ----------------
__device__ __forceinline__ void gemm128_pf(const u16* __restrict__ A, const u16* __restrict__ BT,
    int K, int ldA, int ldBT, int row0, int col0, u16* As, u16* Bs, f32x4 acc[4][4]) {
  int t = threadIdx.x, lane = t & 63, wid = t >> 6;
  int wr = (wid >> 1) * 64, wc = (wid & 1) * 64;
  int lr = lane & 15, lg = lane >> 4;
  int sr = t >> 2, sc = (t & 3) * 8;
  const u16* Ar0 = A  + (size_t)(row0 + sr)*ldA + sc;
  const u16* Ar1 = A  + (size_t)(row0 + sr + 64)*ldA + sc;
  const u16* Br0 = BT + (size_t)(col0 + sr)*ldBT + sc;
  const u16* Br1 = BT + (size_t)(col0 + sr + 64)*ldBT + sc;
  uint4 pa0 = *(const uint4*)Ar0, pa1 = *(const uint4*)Ar1;
  uint4 pb0 = *(const uint4*)Br0, pb1 = *(const uint4*)Br1;
  for (int k0 = 0; k0 < K; k0 += 32) {
    __syncthreads();
    *(uint4*)&As[sr*40 + sc]        = pa0;
    *(uint4*)&As[(sr + 64)*40 + sc] = pa1;
    *(uint4*)&Bs[sr*40 + sc]        = pb0;
    *(uint4*)&Bs[(sr + 64)*40 + sc] = pb1;
    __syncthreads();
    if (k0 + 32 < K) {
      pa0 = *(const uint4*)(Ar0 + k0 + 32);
      pa1 = *(const uint4*)(Ar1 + k0 + 32);
      pb0 = *(const uint4*)(Br0 + k0 + 32);
      pb1 = *(const uint4*)(Br1 + k0 + 32);
    }
    s16x8 af[4], bf[4];
    #pragma unroll
    for (int f = 0; f < 4; f++) {
      af[f] = *(s16x8*)&As[(wr + f*16 + lr)*40 + lg*8];
      bf[f] = *(s16x8*)&Bs[(wc + f*16 + lr)*40 + lg*8];
    }
    #pragma unroll
    for (int i = 0; i < 4; i++)
      #pragma unroll
      for (int j = 0; j < 4; j++)
        acc[i][j] = MFMA16(af[i], bf[j], acc[i][j]);
  }
}

// ---------------- 64x64 MFMA GEMM core (K=256) + register prefetch ----------------
__device__ __forceinline__ void gemm64_pf(const u16* __restrict__ Ab, const u16* __restrict__ Bb,
    int row0, int col0, u16* As, u16* Bs, f32x4 acc[2][2]) {
  int t = threadIdx.x, lane = t & 63, wid = t >> 6;
  int wr = (wid >> 1)*32, wc = (wid & 1)*32;
  int lr = lane & 15, lg = lane >> 4;
  int sr = t >> 2, sc = (t & 3)*8;
  const u16* Arow = Ab + (size_t)(row0 + sr)*256 + sc;
  const u16* Brow = Bb + (size_t)(col0 + sr)*256 + sc;
  uint4 pa = *(const uint4*)Arow;
  uint4 pb = *(const uint4*)Brow;
  for (int k0 = 0; k0 < 256; k0 += 32) {
    __syncthreads();
    *(uint4*)&As[sr*40 + sc] = pa;
    *(uint4*)&Bs[sr*40 + sc] = pb;
    __syncthreads();
    if (k0 + 32 < 256) {
      pa = *(const uint4*)(Arow + k0 + 32);
      pb = *(const uint4*)(Brow + k0 + 32);
    }
    s16x8 af[2], bf[2];
    #pragma unroll
    for (int f = 0; f < 2; f++) {
      af[f] = *(s16x8*)&As[(wr + f*16 + lr)*40 + lg*8];
      bf[f] = *(s16x8*)&Bs[(wc + f*16 + lr)*40 + lg*8];
    }
    #pragma unroll
    for (int i = 0; i < 2; i++)
      #pragma unroll
      for (int j = 0; j < 2; j++)
        acc[i][j] = MFMA16(af[i], bf[j], acc[i][j]);
  }
}

// ---------------- QKV (XCD-swizzled) ----------------
__global__ __launch_bounds__(256, 4) void qkv_mfma(const u16* __restrict__ xn, const u16* __restrict__ wT,
    u16* __restrict__ q, u16* __restrict__ k, u16* __restrict__ v) {
  __shared__ u16 As[128*40], Bs[128*40];
  f32x4 acc[4][4];
  #pragma unroll
  for (int i = 0; i < 4; i++)
    #pragma unroll
    for (int j = 0; j < 4; j++) acc[i][j] = (f32x4)0.f;
  int bI = blockIdx.x;
  int job = (bI & 7)*192 + (bI >> 3);
  int row0 = (job / 12) * 128, col0 = (job % 12) * 128;
  gemm128_pf(xn, wT, 512, 512, 512, row0, col0, As, Bs, acc);
  int t = threadIdx.x, lane = t & 63, wid = t >> 6, lr = lane & 15, lg = lane >> 4;
  int wr = (wid >> 1)*64, wc = (wid & 1)*64;
  #pragma unroll
  for (int i = 0; i < 4; i++)
    #pragma unroll
    for (int j = 0; j < 4; j++)
      #pragma unroll
      for (int r = 0; r < 4; r++) {
        int row = row0 + wr + i*16 + lg*4 + r;
        int col = col0 + wc + j*16 + lr;
        float val = acc[i][j][r];
        int part = col >> 9, rem = col & 511, h = rem >> 6, d = rem & 63;
        int b = row >> 12, n = row & 4095;
        size_t bh = (size_t)(b*8 + h);
        size_t dst = (bh*4096 + n)*64 + d;
        if (part == 0)      q[dst] = f2b(val * 0.125f);
        else if (part == 1) k[dst] = f2b(val);
        else                v[dst] = f2b(val);
      }
}

// ---------------- out GEMM (XCD-swizzled) ----------------
__global__ __launch_bounds__(256, 4) void out_mfma(const u16* __restrict__ outh, const u16* __restrict__ wT,
    const float* __restrict__ bo, const float* __restrict__ x, float* __restrict__ out) {
  __shared__ u16 As[128*40], Bs[128*40];
  f32x4 acc[4][4];
  #pragma unroll
  for (int i = 0; i < 4; i++)
    #pragma unroll
    for (int j = 0; j < 4; j++) acc[i][j] = (f32x4)0.f;
  int bI = blockIdx.x;
  int job = (bI & 7)*64 + (bI >> 3);
  int row0 = (job / 4) * 128, col0 = (job % 4) * 128;
  gemm128_pf(outh, wT, 512, 512, 512, row0, col0, As, Bs, acc);
  int t = threadIdx.x, lane = t & 63, wid = t >> 6, lr = lane & 15, lg = lane >> 4;
  int wr = (wid >> 1)*64, wc = (wid & 1)*64;
  #pragma unroll
  for (int i = 0; i < 4; i++)
    #pragma unroll
    for (int j = 0; j < 4; j++)
      #pragma unroll
      for (int r = 0; r < 4; r++) {
        int row = row0 + wr + i*16 + lg*4 + r;
        int col = col0 + wc + j*16 + lr;
        size_t idx = (size_t)row*512 + col;
        out[idx] = x[idx] + acc[i][j][r] + bo[col];
      }
}

// ---------------- pinv stage 1: P = a2 @ z ; write P, P^T, (7I-P)^T ----------------
__global__ __launch_bounds__(256) void pinv_s1(const u16* __restrict__ a2h, const u16* __restrict__ zcT,
    u16* __restrict__ xz, u16* __restrict__ xzT, u16* __restrict__ e1T) {
  __shared__ u16 As[64*40], Bs[64*40];
  size_t bb = (size_t)blockIdx.z << 16;
  f32x4 acc[2][2];
  #pragma unroll
  for (int i = 0; i < 2; i++) { acc[i][0] = (f32x4)0.f; acc[i][1] = (f32x4)0.f; }
  int row0 = blockIdx.y*64, col0 = blockIdx.x*64;
  gemm64_pf(a2h + bb, zcT + bb, row0, col0, As, Bs, acc);
  int t = threadIdx.x, lane = t & 63, wid = t >> 6, lr = lane & 15, lg = lane >> 4;
  int wr = (wid >> 1)*32, wc = (wid & 1)*32;
  #pragma unroll
  for (int i = 0; i < 2; i++)
    #pragma unroll
    for (int j = 0; j < 2; j++)
      #pragma unroll
      for (int r = 0; r < 4; r++) {
        int row = row0 + wr + i*16 + lg*4 + r;
        int col = col0 + wc + j*16 + lr;
        float c = acc[i][j][r];
        xz [bb + (size_t)row*256 + col] = f2b(c);
        xzT[bb + (size_t)col*256 + row] = f2b(c);
        e1T[bb + (size_t)col*256 + row] = f2b((row == col ? 7.f : 0.f) - c);
      }
}

// ---------------- pinv stage 2: z 0-31: e2T=(15I - P@e1)^T ; 32-63: W = z@P ----------------
__global__ __launch_bounds__(256) void pinv_s2(const u16* __restrict__ xz, const u16* __restrict__ e1T,
    const u16* __restrict__ zc, const u16* __restrict__ xzT,
    u16* __restrict__ e2T, u16* __restrict__ W) {
  __shared__ u16 As[64*40], Bs[64*40];
  int bz = blockIdx.z;
  bool isQ = bz < 32;
  size_t bb = (size_t)(isQ ? bz : bz - 32) << 16;
  const u16* Aptr = (isQ ? xz : zc) + bb;
  const u16* Bptr = (isQ ? e1T : xzT) + bb;
  f32x4 acc[2][2];
  #pragma unroll
  for (int i = 0; i < 2; i++) { acc[i][0] = (f32x4)0.f; acc[i][1] = (f32x4)0.f; }
  int row0 = blockIdx.y*64, col0 = blockIdx.x*64;
  gemm64_pf(Aptr, Bptr, row0, col0, As, Bs, acc);
  int t = threadIdx.x, lane = t & 63, wid = t >> 6, lr = lane & 15, lg = lane >> 4;
  int wr = (wid >> 1)*32, wc = (wid & 1)*32;
  #pragma unroll
  for (int i = 0; i < 2; i++)
    #pragma unroll
    for (int j = 0; j < 2; j++)
      #pragma unroll
      for (int r = 0; r < 4; r++) {
        int row = row0 + wr + i*16 + lg*4 + r;
        int col = col0 + wc + j*16 + lr;
        float c = acc[i][j][r];
        if (isQ) e2T[bb + (size_t)col*256 + row] = f2b((row == col ? 15.f : 0.f) - c);
        else     W  [bb + (size_t)row*256 + col] = f2b(c);
      }
}

// ---------------- pinv stage 3: zn = 3.25 z - 0.25 W@e2 ; write zn, zn^T ----------------
__global__ __launch_bounds__(256) void pinv_s3(const u16* __restrict__ W, const u16* __restrict__ e2T,
    const u16* __restrict__ zc, u16* __restrict__ zn, u16* __restrict__ znT) {
  __shared__ u16 As[64*40], Bs[64*40];
  size_t bb = (size_t)blockIdx.z << 16;
  f32x4 acc[2][2];
  #pragma unroll
  for (int i = 0; i < 2; i++) { acc[i][0] = (f32x4)0.f; acc[i][1] = (f32x4)0.f; }
  int row0 = blockIdx.y*64, col0 = blockIdx.x*64;
  gemm64_pf(W + bb, e2T + bb, row0, col0, As, Bs, acc);
  int t = threadIdx.x, lane = t & 63, wid = t >> 6, lr = lane & 15, lg = lane >> 4;
  int wr = (wid >> 1)*32, wc = (wid & 1)*32;
  #pragma unroll
  for (int i = 0; i < 2; i++)
    #pragma unroll
    for (int j = 0; j < 2; j++)
      #pragma unroll
      for (int r = 0; r < 4; r++) {
        int row = row0 + wr + i*16 + lg*4 + r;
        int col = col0 + wc + j*16 + lr;
        size_t idx = bb + (size_t)row*256 + col;
        float val = 3.25f*b2f(zc[idx]) - 0.25f*acc[i][j][r];
        zn [idx] = f2b(val);
        znT[bb + (size_t)col*256 + row] = f2b(val);
      }
}

// ---------------- batched 64x64-tile MFMA GEMM (final w2T), prefetch ----------------
__global__ __launch_bounds__(256) void bmm64(const u16* __restrict__ A, const u16* __restrict__ BT,
    u16* __restrict__ CT, int M, int N, int K) {
  __shared__ u16 As[64*40], Bs[64*40];
  int batch = blockIdx.z;
  const u16* Ab = A  + (size_t)batch*M*K;
  const u16* Bb = BT + (size_t)batch*N*K;
  int row0 = blockIdx.y*64, col0 = blockIdx.x*64;
  int t = threadIdx.x, lane = t & 63, wid = t >> 6, lr = lane & 15, lg = lane >> 4;
  int wr = (wid >> 1)*32, wc = (wid & 1)*32;
  int sr = t >> 2, sc = (t & 3)*8;
  const u16* Arow = Ab + (size_t)(row0 + sr)*K + sc;
  const u16* Brow = Bb + (size_t)(col0 + sr)*K + sc;
  uint4 pa = *(const uint4*)Arow;
  uint4 pb = *(const uint4*)Brow;
  f32x4 acc[2][2];
  #pragma unroll
  for (int i = 0; i < 2; i++)
    #pragma unroll
    for (int j = 0; j < 2; j++) acc[i][j] = (f32x4)0.f;
  for (int k0 = 0; k0 < K; k0 += 32) {
    __syncthreads();
    *(uint4*)&As[sr*40 + sc] = pa;
    *(uint4*)&Bs[sr*40 + sc] = pb;
    __syncthreads();
    if (k0 + 32 < K) {
      pa = *(const uint4*)(Arow + k0 + 32);
      pb = *(const uint4*)(Brow + k0 + 32);
    }
    s16x8 af[2], bf[2];
    #pragma unroll
    for (int f = 0; f < 2; f++) {
      af[f] = *(s16x8*)&As[(wr + f*16 + lr)*40 + lg*8];
      bf[f] = *(s16x8*)&Bs[(wc + f*16 + lr)*40 + lg*8];
    }
    #pragma unroll
    for (int i = 0; i < 2; i++)
      #pragma unroll
      for (int j = 0; j < 2; j++)
        acc[i][j] = MFMA16(af[i], bf[j], acc[i][j]);
  }
  size_t cb = (size_t)batch*M*N;
  #pragma unroll
  for (int i = 0; i < 2; i++)
    #pragma unroll
    for (int j = 0; j < 2; j++)
      #pragma unroll
      for (int r = 0; r < 4; r++) {
        int row = row0 + wr + i*16 + lg*4 + r;
        int col = col0 + wc + j*16 + lr;
        CT[cb + (size_t)col*M + row] = f2b(acc[i][j][r]);
      }
}

// ---------------- landmarks ----------------
__global__ void landmark_kernel(const u16* __restrict__ q, const u16* __restrict__ k,
                                u16* __restrict__ ql, u16* __restrict__ kl) {
  int idx = blockIdx.x;
  int d = threadIdx.x;
  size_t base = ((size_t)idx * 16) * 64 + d;
  float sq = 0.f, sk = 0.f;
  #pragma unroll
  for (int j = 0; j < 16; j++) { sq += b2f(q[base + (size_t)j*64]); sk += b2f(k[base + (size_t)j*64]); }
  ql[(size_t)idx*64 + d] = f2b(sq * (1.f/16.f));
  kl[(size_t)idx*64 + d] = f2b(sk * (1.f/16.f));
}

// ---------------- sim2 (split): rows rq*64..+64 of one bh; partial colsums to pcs ----------------
__global__ __launch_bounds__(256, 4) void sim2_mfma(const u16* __restrict__ ql, const u16* __restrict__ kl,
    float* __restrict__ a2, u16* __restrict__ a2h, float* __restrict__ pcs) {
  __shared__ u16 Qs[64*72];
  __shared__ u16 Ks2[256*72];
  __shared__ float wcol[4*256];
  int rq = blockIdx.x, bh = blockIdx.y;
  int t = threadIdx.x, lane = t & 63, wid = t >> 6, lr = lane & 15, lg = lane >> 4;
  #pragma unroll
  for (int p = 0; p < 2; p++) {
    int c = t + p*256;
    int r = c >> 3, col = (c & 7)*8;
    *(uint4*)&Qs[r*72 + col] = *(const uint4*)&ql[((size_t)bh*256 + rq*64 + r)*64 + col];
  }
  #pragma unroll
  for (int p = 0; p < 8; p++) {
    int c = t + p*256;
    int r = c >> 3, col = (c & 7)*8;
    *(uint4*)&Ks2[r*72 + col] = *(const uint4*)&kl[((size_t)bh*256 + r)*64 + col];
  }
  __syncthreads();
  float colp[16];
  #pragma unroll
  for (int cf = 0; cf < 16; cf++) colp[cf] = 0.f;
  int rbase = wid*16;
  s16x8 a0 = *(s16x8*)&Qs[(rbase + lr)*72 + lg*8];
  s16x8 a1 = *(s16x8*)&Qs[(rbase + lr)*72 + 32 + lg*8];
  f32x4 sf[16];
  #pragma unroll
  for (int cf = 0; cf < 16; cf++) {
    s16x8 b0 = *(s16x8*)&Ks2[(cf*16 + lr)*72 + lg*8];
    s16x8 b1 = *(s16x8*)&Ks2[(cf*16 + lr)*72 + 32 + lg*8];
    sf[cf] = MFMA16(a1, b1, MFMA16(a0, b0, (f32x4)0.f));
  }
  #pragma unroll
  for (int r = 0; r < 4; r++) {
    float mx = -3e38f;
    #pragma unroll
    for (int cf = 0; cf < 16; cf++) mx = fmaxf(mx, sf[cf][r]);
    #pragma unroll
    for (int o = 1; o < 16; o <<= 1) mx = fmaxf(mx, __shfl_xor(mx, o));
    float sum = 0.f;
    #pragma unroll
    for (int cf = 0; cf < 16; cf++) { sf[cf][r] = __expf(sf[cf][r] - mx); sum += sf[cf][r]; }
    #pragma unroll
    for (int o = 1; o < 16; o <<= 1) sum += __shfl_xor(sum, o);
    float inv = 1.f / sum;
    int row = rq*64 + rbase + lg*4 + r;
    size_t base = (size_t)bh*65536 + (size_t)row*256;
    #pragma unroll
    for (int cf = 0; cf < 16; cf++) {
      float pp = sf[cf][r] * inv;
      a2[base + cf*16 + lr] = pp;
      a2h[base + cf*16 + lr] = f2b(pp);
      colp[cf] += pp;
    }
  }
  #pragma unroll
  for (int cf = 0; cf < 16; cf++) {
    colp[cf] += __shfl_xor(colp[cf], 16);
    colp[cf] += __shfl_xor(colp[cf], 32);
  }
  if (lg == 0) {
    #pragma unroll
    for (int cf = 0; cf < 16; cf++) wcol[wid*256 + cf*16 + lr] = colp[cf];
  }
  __syncthreads();
  pcs[((size_t)bh*4 + rq)*256 + t] = wcol[t] + wcol[256 + t] + wcol[512 + t] + wcol[768 + t];
}

// ---------------- colmax: max over column sums ----------------
__global__ __launch_bounds__(256) void colmax_kernel(const float* __restrict__ pcs, unsigned* __restrict__ scal) {
  __shared__ float red[256];
  int bh = blockIdx.x, t = threadIdx.x;
  size_t b4 = (size_t)bh*4*256;
  red[t] = pcs[b4 + t] + pcs[b4 + 256 + t] + pcs[b4 + 512 + t] + pcs[b4 + 768 + t];
  __syncthreads();
  for (int o = 128; o > 0; o >>= 1) {
    if (t < o) red[t] = fmaxf(red[t], red[t+o]);
    __syncthreads();
  }
  if (t == 0) atomicMax(scal + 1, __float_as_uint(red[0]));
}

// ---------------- z0 = a2^T / colmax ----------------
__global__ void z0_kernel(const float* __restrict__ a2, const unsigned* __restrict__ scal,
                          u16* __restrict__ zA, u16* __restrict__ zAT) {
  size_t idx = (size_t)blockIdx.x*256 + threadIdx.x;
  float inv = 1.f / __uint_as_float(scal[1]);
  size_t bh = idx >> 16; int rem = (int)(idx & 65535); int i = rem >> 8, j = rem & 255;
  zA[idx]  = f2b(a2[(bh<<16) + ((size_t)j<<8) + i] * inv);
  zAT[idx] = f2b(a2[idx] * inv);
}

// ---------------- split-K flash partials: 2 q-tiles per block, K/V staged once ----------------
__global__ __launch_bounds__(256) void flash_part(const u16* __restrict__ Q, const u16* __restrict__ Kg,
    const u16* __restrict__ VT, u16* __restrict__ po, float* __restrict__ pm, float* __restrict__ pl) {
  __shared__ u16 Ks[64*72];
  __shared__ u16 Vs[64*72];
  __shared__ u16 Ps[4*16*72];
  int qg = blockIdx.x, ch = blockIdx.y, bh = blockIdx.z;
  int t = threadIdx.x, lane = t & 63, wid = t >> 6, lr = lane & 15, lg = lane >> 4;
  const u16* Qb  = Q  + ((size_t)bh*256)*64;
  const u16* Kb  = Kg + ((size_t)bh*4096 + ch*512)*64;
  const u16* VTb = VT + ((size_t)bh*64)*4096 + ch*512;
  // Q fragments for the block's two 64-row q-tiles (per-wave 16 rows each)
  s16x8 aq[2][2];
  #pragma unroll
  for (int qq = 0; qq < 2; qq++) {
    int qrow = (qg*2 + qq)*64 + wid*16 + lr;
    aq[qq][0] = *(const s16x8*)&Qb[(size_t)qrow*64 + lg*8];
    aq[qq][1] = *(const s16x8*)&Qb[(size_t)qrow*64 + 32 + lg*8];
  }
  f32x4 oacc[2][4];
  float m_[2][4], l_[2][4];
  #pragma unroll
  for (int qq = 0; qq < 2; qq++)
    #pragma unroll
    for (int f = 0; f < 4; f++) {
      oacc[qq][f] = (f32x4)0.f;
      m_[qq][f] = -3e38f;
      l_[qq][f] = 0.f;
    }
  u16* Pw = Ps + wid*16*72;
  uint4 pk[2], pv[2];
  #pragma unroll
  for (int p = 0; p < 2; p++) {
    int c = t + p*256; int r = c >> 3, cc = (c & 7)*8;
    pk[p] = *(const uint4*)&Kb[(size_t)r*64 + cc];
    pv[p] = *(const uint4*)&VTb[(size_t)r*4096 + cc];
  }
  for (int k0 = 0; k0 < 512; k0 += 64) {
    __syncthreads();
    #pragma unroll
    for (int p = 0; p < 2; p++) {
      int c = t + p*256; int r = c >> 3, cc = (c & 7)*8;
      *(uint4*)&Ks[r*72 + cc] = pk[p];
      *(uint4*)&Vs[r*72 + cc] = pv[p];
    }
    __syncthreads();
    if (k0 + 64 < 512) {
      #pragma unroll
      for (int p = 0; p < 2; p++) {
        int c = t + p*256; int r = c >> 3, cc = (c & 7)*8;
        pk[p] = *(const uint4*)&Kb[(size_t)(k0 + 64 + r)*64 + cc];
        pv[p] = *(const uint4*)&VTb[(size_t)r*4096 + k0 + 64 + cc];
      }
    }
    #pragma unroll
    for (int qq = 0; qq < 2; qq++) {
      f32x4 sf[4];
      #pragma unroll
      for (int f = 0; f < 4; f++) {
        s16x8 b0 = *(s16x8*)&Ks[(f*16 + lr)*72 + lg*8];
        s16x8 b1 = *(s16x8*)&Ks[(f*16 + lr)*72 + 32 + lg*8];
        f32x4 s = (f32x4)0.f;
        s = MFMA16(aq[qq][0], b0, s);
        s = MFMA16(aq[qq][1], b1, s);
        sf[f] = s;
      }
      #pragma unroll
      for (int r = 0; r < 4; r++) {
        float mx = fmaxf(fmaxf(sf[0][r], sf[1][r]), fmaxf(sf[2][r], sf[3][r]));
        #pragma unroll
        for (int o = 1; o < 16; o <<= 1) mx = fmaxf(mx, __shfl_xor(mx, o));
        float mn = fmaxf(m_[qq][r], mx);
        float sum = 0.f;
        #pragma unroll
        for (int f = 0; f < 4; f++) {
          float pv2 = __expf(sf[f][r] - mn);
          sum += pv2;
          Pw[(lg*4 + r)*72 + f*16 + lr] = f2b(pv2);
        }
        #pragma unroll
        for (int o = 1; o < 16; o <<= 1) sum += __shfl_xor(sum, o);
        float sc = __expf(m_[qq][r] - mn);
        l_[qq][r] = l_[qq][r]*sc + sum;
        m_[qq][r] = mn;
        #pragma unroll
        for (int f = 0; f < 4; f++) oacc[qq][f][r] *= sc;
      }
      // P is per-wave; within-wave LDS ordering handled by compiler waitcnts
      #pragma unroll
      for (int ks = 0; ks < 2; ks++) {
        s16x8 ap = *(s16x8*)&Pw[lr*72 + ks*32 + lg*8];
        #pragma unroll
        for (int df = 0; df < 4; df++) {
          s16x8 bv = *(s16x8*)&Vs[(df*16 + lr)*72 + ks*32 + lg*8];
          oacc[qq][df] = MFMA16(ap, bv, oacc[qq][df]);
        }
      }
    }
  }
  #pragma unroll
  for (int qq = 0; qq < 2; qq++) {
    int pidx = (bh*4 + qg*2 + qq)*8 + ch;
    #pragma unroll
    for (int r = 0; r < 4; r++) {
      int lrow = wid*16 + lg*4 + r;
      if (lr == 0) { pm[pidx*64 + lrow] = m_[qq][r]; pl[pidx*64 + lrow] = l_[qq][r]; }
      #pragma unroll
      for (int df = 0; df < 4; df++)
        po[((size_t)pidx*64 + lrow)*64 + df*16 + lr] = f2b(oacc[qq][df][r]);
    }
  }
}

// ---------------- merge partials (bf16 po, fp32 accumulate) ----------------
__global__ __launch_bounds__(256) void flash_merge(const u16* __restrict__ po, const float* __restrict__ pm,
    const float* __restrict__ pl, u16* __restrict__ a3vT) {
  int row = blockIdx.x*4 + (threadIdx.x >> 6);
  int d = threadIdx.x & 63;
  int bh = row >> 8, qrow = row & 255, qt = qrow >> 6, lrow = qrow & 63;
  int pbase = (bh*4 + qt)*8;
  float m = -3e38f;
  #pragma unroll
  for (int ch = 0; ch < 8; ch++) m = fmaxf(m, pm[(pbase+ch)*64 + lrow]);
  float L = 0.f, O = 0.f;
  #pragma unroll
  for (int ch = 0; ch < 8; ch++) {
    float w = __expf(pm[(pbase+ch)*64 + lrow] - m);
    L += w * pl[(pbase+ch)*64 + lrow];
    O += w * b2f(po[((size_t)(pbase+ch)*64 + lrow)*64 + d]);
  }
  a3vT[((size_t)bh*64 + d)*256 + qrow] = f2b(O / L);
}

// ---------------- exact-softmax flash: outh = softmax(q @ kl^T) @ w2 ----------------
__global__ __launch_bounds__(256, 4) void flash_a1(const u16* __restrict__ Q, const u16* __restrict__ Kl,
    const u16* __restrict__ W2T, u16* __restrict__ outh) {
  __shared__ u16 Ks[64*72];
  __shared__ u16 Vs[64*264];
  __shared__ u16 Ps[4*16*264];
  int bh = blockIdx.y;
  int q0 = blockIdx.x * 64;
  int t = threadIdx.x, lane = t & 63, wid = t >> 6, lr = lane & 15, lg = lane >> 4;
  const u16* Qb = Q + ((size_t)bh*4096)*64;
  #pragma unroll
  for (int p = 0; p < 8; p++) {
    int c = t + p*256; int r = c >> 5, col = (c & 31)*8;
    *(uint4*)&Vs[r*264 + col] = *(const uint4*)&W2T[((size_t)bh*64 + r)*256 + col];
  }
  int qrow = q0 + wid*16 + lr;
  s16x8 aq0 = *(const s16x8*)&Qb[(size_t)qrow*64 + lg*8];
  s16x8 aq1 = *(const s16x8*)&Qb[(size_t)qrow*64 + 32 + lg*8];
  f32x4 sf[16];
  #pragma unroll
  for (int f = 0; f < 16; f++) sf[f] = (f32x4)0.f;
  #pragma unroll
  for (int kt = 0; kt < 4; kt++) {
    __syncthreads();
    #pragma unroll
    for (int p = 0; p < 2; p++) {
      int c = t + p*256; int r = c >> 3, cc = (c & 7)*8;
      *(uint4*)&Ks[r*72 + cc] = *(const uint4*)&Kl[((size_t)bh*256 + kt*64 + r)*64 + cc];
    }
    __syncthreads();
    #pragma unroll
    for (int f2 = 0; f2 < 4; f2++) {
      s16x8 b0 = *(s16x8*)&Ks[(f2*16 + lr)*72 + lg*8];
      s16x8 b1 = *(s16x8*)&Ks[(f2*16 + lr)*72 + 32 + lg*8];
      sf[kt*4 + f2] = MFMA16(aq1, b1, MFMA16(aq0, b0, sf[kt*4 + f2]));
    }
  }
  u16* Pw = Ps + wid*16*264;
  float linv[4];
  #pragma unroll
  for (int r = 0; r < 4; r++) {
    float mx = -3e38f;
    #pragma unroll
    for (int f = 0; f < 16; f++) mx = fmaxf(mx, sf[f][r]);
    #pragma unroll
    for (int o = 1; o < 16; o <<= 1) mx = fmaxf(mx, __shfl_xor(mx, o));
    float sum = 0.f;
    #pragma unroll
    for (int f = 0; f < 16; f++) {
      float pv = __expf(sf[f][r] - mx);
      sum += pv;
      Pw[(lg*4 + r)*264 + f*16 + lr] = f2b(pv);
    }
    #pragma unroll
    for (int o = 1; o < 16; o <<= 1) sum += __shfl_xor(sum, o);
    linv[r] = 1.f / sum;
  }
  f32x4 oacc[4];
  #pragma unroll
  for (int f = 0; f < 4; f++) oacc[f] = (f32x4)0.f;
  #pragma unroll
  for (int ks = 0; ks < 8; ks++) {
    s16x8 ap = *(s16x8*)&Pw[lr*264 + ks*32 + lg*8];
    #pragma unroll
    for (int df = 0; df < 4; df++) {
      s16x8 bv = *(s16x8*)&Vs[(df*16 + lr)*264 + ks*32 + lg*8];
      oacc[df] = MFMA16(ap, bv, oacc[df]);
    }
  }
  int b = bh >> 3, h = bh & 7;
  #pragma unroll
  for (int df = 0; df < 4; df++)
    #pragma unroll
    for (int r = 0; r < 4; r++) {
      int lrow = wid*16 + lg*4 + r;
      int col = df*16 + lr;
      outh[((size_t)(b*4096 + q0 + lrow))*512 + h*64 + col] = f2b(oacc[df][r] * linv[r]);
    }
}

// ---------------- LDS-tiled residual depthwise conv ----------------
__global__ __launch_bounds__(256) void conv_lds(const u16* __restrict__ v, const float* __restrict__ rw,
                                                u16* __restrict__ outh) {
  __shared__ u16 tile[160*72];
  __shared__ float wsm[33];
  int bh = blockIdx.y;
  int n0 = blockIdx.x * 128;
  int b = bh >> 3, h = bh & 7;
  int t = threadIdx.x;
  if (t < 33) wsm[t] = rw[h*33 + t];
  const u16* vb = v + ((size_t)bh*4096)*64;
  #pragma unroll
  for (int p = 0; p < 5; p++) {
    int c = t + p*256;
    int r = c >> 3, col = (c & 7)*8;
    int nn = n0 - 16 + r;
    uint4 val = make_uint4(0u,0u,0u,0u);
    if (nn >= 0 && nn < 4096) val = *(const uint4*)&vb[(size_t)nn*64 + col];
    *(uint4*)&tile[r*72 + col] = val;
  }
  __syncthreads();
  int d8 = (t & 7) * 8;
  int r0 = t >> 3;
  #pragma unroll
  for (int pass = 0; pass < 4; pass++) {
    int lrow = pass*32 + r0;
    float acc[8] = {};
    #pragma unroll
    for (int j = 0; j < 33; j++) {
      uint4 vv = *(uint4*)&tile[(lrow + j)*72 + d8];
      float w = wsm[j];
      acc[0] += b2f((u16)(vv.x & 0xffff)) * w;
      acc[1] += b2f((u16)(vv.x >> 16))    * w;
      acc[2] += b2f((u16)(vv.y & 0xffff)) * w;
      acc[3] += b2f((u16)(vv.y >> 16))    * w;
      acc[4] += b2f((u16)(vv.z & 0xffff)) * w;
      acc[5] += b2f((u16)(vv.z >> 16))    * w;
      acc[6] += b2f((u16)(vv.w & 0xffff)) * w;
      acc[7] += b2f((u16)(vv.w >> 16))    * w;
    }
    size_t oi = ((size_t)(b*4096 + n0 + lrow))*512 + h*64 + d8;
    uint4 ov = *(uint4*)&outh[oi];
    uint4 nv;
    nv.x = (unsigned)f2b(b2f((u16)(ov.x & 0xffff)) + acc[0]) | ((unsigned)f2b(b2f((u16)(ov.x >> 16)) + acc[1]) << 16);
    nv.y = (unsigned)f2b(b2f((u16)(ov.y & 0xffff)) + acc[2]) | ((unsigned)f2b(b2f((u16)(ov.y >> 16)) + acc[3]) << 16);
    nv.z = (unsigned)f2b(b2f((u16)(ov.z & 0xffff)) + acc[4]) | ((unsigned)f2b(b2f((u16)(ov.z >> 16)) + acc[5]) << 16);
    nv.w = (unsigned)f2b(b2f((u16)(ov.w & 0xffff)) + acc[6]) | ((unsigned)f2b(b2f((u16)(ov.w >> 16)) + acc[7]) << 16);
    *(uint4*)&outh[oi] = nv;
  }
}

extern "C" void kernel_launch(void* const* d_in, const int* in_sizes, int n_in,
                              void* d_out, int out_size, void* d_ws, size_t ws_size,
                              hipStream_t stream) {
  const float* x      = (const float*)d_in[0];
  const float* norm_w = (const float*)d_in[1];
  const float* norm_b = (const float*)d_in[2];
  const float* w_qkv  = (const float*)d_in[3];
  const float* w_out  = (const float*)d_in[4];
  const float* b_out  = (const float*)d_in[5];
  const float* res_w  = (const float*)d_in[6];
  float* out = (float*)d_out;
  char* ws = (char*)d_ws;

  size_t off = 0;
  u16* xn    = (u16*)(ws + off); off += 16777216;
  u16* q     = (u16*)(ws + off); off += 16777216;
  u16* k     = (u16*)(ws + off); off += 16777216;
  u16* v     = (u16*)(ws + off); off += 16777216;
  u16* vT    = (u16*)(ws + off); off += 16777216;
  u16* ql    = (u16*)(ws + off); off += 1048576;
  u16* kl    = (u16*)(ws + off); off += 1048576;
  float* a2  = (float*)(ws + off); off += 8388608;
  u16* a2h   = (u16*)(ws + off); off += 4194304;
  u16* zA    = (u16*)(ws + off); off += 4194304;
  u16* zAT   = (u16*)(ws + off); off += 4194304;
  u16* zB    = (u16*)(ws + off); off += 4194304;
  u16* zBT   = (u16*)(ws + off); off += 4194304;
  u16* xz    = (u16*)(ws + off); off += 4194304;
  u16* xzT   = (u16*)(ws + off); off += 4194304;
  u16* e1T   = (u16*)(ws + off); off += 4194304;
  u16* e2T   = (u16*)(ws + off); off += 4194304;
  u16* Wm    = (u16*)(ws + off); off += 4194304;
  u16* a3vT  = (u16*)(ws + off); off += 1048576;
  u16* w2T   = (u16*)(ws + off); off += 1048576;
  u16* wqkvT = (u16*)(ws + off); off += 1572864;
  u16* woutT = (u16*)(ws + off); off += 524288;
  u16* outh  = (u16*)(ws + off); off += 16777216;
  u16* po    = (u16*)(ws + off); off += 8388608;
  float* pm  = (float*)(ws + off); off += 262144;
  float* pl  = (float*)(ws + off); off += 262144;
  float* pcs = (float*)(ws + off); off += 131072;
  unsigned* scal = (unsigned*)(ws + off); off += 8;

  ln_kernel<<<16384, 256, 0, stream>>>(x, norm_w, norm_b, xn);
  wcast_T<<<3072, 256, 0, stream>>>(w_qkv, wqkvT, 512, 1536);
  wcast_T<<<1024, 256, 0, stream>>>(w_out, woutT, 512, 512);
  qkv_mfma<<<1536, 256, 0, stream>>>(xn, wqkvT, q, k, v);
  vtrans<<<dim3(64, 32), 256, 0, stream>>>(v, vT);
  landmark_kernel<<<8192, 64, 0, stream>>>(q, k, ql, kl);
  hipMemsetAsync(scal, 0, 8, stream);
  sim2_mfma<<<dim3(4, 32), 256, 0, stream>>>(ql, kl, a2, a2h, pcs);
  colmax_kernel<<<32, 256, 0, stream>>>(pcs, scal);
  flash_part<<<dim3(2, 8, 32), 256, 0, stream>>>(ql, k, vT, po, pm, pl);
  flash_merge<<<2048, 256, 0, stream>>>(po, pm, pl, a3vT);
  z0_kernel<<<8192, 256, 0, stream>>>(a2, scal, zA, zAT);

  u16 *zc = zA, *zcT = zAT, *zn = zB, *znT = zBT;
  for (int it = 0; it < 6; it++) {
    pinv_s1<<<dim3(4,4,32), 256, 0, stream>>>(a2h, zcT, xz, xzT, e1T);
    pinv_s2<<<dim3(4,4,64), 256, 0, stream>>>(xz, e1T, zc, xzT, e2T, Wm);
    pinv_s3<<<dim3(4,4,32), 256, 0, stream>>>(Wm, e2T, zc, zn, znT);
    u16* tp;
    tp = zc; zc = zn; zn = tp;
    tp = zcT; zcT = znT; znT = tp;
  }

  bmm64<<<dim3(1,4,32), 256, 0, stream>>>(zc, a3vT, w2T, 256, 64, 256);
  flash_a1<<<dim3(64, 32), 256, 0, stream>>>(q, kl, w2T, outh);
  conv_lds<<<dim3(32, 32), 256, 0, stream>>>(v, res_w, outh);
  out_mfma<<<512, 256, 0, stream>>>(outh, woutT, b_out, x, out);
}

// Round 11
// 432.075 us; speedup vs baseline: 3.0406x; 1.0247x over previous
//
#include <hip/hip_runtime.h>
#include <math.h>

typedef unsigned short u16;
typedef short s16x8 __attribute__((ext_vector_type(8)));
typedef float f32x4 __attribute__((ext_vector_type(4)));

#define MFMA16(a, b, c) __builtin_amdgcn_mfma_f32_16x16x32_bf16((a), (b), (c), 0, 0, 0)

__device__ __forceinline__ u16 f2b(float f) {
  unsigned u = __float_as_uint(f);
  unsigned r = (u + 0x7fff + ((u >> 16) & 1)) >> 16;
  return (u16)r;
}
__device__ __forceinline__ float b2f(u16 h) { return __uint_as_float(((unsigned)h) << 16); }

// ---------------- LayerNorm -> bf16 ----------------
__global__ __launch_bounds__(256) void ln_kernel(const float* __restrict__ x, const float* __restrict__ w,
                          const float* __restrict__ b, u16* __restrict__ xn) {
  int row = blockIdx.x;
  const float* xr = x + (size_t)row * 512;
  int t = threadIdx.x;
  float v0 = xr[t], v1 = xr[t + 256];
  float s = v0 + v1, ss = v0*v0 + v1*v1;
  for (int o = 32; o > 0; o >>= 1) { s += __shfl_down(s, o); ss += __shfl_down(ss, o); }
  __shared__ float ls[4], lss[4];
  int wid = t >> 6, lane = t & 63;
  if (lane == 0) { ls[wid] = s; lss[wid] = ss; }
  __syncthreads();
  float tot  = ls[0]+ls[1]+ls[2]+ls[3];
  float tot2 = lss[0]+lss[1]+lss[2]+lss[3];
  float mean = tot * (1.f/512);
  float var  = tot2 * (1.f/512) - mean*mean;
  float inv = rsqrtf(var + 1e-5f);
  u16* xo = xn + (size_t)row * 512;
  xo[t]     = f2b((v0-mean)*inv*w[t]     + b[t]);
  xo[t+256] = f2b((v1-mean)*inv*w[t+256] + b[t+256]);
}

// ---------------- weight transpose + cast ----------------
__global__ __launch_bounds__(256) void wcast_T(const float* __restrict__ W, u16* __restrict__ WT, int R, int C) {
  int idx = blockIdx.x*256 + threadIdx.x;
  if (idx >= R*C) return;
  int r = idx / C, c = idx - r*C;
  WT[(size_t)c*R + r] = f2b(W[idx]);
}

// ---------------- v transpose ----------------
__global__ __launch_bounds__(256) void vtrans(const u16* __restrict__ v, u16* __restrict__ vT) {
  __shared__ u16 tile[64][72];
  int bh = blockIdx.y, n0 = blockIdx.x * 64;
  int t = threadIdx.x;
  const u16* vb = v + ((size_t)bh*4096 + n0)*64;
  #pragma unroll
  for (int p = 0; p < 2; p++) {
    int c = t + p*256;
    int r = c >> 3, col = (c & 7)*8;
    *(uint4*)&tile[r][col] = *(const uint4*)&vb[(size_t)r*64 + col];
  }
  __syncthreads();
  #pragma unroll
  for (int p = 0; p < 2; p++) {
    int c = t + p*256;
    int d = c >> 3, ncol = (c & 7)*8;
    u16 tmp[8];
    #pragma unroll
    for (int j = 0; j < 8; j++) tmp[j] = tile[ncol + j][d];
    *(uint4*)&vT[((size_t)bh*64 + d)*4096 + n0 + ncol] = *(uint4*)tmp;
  }
}

// ---------------- 128x128 MFMA GEMM core, BK=32 + register prefetch ----------------
__device__ __forceinline__ void gemm128_pf(const u16* __restrict__ A, const u16* __restrict__ BT,
    int K, int ldA, int ldBT, int row0, int col0, u16* As, u16* Bs, f32x4 acc[4][4]) {
  int t = threadIdx.x, lane = t & 63, wid = t >> 6;
  int wr = (wid >> 1) * 64, wc = (wid & 1) * 64;
  int lr = lane & 15, lg = lane >> 4;
  int sr = t >> 2, sc = (t & 3) * 8;
  const u16* Ar0 = A  + (size_t)(row0 + sr)*ldA + sc;
  const u16* Ar1 = A  + (size_t)(row0 + sr + 64)*ldA + sc;
  const u16* Br0 = BT + (size_t)(col0 + sr)*ldBT + sc;
  const u16* Br1 = BT + (size_t)(col0 + sr + 64)*ldBT + sc;
  uint4 pa0 = *(const uint4*)Ar0, pa1 = *(const uint4*)Ar1;
  uint4 pb0 = *(const uint4*)Br0, pb1 = *(const uint4*)Br1;
  for (int k0 = 0; k0 < K; k0 += 32) {
    __syncthreads();
    *(uint4*)&As[sr*40 + sc]        = pa0;
    *(uint4*)&As[(sr + 64)*40 + sc] = pa1;
    *(uint4*)&Bs[sr*40 + sc]        = pb0;
    *(uint4*)&Bs[(sr + 64)*40 + sc] = pb1;
    __syncthreads();
    if (k0 + 32 < K) {
      pa0 = *(const uint4*)(Ar0 + k0 + 32);
      pa1 = *(const uint4*)(Ar1 + k0 + 32);
      pb0 = *(const uint4*)(Br0 + k0 + 32);
      pb1 = *(const uint4*)(Br1 + k0 + 32);
    }
    s16x8 af[4], bf[4];
    #pragma unroll
    for (int f = 0; f < 4; f++) {
      af[f] = *(s16x8*)&As[(wr + f*16 + lr)*40 + lg*8];
      bf[f] = *(s16x8*)&Bs[(wc + f*16 + lr)*40 + lg*8];
    }
    #pragma unroll
    for (int i = 0; i < 4; i++)
      #pragma unroll
      for (int j = 0; j < 4; j++)
        acc[i][j] = MFMA16(af[i], bf[j], acc[i][j]);
  }
}

// ---------------- 64x64 MFMA GEMM core (K=256), BK=64 + register prefetch ----------------
__device__ __forceinline__ void gemm64_pf(const u16* __restrict__ Ab, const u16* __restrict__ Bb,
    int row0, int col0, u16* As, u16* Bs, f32x4 acc[2][2]) {
  int t = threadIdx.x, lane = t & 63, wid = t >> 6;
  int wr = (wid >> 1)*32, wc = (wid & 1)*32;
  int lr = lane & 15, lg = lane >> 4;
  int sr = t >> 3, sc = (t & 7)*8;
  const u16* Ar0 = Ab + (size_t)(row0 + sr)*256 + sc;
  const u16* Ar1 = Ab + (size_t)(row0 + 32 + sr)*256 + sc;
  const u16* Br0 = Bb + (size_t)(col0 + sr)*256 + sc;
  const u16* Br1 = Bb + (size_t)(col0 + 32 + sr)*256 + sc;
  uint4 pa0 = *(const uint4*)Ar0, pa1 = *(const uint4*)Ar1;
  uint4 pb0 = *(const uint4*)Br0, pb1 = *(const uint4*)Br1;
  for (int k0 = 0; k0 < 256; k0 += 64) {
    __syncthreads();
    *(uint4*)&As[sr*72 + sc]        = pa0;
    *(uint4*)&As[(sr + 32)*72 + sc] = pa1;
    *(uint4*)&Bs[sr*72 + sc]        = pb0;
    *(uint4*)&Bs[(sr + 32)*72 + sc] = pb1;
    __syncthreads();
    if (k0 + 64 < 256) {
      pa0 = *(const uint4*)(Ar0 + k0 + 64);
      pa1 = *(const uint4*)(Ar1 + k0 + 64);
      pb0 = *(const uint4*)(Br0 + k0 + 64);
      pb1 = *(const uint4*)(Br1 + k0 + 64);
    }
    #pragma unroll
    for (int kk = 0; kk < 2; kk++) {
      s16x8 af[2], bf[2];
      #pragma unroll
      for (int f = 0; f < 2; f++) {
        af[f] = *(s16x8*)&As[(wr + f*16 + lr)*72 + kk*32 + lg*8];
        bf[f] = *(s16x8*)&Bs[(wc + f*16 + lr)*72 + kk*32 + lg*8];
      }
      #pragma unroll
      for (int i = 0; i < 2; i++)
        #pragma unroll
        for (int j = 0; j < 2; j++)
          acc[i][j] = MFMA16(af[i], bf[j], acc[i][j]);
    }
  }
}

// ---------------- QKV (XCD-swizzled) ----------------
__global__ __launch_bounds__(256, 4) void qkv_mfma(const u16* __restrict__ xn, const u16* __restrict__ wT,
    u16* __restrict__ q, u16* __restrict__ k, u16* __restrict__ v) {
  __shared__ u16 As[128*40], Bs[128*40];
  f32x4 acc[4][4];
  #pragma unroll
  for (int i = 0; i < 4; i++)
    #pragma unroll
    for (int j = 0; j < 4; j++) acc[i][j] = (f32x4)0.f;
  int bI = blockIdx.x;
  int job = (bI & 7)*192 + (bI >> 3);
  int row0 = (job / 12) * 128, col0 = (job % 12) * 128;
  gemm128_pf(xn, wT, 512, 512, 512, row0, col0, As, Bs, acc);
  int t = threadIdx.x, lane = t & 63, wid = t >> 6, lr = lane & 15, lg = lane >> 4;
  int wr = (wid >> 1)*64, wc = (wid & 1)*64;
  #pragma unroll
  for (int i = 0; i < 4; i++)
    #pragma unroll
    for (int j = 0; j < 4; j++)
      #pragma unroll
      for (int r = 0; r < 4; r++) {
        int row = row0 + wr + i*16 + lg*4 + r;
        int col = col0 + wc + j*16 + lr;
        float val = acc[i][j][r];
        int part = col >> 9, rem = col & 511, h = rem >> 6, d = rem & 63;
        int b = row >> 12, n = row & 4095;
        size_t bh = (size_t)(b*8 + h);
        size_t dst = (bh*4096 + n)*64 + d;
        if (part == 0)      q[dst] = f2b(val * 0.125f);
        else if (part == 1) k[dst] = f2b(val);
        else                v[dst] = f2b(val);
      }
}

// ---------------- out GEMM (XCD-swizzled) ----------------
__global__ __launch_bounds__(256, 4) void out_mfma(const u16* __restrict__ outh, const u16* __restrict__ wT,
    const float* __restrict__ bo, const float* __restrict__ x, float* __restrict__ out) {
  __shared__ u16 As[128*40], Bs[128*40];
  f32x4 acc[4][4];
  #pragma unroll
  for (int i = 0; i < 4; i++)
    #pragma unroll
    for (int j = 0; j < 4; j++) acc[i][j] = (f32x4)0.f;
  int bI = blockIdx.x;
  int job = (bI & 7)*64 + (bI >> 3);
  int row0 = (job / 4) * 128, col0 = (job % 4) * 128;
  gemm128_pf(outh, wT, 512, 512, 512, row0, col0, As, Bs, acc);
  int t = threadIdx.x, lane = t & 63, wid = t >> 6, lr = lane & 15, lg = lane >> 4;
  int wr = (wid >> 1)*64, wc = (wid & 1)*64;
  #pragma unroll
  for (int i = 0; i < 4; i++)
    #pragma unroll
    for (int j = 0; j < 4; j++)
      #pragma unroll
      for (int r = 0; r < 4; r++) {
        int row = row0 + wr + i*16 + lg*4 + r;
        int col = col0 + wc + j*16 + lr;
        size_t idx = (size_t)row*512 + col;
        out[idx] = x[idx] + acc[i][j][r] + bo[col];
      }
}

// ---------------- pinv stage 1: P = a2 @ z ; write P, P^T, (7I-P)^T ----------------
__global__ __launch_bounds__(256) void pinv_s1(const u16* __restrict__ a2h, const u16* __restrict__ zcT,
    u16* __restrict__ xz, u16* __restrict__ xzT, u16* __restrict__ e1T) {
  __shared__ u16 As[64*72], Bs[64*72];
  size_t bb = (size_t)blockIdx.z << 16;
  f32x4 acc[2][2];
  #pragma unroll
  for (int i = 0; i < 2; i++) { acc[i][0] = (f32x4)0.f; acc[i][1] = (f32x4)0.f; }
  int row0 = blockIdx.y*64, col0 = blockIdx.x*64;
  gemm64_pf(a2h + bb, zcT + bb, row0, col0, As, Bs, acc);
  int t = threadIdx.x, lane = t & 63, wid = t >> 6, lr = lane & 15, lg = lane >> 4;
  int wr = (wid >> 1)*32, wc = (wid & 1)*32;
  #pragma unroll
  for (int i = 0; i < 2; i++)
    #pragma unroll
    for (int j = 0; j < 2; j++)
      #pragma unroll
      for (int r = 0; r < 4; r++) {
        int row = row0 + wr + i*16 + lg*4 + r;
        int col = col0 + wc + j*16 + lr;
        float c = acc[i][j][r];
        xz [bb + (size_t)row*256 + col] = f2b(c);
        xzT[bb + (size_t)col*256 + row] = f2b(c);
        e1T[bb + (size_t)col*256 + row] = f2b((row == col ? 7.f : 0.f) - c);
      }
}

// ---------------- pinv stage 2: z 0-31: e2T=(15I - P@e1)^T ; 32-63: W = z@P ----------------
__global__ __launch_bounds__(256) void pinv_s2(const u16* __restrict__ xz, const u16* __restrict__ e1T,
    const u16* __restrict__ zc, const u16* __restrict__ xzT,
    u16* __restrict__ e2T, u16* __restrict__ W) {
  __shared__ u16 As[64*72], Bs[64*72];
  int bz = blockIdx.z;
  bool isQ = bz < 32;
  size_t bb = (size_t)(isQ ? bz : bz - 32) << 16;
  const u16* Aptr = (isQ ? xz : zc) + bb;
  const u16* Bptr = (isQ ? e1T : xzT) + bb;
  f32x4 acc[2][2];
  #pragma unroll
  for (int i = 0; i < 2; i++) { acc[i][0] = (f32x4)0.f; acc[i][1] = (f32x4)0.f; }
  int row0 = blockIdx.y*64, col0 = blockIdx.x*64;
  gemm64_pf(Aptr, Bptr, row0, col0, As, Bs, acc);
  int t = threadIdx.x, lane = t & 63, wid = t >> 6, lr = lane & 15, lg = lane >> 4;
  int wr = (wid >> 1)*32, wc = (wid & 1)*32;
  #pragma unroll
  for (int i = 0; i < 2; i++)
    #pragma unroll
    for (int j = 0; j < 2; j++)
      #pragma unroll
      for (int r = 0; r < 4; r++) {
        int row = row0 + wr + i*16 + lg*4 + r;
        int col = col0 + wc + j*16 + lr;
        float c = acc[i][j][r];
        if (isQ) e2T[bb + (size_t)col*256 + row] = f2b((row == col ? 15.f : 0.f) - c);
        else     W  [bb + (size_t)row*256 + col] = f2b(c);
      }
}

// ---------------- pinv stage 3: zn = 3.25 z - 0.25 W@e2 ; write zn, zn^T ----------------
__global__ __launch_bounds__(256) void pinv_s3(const u16* __restrict__ W, const u16* __restrict__ e2T,
    const u16* __restrict__ zc, u16* __restrict__ zn, u16* __restrict__ znT) {
  __shared__ u16 As[64*72], Bs[64*72];
  size_t bb = (size_t)blockIdx.z << 16;
  f32x4 acc[2][2];
  #pragma unroll
  for (int i = 0; i < 2; i++) { acc[i][0] = (f32x4)0.f; acc[i][1] = (f32x4)0.f; }
  int row0 = blockIdx.y*64, col0 = blockIdx.x*64;
  gemm64_pf(W + bb, e2T + bb, row0, col0, As, Bs, acc);
  int t = threadIdx.x, lane = t & 63, wid = t >> 6, lr = lane & 15, lg = lane >> 4;
  int wr = (wid >> 1)*32, wc = (wid & 1)*32;
  #pragma unroll
  for (int i = 0; i < 2; i++)
    #pragma unroll
    for (int j = 0; j < 2; j++)
      #pragma unroll
      for (int r = 0; r < 4; r++) {
        int row = row0 + wr + i*16 + lg*4 + r;
        int col = col0 + wc + j*16 + lr;
        size_t idx = bb + (size_t)row*256 + col;
        float val = 3.25f*b2f(zc[idx]) - 0.25f*acc[i][j][r];
        zn [idx] = f2b(val);
        znT[bb + (size_t)col*256 + row] = f2b(val);
      }
}

// ---------------- batched 64x64-tile MFMA GEMM (final w2T), BK=32 prefetch ----------------
__global__ __launch_bounds__(256) void bmm64(const u16* __restrict__ A, const u16* __restrict__ BT,
    u16* __restrict__ CT, int M, int N, int K) {
  __shared__ u16 As[64*40], Bs[64*40];
  int batch = blockIdx.z;
  const u16* Ab = A  + (size_t)batch*M*K;
  const u16* Bb = BT + (size_t)batch*N*K;
  int row0 = blockIdx.y*64, col0 = blockIdx.x*64;
  int t = threadIdx.x, lane = t & 63, wid = t >> 6, lr = lane & 15, lg = lane >> 4;
  int wr = (wid >> 1)*32, wc = (wid & 1)*32;
  int sr = t >> 2, sc = (t & 3)*8;
  const u16* Arow = Ab + (size_t)(row0 + sr)*K + sc;
  const u16* Brow = Bb + (size_t)(col0 + sr)*K + sc;
  uint4 pa = *(const uint4*)Arow;
  uint4 pb = *(const uint4*)Brow;
  f32x4 acc[2][2];
  #pragma unroll
  for (int i = 0; i < 2; i++)
    #pragma unroll
    for (int j = 0; j < 2; j++) acc[i][j] = (f32x4)0.f;
  for (int k0 = 0; k0 < K; k0 += 32) {
    __syncthreads();
    *(uint4*)&As[sr*40 + sc] = pa;
    *(uint4*)&Bs[sr*40 + sc] = pb;
    __syncthreads();
    if (k0 + 32 < K) {
      pa = *(const uint4*)(Arow + k0 + 32);
      pb = *(const uint4*)(Brow + k0 + 32);
    }
    s16x8 af[2], bf[2];
    #pragma unroll
    for (int f = 0; f < 2; f++) {
      af[f] = *(s16x8*)&As[(wr + f*16 + lr)*40 + lg*8];
      bf[f] = *(s16x8*)&Bs[(wc + f*16 + lr)*40 + lg*8];
    }
    #pragma unroll
    for (int i = 0; i < 2; i++)
      #pragma unroll
      for (int j = 0; j < 2; j++)
        acc[i][j] = MFMA16(af[i], bf[j], acc[i][j]);
  }
  size_t cb = (size_t)batch*M*N;
  #pragma unroll
  for (int i = 0; i < 2; i++)
    #pragma unroll
    for (int j = 0; j < 2; j++)
      #pragma unroll
      for (int r = 0; r < 4; r++) {
        int row = row0 + wr + i*16 + lg*4 + r;
        int col = col0 + wc + j*16 + lr;
        CT[cb + (size_t)col*M + row] = f2b(acc[i][j][r]);
      }
}

// ---------------- landmarks ----------------
__global__ void landmark_kernel(const u16* __restrict__ q, const u16* __restrict__ k,
                                u16* __restrict__ ql, u16* __restrict__ kl) {
  int idx = blockIdx.x;
  int d = threadIdx.x;
  size_t base = ((size_t)idx * 16) * 64 + d;
  float sq = 0.f, sk = 0.f;
  #pragma unroll
  for (int j = 0; j < 16; j++) { sq += b2f(q[base + (size_t)j*64]); sk += b2f(k[base + (size_t)j*64]); }
  ql[(size_t)idx*64 + d] = f2b(sq * (1.f/16.f));
  kl[(size_t)idx*64 + d] = f2b(sk * (1.f/16.f));
}

// ---------------- sim2 (split): rows rq*64..+64 of one bh; partial colsums to pcs ----------------
__global__ __launch_bounds__(256, 4) void sim2_mfma(const u16* __restrict__ ql, const u16* __restrict__ kl,
    float* __restrict__ a2, u16* __restrict__ a2h, float* __restrict__ pcs) {
  __shared__ u16 Qs[64*72];
  __shared__ u16 Ks2[256*72];
  __shared__ float wcol[4*256];
  int rq = blockIdx.x, bh = blockIdx.y;
  int t = threadIdx.x, lane = t & 63, wid = t >> 6, lr = lane & 15, lg = lane >> 4;
  #pragma unroll
  for (int p = 0; p < 2; p++) {
    int c = t + p*256;
    int r = c >> 3, col = (c & 7)*8;
    *(uint4*)&Qs[r*72 + col] = *(const uint4*)&ql[((size_t)bh*256 + rq*64 + r)*64 + col];
  }
  #pragma unroll
  for (int p = 0; p < 8; p++) {
    int c = t + p*256;
    int r = c >> 3, col = (c & 7)*8;
    *(uint4*)&Ks2[r*72 + col] = *(const uint4*)&kl[((size_t)bh*256 + r)*64 + col];
  }
  __syncthreads();
  float colp[16];
  #pragma unroll
  for (int cf = 0; cf < 16; cf++) colp[cf] = 0.f;
  int rbase = wid*16;
  s16x8 a0 = *(s16x8*)&Qs[(rbase + lr)*72 + lg*8];
  s16x8 a1 = *(s16x8*)&Qs[(rbase + lr)*72 + 32 + lg*8];
  f32x4 sf[16];
  #pragma unroll
  for (int cf = 0; cf < 16; cf++) {
    s16x8 b0 = *(s16x8*)&Ks2[(cf*16 + lr)*72 + lg*8];
    s16x8 b1 = *(s16x8*)&Ks2[(cf*16 + lr)*72 + 32 + lg*8];
    sf[cf] = MFMA16(a1, b1, MFMA16(a0, b0, (f32x4)0.f));
  }
  #pragma unroll
  for (int r = 0; r < 4; r++) {
    float mx = -3e38f;
    #pragma unroll
    for (int cf = 0; cf < 16; cf++) mx = fmaxf(mx, sf[cf][r]);
    #pragma unroll
    for (int o = 1; o < 16; o <<= 1) mx = fmaxf(mx, __shfl_xor(mx, o));
    float sum = 0.f;
    #pragma unroll
    for (int cf = 0; cf < 16; cf++) { sf[cf][r] = __expf(sf[cf][r] - mx); sum += sf[cf][r]; }
    #pragma unroll
    for (int o = 1; o < 16; o <<= 1) sum += __shfl_xor(sum, o);
    float inv = 1.f / sum;
    int row = rq*64 + rbase + lg*4 + r;
    size_t base = (size_t)bh*65536 + (size_t)row*256;
    #pragma unroll
    for (int cf = 0; cf < 16; cf++) {
      float pp = sf[cf][r] * inv;
      a2[base + cf*16 + lr] = pp;
      a2h[base + cf*16 + lr] = f2b(pp);
      colp[cf] += pp;
    }
  }
  #pragma unroll
  for (int cf = 0; cf < 16; cf++) {
    colp[cf] += __shfl_xor(colp[cf], 16);
    colp[cf] += __shfl_xor(colp[cf], 32);
  }
  if (lg == 0) {
    #pragma unroll
    for (int cf = 0; cf < 16; cf++) wcol[wid*256 + cf*16 + lr] = colp[cf];
  }
  __syncthreads();
  pcs[((size_t)bh*4 + rq)*256 + t] = wcol[t] + wcol[256 + t] + wcol[512 + t] + wcol[768 + t];
}

// ---------------- colmax: max over column sums ----------------
__global__ __launch_bounds__(256) void colmax_kernel(const float* __restrict__ pcs, unsigned* __restrict__ scal) {
  __shared__ float red[256];
  int bh = blockIdx.x, t = threadIdx.x;
  size_t b4 = (size_t)bh*4*256;
  red[t] = pcs[b4 + t] + pcs[b4 + 256 + t] + pcs[b4 + 512 + t] + pcs[b4 + 768 + t];
  __syncthreads();
  for (int o = 128; o > 0; o >>= 1) {
    if (t < o) red[t] = fmaxf(red[t], red[t+o]);
    __syncthreads();
  }
  if (t == 0) atomicMax(scal + 1, __float_as_uint(red[0]));
}

// ---------------- z0 = a2^T / colmax ----------------
__global__ void z0_kernel(const float* __restrict__ a2, const unsigned* __restrict__ scal,
                          u16* __restrict__ zA, u16* __restrict__ zAT) {
  size_t idx = (size_t)blockIdx.x*256 + threadIdx.x;
  float inv = 1.f / __uint_as_float(scal[1]);
  size_t bh = idx >> 16; int rem = (int)(idx & 65535); int i = rem >> 8, j = rem & 255;
  zA[idx]  = f2b(a2[(bh<<16) + ((size_t)j<<8) + i] * inv);
  zAT[idx] = f2b(a2[idx] * inv);
}

// ---------------- split-K flash partials: 2 q-tiles per block, 16 chunks of 256 keys ----------------
__global__ __launch_bounds__(256) void flash_part(const u16* __restrict__ Q, const u16* __restrict__ Kg,
    const u16* __restrict__ VT, u16* __restrict__ po, float* __restrict__ pm, float* __restrict__ pl) {
  __shared__ u16 Ks[64*72];
  __shared__ u16 Vs[64*72];
  __shared__ u16 Ps[4*16*72];
  int qg = blockIdx.x, ch = blockIdx.y, bh = blockIdx.z;
  int t = threadIdx.x, lane = t & 63, wid = t >> 6, lr = lane & 15, lg = lane >> 4;
  const u16* Qb  = Q  + ((size_t)bh*256)*64;
  const u16* Kb  = Kg + ((size_t)bh*4096 + ch*256)*64;
  const u16* VTb = VT + ((size_t)bh*64)*4096 + ch*256;
  s16x8 aq[2][2];
  #pragma unroll
  for (int qq = 0; qq < 2; qq++) {
    int qrow = (qg*2 + qq)*64 + wid*16 + lr;
    aq[qq][0] = *(const s16x8*)&Qb[(size_t)qrow*64 + lg*8];
    aq[qq][1] = *(const s16x8*)&Qb[(size_t)qrow*64 + 32 + lg*8];
  }
  f32x4 oacc[2][4];
  float m_[2][4], l_[2][4];
  #pragma unroll
  for (int qq = 0; qq < 2; qq++)
    #pragma unroll
    for (int f = 0; f < 4; f++) {
      oacc[qq][f] = (f32x4)0.f;
      m_[qq][f] = -3e38f;
      l_[qq][f] = 0.f;
    }
  u16* Pw = Ps + wid*16*72;
  uint4 pk[2], pv[2];
  #pragma unroll
  for (int p = 0; p < 2; p++) {
    int c = t + p*256; int r = c >> 3, cc = (c & 7)*8;
    pk[p] = *(const uint4*)&Kb[(size_t)r*64 + cc];
    pv[p] = *(const uint4*)&VTb[(size_t)r*4096 + cc];
  }
  for (int k0 = 0; k0 < 256; k0 += 64) {
    __syncthreads();
    #pragma unroll
    for (int p = 0; p < 2; p++) {
      int c = t + p*256; int r = c >> 3, cc = (c & 7)*8;
      *(uint4*)&Ks[r*72 + cc] = pk[p];
      *(uint4*)&Vs[r*72 + cc] = pv[p];
    }
    __syncthreads();
    if (k0 + 64 < 256) {
      #pragma unroll
      for (int p = 0; p < 2; p++) {
        int c = t + p*256; int r = c >> 3, cc = (c & 7)*8;
        pk[p] = *(const uint4*)&Kb[(size_t)(k0 + 64 + r)*64 + cc];
        pv[p] = *(const uint4*)&VTb[(size_t)r*4096 + k0 + 64 + cc];
      }
    }
    #pragma unroll
    for (int qq = 0; qq < 2; qq++) {
      f32x4 sf[4];
      #pragma unroll
      for (int f = 0; f < 4; f++) {
        s16x8 b0 = *(s16x8*)&Ks[(f*16 + lr)*72 + lg*8];
        s16x8 b1 = *(s16x8*)&Ks[(f*16 + lr)*72 + 32 + lg*8];
        f32x4 s = (f32x4)0.f;
        s = MFMA16(aq[qq][0], b0, s);
        s = MFMA16(aq[qq][1], b1, s);
        sf[f] = s;
      }
      #pragma unroll
      for (int r = 0; r < 4; r++) {
        float mx = fmaxf(fmaxf(sf[0][r], sf[1][r]), fmaxf(sf[2][r], sf[3][r]));
        #pragma unroll
        for (int o = 1; o < 16; o <<= 1) mx = fmaxf(mx, __shfl_xor(mx, o));
        float mn = fmaxf(m_[qq][r], mx);
        float sum = 0.f;
        #pragma unroll
        for (int f = 0; f < 4; f++) {
          float pv2 = __expf(sf[f][r] - mn);
          sum += pv2;
          Pw[(lg*4 + r)*72 + f*16 + lr] = f2b(pv2);
        }
        #pragma unroll
        for (int o = 1; o < 16; o <<= 1) sum += __shfl_xor(sum, o);
        float sc = __expf(m_[qq][r] - mn);
        l_[qq][r] = l_[qq][r]*sc + sum;
        m_[qq][r] = mn;
        #pragma unroll
        for (int f = 0; f < 4; f++) oacc[qq][f][r] *= sc;
      }
      #pragma unroll
      for (int ks = 0; ks < 2; ks++) {
        s16x8 ap = *(s16x8*)&Pw[lr*72 + ks*32 + lg*8];
        #pragma unroll
        for (int df = 0; df < 4; df++) {
          s16x8 bv = *(s16x8*)&Vs[(df*16 + lr)*72 + ks*32 + lg*8];
          oacc[qq][df] = MFMA16(ap, bv, oacc[qq][df]);
        }
      }
    }
  }
  #pragma unroll
  for (int qq = 0; qq < 2; qq++) {
    int pidx = (bh*4 + qg*2 + qq)*16 + ch;
    #pragma unroll
    for (int r = 0; r < 4; r++) {
      int lrow = wid*16 + lg*4 + r;
      if (lr == 0) { pm[pidx*64 + lrow] = m_[qq][r]; pl[pidx*64 + lrow] = l_[qq][r]; }
      #pragma unroll
      for (int df = 0; df < 4; df++)
        po[((size_t)pidx*64 + lrow)*64 + df*16 + lr] = f2b(oacc[qq][df][r]);
    }
  }
}

// ---------------- merge 16 partials (bf16 po, fp32 accumulate) ----------------
__global__ __launch_bounds__(256) void flash_merge(const u16* __restrict__ po, const float* __restrict__ pm,
    const float* __restrict__ pl, u16* __restrict__ a3vT) {
  int row = blockIdx.x*4 + (threadIdx.x >> 6);
  int d = threadIdx.x & 63;
  int bh = row >> 8, qrow = row & 255, qt = qrow >> 6, lrow = qrow & 63;
  int pbase = (bh*4 + qt)*16;
  float m = -3e38f;
  #pragma unroll
  for (int ch = 0; ch < 16; ch++) m = fmaxf(m, pm[(pbase+ch)*64 + lrow]);
  float L = 0.f, O = 0.f;
  #pragma unroll
  for (int ch = 0; ch < 16; ch++) {
    float w = __expf(pm[(pbase+ch)*64 + lrow] - m);
    L += w * pl[(pbase+ch)*64 + lrow];
    O += w * b2f(po[((size_t)(pbase+ch)*64 + lrow)*64 + d]);
  }
  a3vT[((size_t)bh*64 + d)*256 + qrow] = f2b(O / L);
}

// ---------------- exact-softmax flash: outh = softmax(q @ kl^T) @ w2 ----------------
__global__ __launch_bounds__(256, 4) void flash_a1(const u16* __restrict__ Q, const u16* __restrict__ Kl,
    const u16* __restrict__ W2T, u16* __restrict__ outh) {
  __shared__ u16 Ks[64*72];
  __shared__ u16 Vs[64*264];
  __shared__ u16 Ps[4*16*264];
  int bh = blockIdx.y;
  int q0 = blockIdx.x * 64;
  int t = threadIdx.x, lane = t & 63, wid = t >> 6, lr = lane & 15, lg = lane >> 4;
  const u16* Qb = Q + ((size_t)bh*4096)*64;
  #pragma unroll
  for (int p = 0; p < 8; p++) {
    int c = t + p*256; int r = c >> 5, col = (c & 31)*8;
    *(uint4*)&Vs[r*264 + col] = *(const uint4*)&W2T[((size_t)bh*64 + r)*256 + col];
  }
  int qrow = q0 + wid*16 + lr;
  s16x8 aq0 = *(const s16x8*)&Qb[(size_t)qrow*64 + lg*8];
  s16x8 aq1 = *(const s16x8*)&Qb[(size_t)qrow*64 + 32 + lg*8];
  f32x4 sf[16];
  #pragma unroll
  for (int f = 0; f < 16; f++) sf[f] = (f32x4)0.f;
  #pragma unroll
  for (int kt = 0; kt < 4; kt++) {
    __syncthreads();
    #pragma unroll
    for (int p = 0; p < 2; p++) {
      int c = t + p*256; int r = c >> 3, cc = (c & 7)*8;
      *(uint4*)&Ks[r*72 + cc] = *(const uint4*)&Kl[((size_t)bh*256 + kt*64 + r)*64 + cc];
    }
    __syncthreads();
    #pragma unroll
    for (int f2 = 0; f2 < 4; f2++) {
      s16x8 b0 = *(s16x8*)&Ks[(f2*16 + lr)*72 + lg*8];
      s16x8 b1 = *(s16x8*)&Ks[(f2*16 + lr)*72 + 32 + lg*8];
      sf[kt*4 + f2] = MFMA16(aq1, b1, MFMA16(aq0, b0, sf[kt*4 + f2]));
    }
  }
  u16* Pw = Ps + wid*16*264;
  float linv[4];
  #pragma unroll
  for (int r = 0; r < 4; r++) {
    float mx = -3e38f;
    #pragma unroll
    for (int f = 0; f < 16; f++) mx = fmaxf(mx, sf[f][r]);
    #pragma unroll
    for (int o = 1; o < 16; o <<= 1) mx = fmaxf(mx, __shfl_xor(mx, o));
    float sum = 0.f;
    #pragma unroll
    for (int f = 0; f < 16; f++) {
      float pv = __expf(sf[f][r] - mx);
      sum += pv;
      Pw[(lg*4 + r)*264 + f*16 + lr] = f2b(pv);
    }
    #pragma unroll
    for (int o = 1; o < 16; o <<= 1) sum += __shfl_xor(sum, o);
    linv[r] = 1.f / sum;
  }
  f32x4 oacc[4];
  #pragma unroll
  for (int f = 0; f < 4; f++) oacc[f] = (f32x4)0.f;
  #pragma unroll
  for (int ks = 0; ks < 8; ks++) {
    s16x8 ap = *(s16x8*)&Pw[lr*264 + ks*32 + lg*8];
    #pragma unroll
    for (int df = 0; df < 4; df++) {
      s16x8 bv = *(s16x8*)&Vs[(df*16 + lr)*264 + ks*32 + lg*8];
      oacc[df] = MFMA16(ap, bv, oacc[df]);
    }
  }
  int b = bh >> 3, h = bh & 7;
  #pragma unroll
  for (int df = 0; df < 4; df++)
    #pragma unroll
    for (int r = 0; r < 4; r++) {
      int lrow = wid*16 + lg*4 + r;
      int col = df*16 + lr;
      outh[((size_t)(b*4096 + q0 + lrow))*512 + h*64 + col] = f2b(oacc[df][r] * linv[r]);
    }
}

// ---------------- LDS-tiled residual depthwise conv ----------------
__global__ __launch_bounds__(256) void conv_lds(const u16* __restrict__ v, const float* __restrict__ rw,
                                                u16* __restrict__ outh) {
  __shared__ u16 tile[160*72];
  __shared__ float wsm[33];
  int bh = blockIdx.y;
  int n0 = blockIdx.x * 128;
  int b = bh >> 3, h = bh & 7;
  int t = threadIdx.x;
  if (t < 33) wsm[t] = rw[h*33 + t];
  const u16* vb = v + ((size_t)bh*4096)*64;
  #pragma unroll
  for (int p = 0; p < 5; p++) {
    int c = t + p*256;
    int r = c >> 3, col = (c & 7)*8;
    int nn = n0 - 16 + r;
    uint4 val = make_uint4(0u,0u,0u,0u);
    if (nn >= 0 && nn < 4096) val = *(const uint4*)&vb[(size_t)nn*64 + col];
    *(uint4*)&tile[r*72 + col] = val;
  }
  __syncthreads();
  int d8 = (t & 7) * 8;
  int r0 = t >> 3;
  #pragma unroll
  for (int pass = 0; pass < 4; pass++) {
    int lrow = pass*32 + r0;
    float acc[8] = {};
    #pragma unroll
    for (int j = 0; j < 33; j++) {
      uint4 vv = *(uint4*)&tile[(lrow + j)*72 + d8];
      float w = wsm[j];
      acc[0] += b2f((u16)(vv.x & 0xffff)) * w;
      acc[1] += b2f((u16)(vv.x >> 16))    * w;
      acc[2] += b2f((u16)(vv.y & 0xffff)) * w;
      acc[3] += b2f((u16)(vv.y >> 16))    * w;
      acc[4] += b2f((u16)(vv.z & 0xffff)) * w;
      acc[5] += b2f((u16)(vv.z >> 16))    * w;
      acc[6] += b2f((u16)(vv.w & 0xffff)) * w;
      acc[7] += b2f((u16)(vv.w >> 16))    * w;
    }
    size_t oi = ((size_t)(b*4096 + n0 + lrow))*512 + h*64 + d8;
    uint4 ov = *(uint4*)&outh[oi];
    uint4 nv;
    nv.x = (unsigned)f2b(b2f((u16)(ov.x & 0xffff)) + acc[0]) | ((unsigned)f2b(b2f((u16)(ov.x >> 16)) + acc[1]) << 16);
    nv.y = (unsigned)f2b(b2f((u16)(ov.y & 0xffff)) + acc[2]) | ((unsigned)f2b(b2f((u16)(ov.y >> 16)) + acc[3]) << 16);
    nv.z = (unsigned)f2b(b2f((u16)(ov.z & 0xffff)) + acc[4]) | ((unsigned)f2b(b2f((u16)(ov.z >> 16)) + acc[5]) << 16);
    nv.w = (unsigned)f2b(b2f((u16)(ov.w & 0xffff)) + acc[6]) | ((unsigned)f2b(b2f((u16)(ov.w >> 16)) + acc[7]) << 16);
    *(uint4*)&outh[oi] = nv;
  }
}

extern "C" void kernel_launch(void* const* d_in, const int* in_sizes, int n_in,
                              void* d_out, int out_size, void* d_ws, size_t ws_size,
                              hipStream_t stream) {
  const float* x      = (const float*)d_in[0];
  const float* norm_w = (const float*)d_in[1];
  const float* norm_b = (const float*)d_in[2];
  const float* w_qkv  = (const float*)d_in[3];
  const float* w_out  = (const float*)d_in[4];
  const float* b_out  = (const float*)d_in[5];
  const float* res_w  = (const float*)d_in[6];
  float* out = (float*)d_out;
  char* ws = (char*)d_ws;

  size_t off = 0;
  u16* xn    = (u16*)(ws + off); off += 16777216;
  u16* q     = (u16*)(ws + off); off += 16777216;
  u16* k     = (u16*)(ws + off); off += 16777216;
  u16* v     = (u16*)(ws + off); off += 16777216;
  u16* vT    = (u16*)(ws + off); off += 16777216;
  u16* ql    = (u16*)(ws + off); off += 1048576;
  u16* kl    = (u16*)(ws + off); off += 1048576;
  float* a2  = (float*)(ws + off); off += 8388608;
  u16* a2h   = (u16*)(ws + off); off += 4194304;
  u16* zA    = (u16*)(ws + off); off += 4194304;
  u16* zAT   = (u16*)(ws + off); off += 4194304;
  u16* zB    = (u16*)(ws + off); off += 4194304;
  u16* zBT   = (u16*)(ws + off); off += 4194304;
  u16* xz    = (u16*)(ws + off); off += 4194304;
  u16* xzT   = (u16*)(ws + off); off += 4194304;
  u16* e1T   = (u16*)(ws + off); off += 4194304;
  u16* e2T   = (u16*)(ws + off); off += 4194304;
  u16* Wm    = (u16*)(ws + off); off += 4194304;
  u16* a3vT  = (u16*)(ws + off); off += 1048576;
  u16* w2T   = (u16*)(ws + off); off += 1048576;
  u16* wqkvT = (u16*)(ws + off); off += 1572864;
  u16* woutT = (u16*)(ws + off); off += 524288;
  u16* outh  = (u16*)(ws + off); off += 16777216;
  u16* po    = (u16*)(ws + off); off += 16777216;   // 2048 pidx x 64 x 64 bf16
  float* pm  = (float*)(ws + off); off += 524288;
  float* pl  = (float*)(ws + off); off += 524288;
  float* pcs = (float*)(ws + off); off += 131072;
  unsigned* scal = (unsigned*)(ws + off); off += 8;

  ln_kernel<<<16384, 256, 0, stream>>>(x, norm_w, norm_b, xn);
  wcast_T<<<3072, 256, 0, stream>>>(w_qkv, wqkvT, 512, 1536);
  wcast_T<<<1024, 256, 0, stream>>>(w_out, woutT, 512, 512);
  qkv_mfma<<<1536, 256, 0, stream>>>(xn, wqkvT, q, k, v);
  vtrans<<<dim3(64, 32), 256, 0, stream>>>(v, vT);
  landmark_kernel<<<8192, 64, 0, stream>>>(q, k, ql, kl);
  hipMemsetAsync(scal, 0, 8, stream);
  sim2_mfma<<<dim3(4, 32), 256, 0, stream>>>(ql, kl, a2, a2h, pcs);
  colmax_kernel<<<32, 256, 0, stream>>>(pcs, scal);
  flash_part<<<dim3(2, 16, 32), 256, 0, stream>>>(ql, k, vT, po, pm, pl);
  flash_merge<<<2048, 256, 0, stream>>>(po, pm, pl, a3vT);
  z0_kernel<<<8192, 256, 0, stream>>>(a2, scal, zA, zAT);

  u16 *zc = zA, *zcT = zAT, *zn = zB, *znT = zBT;
  for (int it = 0; it < 6; it++) {
    pinv_s1<<<dim3(4,4,32), 256, 0, stream>>>(a2h, zcT, xz, xzT, e1T);
    pinv_s2<<<dim3(4,4,64), 256, 0, stream>>>(xz, e1T, zc, xzT, e2T, Wm);
    pinv_s3<<<dim3(4,4,32), 256, 0, stream>>>(Wm, e2T, zc, zn, znT);
    u16* tp;
    tp = zc; zc = zn; zn = tp;
    tp = zcT; zcT = znT; znT = tp;
  }

  bmm64<<<dim3(1,4,32), 256, 0, stream>>>(zc, a3vT, w2T, 256, 64, 256);
  flash_a1<<<dim3(64, 32), 256, 0, stream>>>(q, kl, w2T, outh);
  conv_lds<<<dim3(32, 32), 256, 0, stream>>>(v, res_w, outh);
  out_mfma<<<512, 256, 0, stream>>>(outh, woutT, b_out, x, out);
}

// Round 12
// 421.823 us; speedup vs baseline: 3.1145x; 1.0243x over previous
//
#include <hip/hip_runtime.h>
#include <math.h>

typedef unsigned short u16;
typedef short s16x8 __attribute__((ext_vector_type(8)));
typedef float f32x4 __attribute__((ext_vector_type(4)));

#define MFMA16(a, b, c) __builtin_amdgcn_mfma_f32_16x16x32_bf16((a), (b), (c), 0, 0, 0)

__device__ __forceinline__ u16 f2b(float f) {
  unsigned u = __float_as_uint(f);
  unsigned r = (u + 0x7fff + ((u >> 16) & 1)) >> 16;
  return (u16)r;
}
__device__ __forceinline__ float b2f(u16 h) { return __uint_as_float(((unsigned)h) << 16); }

// ---------------- LayerNorm -> bf16 ----------------
__global__ __launch_bounds__(256) void ln_kernel(const float* __restrict__ x, const float* __restrict__ w,
                          const float* __restrict__ b, u16* __restrict__ xn) {
  int row = blockIdx.x;
  const float* xr = x + (size_t)row * 512;
  int t = threadIdx.x;
  float v0 = xr[t], v1 = xr[t + 256];
  float s = v0 + v1, ss = v0*v0 + v1*v1;
  for (int o = 32; o > 0; o >>= 1) { s += __shfl_down(s, o); ss += __shfl_down(ss, o); }
  __shared__ float ls[4], lss[4];
  int wid = t >> 6, lane = t & 63;
  if (lane == 0) { ls[wid] = s; lss[wid] = ss; }
  __syncthreads();
  float tot  = ls[0]+ls[1]+ls[2]+ls[3];
  float tot2 = lss[0]+lss[1]+lss[2]+lss[3];
  float mean = tot * (1.f/512);
  float var  = tot2 * (1.f/512) - mean*mean;
  float inv = rsqrtf(var + 1e-5f);
  u16* xo = xn + (size_t)row * 512;
  xo[t]     = f2b((v0-mean)*inv*w[t]     + b[t]);
  xo[t+256] = f2b((v1-mean)*inv*w[t+256] + b[t+256]);
}

// ---------------- weight transpose + cast ----------------
__global__ __launch_bounds__(256) void wcast_T(const float* __restrict__ W, u16* __restrict__ WT, int R, int C) {
  int idx = blockIdx.x*256 + threadIdx.x;
  if (idx >= R*C) return;
  int r = idx / C, c = idx - r*C;
  WT[(size_t)c*R + r] = f2b(W[idx]);
}

// ---------------- v transpose ----------------
__global__ __launch_bounds__(256) void vtrans(const u16* __restrict__ v, u16* __restrict__ vT) {
  __shared__ u16 tile[64][72];
  int bh = blockIdx.y, n0 = blockIdx.x * 64;
  int t = threadIdx.x;
  const u16* vb = v + ((size_t)bh*4096 + n0)*64;
  #pragma unroll
  for (int p = 0; p < 2; p++) {
    int c = t + p*256;
    int r = c >> 3, col = (c & 7)*8;
    *(uint4*)&tile[r][col] = *(const uint4*)&vb[(size_t)r*64 + col];
  }
  __syncthreads();
  #pragma unroll
  for (int p = 0; p < 2; p++) {
    int c = t + p*256;
    int d = c >> 3, ncol = (c & 7)*8;
    u16 tmp[8];
    #pragma unroll
    for (int j = 0; j < 8; j++) tmp[j] = tile[ncol + j][d];
    *(uint4*)&vT[((size_t)bh*64 + d)*4096 + n0 + ncol] = *(uint4*)tmp;
  }
}

// ---------------- 128x128 MFMA GEMM core, BK=32 + register prefetch ----------------
__device__ __forceinline__ void gemm128_pf(const u16* __restrict__ A, const u16* __restrict__ BT,
    int K, int ldA, int ldBT, int row0, int col0, u16* As, u16* Bs, f32x4 acc[4][4]) {
  int t = threadIdx.x, lane = t & 63, wid = t >> 6;
  int wr = (wid >> 1) * 64, wc = (wid & 1) * 64;
  int lr = lane & 15, lg = lane >> 4;
  int sr = t >> 2, sc = (t & 3) * 8;
  const u16* Ar0 = A  + (size_t)(row0 + sr)*ldA + sc;
  const u16* Ar1 = A  + (size_t)(row0 + sr + 64)*ldA + sc;
  const u16* Br0 = BT + (size_t)(col0 + sr)*ldBT + sc;
  const u16* Br1 = BT + (size_t)(col0 + sr + 64)*ldBT + sc;
  uint4 pa0 = *(const uint4*)Ar0, pa1 = *(const uint4*)Ar1;
  uint4 pb0 = *(const uint4*)Br0, pb1 = *(const uint4*)Br1;
  for (int k0 = 0; k0 < K; k0 += 32) {
    __syncthreads();
    *(uint4*)&As[sr*40 + sc]        = pa0;
    *(uint4*)&As[(sr + 64)*40 + sc] = pa1;
    *(uint4*)&Bs[sr*40 + sc]        = pb0;
    *(uint4*)&Bs[(sr + 64)*40 + sc] = pb1;
    __syncthreads();
    if (k0 + 32 < K) {
      pa0 = *(const uint4*)(Ar0 + k0 + 32);
      pa1 = *(const uint4*)(Ar1 + k0 + 32);
      pb0 = *(const uint4*)(Br0 + k0 + 32);
      pb1 = *(const uint4*)(Br1 + k0 + 32);
    }
    s16x8 af[4], bf[4];
    #pragma unroll
    for (int f = 0; f < 4; f++) {
      af[f] = *(s16x8*)&As[(wr + f*16 + lr)*40 + lg*8];
      bf[f] = *(s16x8*)&Bs[(wc + f*16 + lr)*40 + lg*8];
    }
    #pragma unroll
    for (int i = 0; i < 4; i++)
      #pragma unroll
      for (int j = 0; j < 4; j++)
        acc[i][j] = MFMA16(af[i], bf[j], acc[i][j]);
  }
}

// ---------------- 64x64 MFMA GEMM core (K=256), BK=64 + register prefetch ----------------
__device__ __forceinline__ void gemm64_pf(const u16* __restrict__ Ab, const u16* __restrict__ Bb,
    int row0, int col0, u16* As, u16* Bs, f32x4 acc[2][2]) {
  int t = threadIdx.x, lane = t & 63, wid = t >> 6;
  int wr = (wid >> 1)*32, wc = (wid & 1)*32;
  int lr = lane & 15, lg = lane >> 4;
  int sr = t >> 3, sc = (t & 7)*8;
  const u16* Ar0 = Ab + (size_t)(row0 + sr)*256 + sc;
  const u16* Ar1 = Ab + (size_t)(row0 + 32 + sr)*256 + sc;
  const u16* Br0 = Bb + (size_t)(col0 + sr)*256 + sc;
  const u16* Br1 = Bb + (size_t)(col0 + 32 + sr)*256 + sc;
  uint4 pa0 = *(const uint4*)Ar0, pa1 = *(const uint4*)Ar1;
  uint4 pb0 = *(const uint4*)Br0, pb1 = *(const uint4*)Br1;
  for (int k0 = 0; k0 < 256; k0 += 64) {
    __syncthreads();
    *(uint4*)&As[sr*72 + sc]        = pa0;
    *(uint4*)&As[(sr + 32)*72 + sc] = pa1;
    *(uint4*)&Bs[sr*72 + sc]        = pb0;
    *(uint4*)&Bs[(sr + 32)*72 + sc] = pb1;
    __syncthreads();
    if (k0 + 64 < 256) {
      pa0 = *(const uint4*)(Ar0 + k0 + 64);
      pa1 = *(const uint4*)(Ar1 + k0 + 64);
      pb0 = *(const uint4*)(Br0 + k0 + 64);
      pb1 = *(const uint4*)(Br1 + k0 + 64);
    }
    #pragma unroll
    for (int kk = 0; kk < 2; kk++) {
      s16x8 af[2], bf[2];
      #pragma unroll
      for (int f = 0; f < 2; f++) {
        af[f] = *(s16x8*)&As[(wr + f*16 + lr)*72 + kk*32 + lg*8];
        bf[f] = *(s16x8*)&Bs[(wc + f*16 + lr)*72 + kk*32 + lg*8];
      }
      #pragma unroll
      for (int i = 0; i < 2; i++)
        #pragma unroll
        for (int j = 0; j < 2; j++)
          acc[i][j] = MFMA16(af[i], bf[j], acc[i][j]);
    }
  }
}

// ---------------- QKV (XCD-swizzled) ----------------
__global__ __launch_bounds__(256, 4) void qkv_mfma(const u16* __restrict__ xn, const u16* __restrict__ wT,
    u16* __restrict__ q, u16* __restrict__ k, u16* __restrict__ v) {
  __shared__ u16 As[128*40], Bs[128*40];
  f32x4 acc[4][4];
  #pragma unroll
  for (int i = 0; i < 4; i++)
    #pragma unroll
    for (int j = 0; j < 4; j++) acc[i][j] = (f32x4)0.f;
  int bI = blockIdx.x;
  int job = (bI & 7)*192 + (bI >> 3);
  int row0 = (job / 12) * 128, col0 = (job % 12) * 128;
  gemm128_pf(xn, wT, 512, 512, 512, row0, col0, As, Bs, acc);
  int t = threadIdx.x, lane = t & 63, wid = t >> 6, lr = lane & 15, lg = lane >> 4;
  int wr = (wid >> 1)*64, wc = (wid & 1)*64;
  #pragma unroll
  for (int i = 0; i < 4; i++)
    #pragma unroll
    for (int j = 0; j < 4; j++)
      #pragma unroll
      for (int r = 0; r < 4; r++) {
        int row = row0 + wr + i*16 + lg*4 + r;
        int col = col0 + wc + j*16 + lr;
        float val = acc[i][j][r];
        int part = col >> 9, rem = col & 511, h = rem >> 6, d = rem & 63;
        int b = row >> 12, n = row & 4095;
        size_t bh = (size_t)(b*8 + h);
        size_t dst = (bh*4096 + n)*64 + d;
        if (part == 0)      q[dst] = f2b(val * 0.125f);
        else if (part == 1) k[dst] = f2b(val);
        else                v[dst] = f2b(val);
      }
}

// ---------------- out GEMM (XCD-swizzled) ----------------
__global__ __launch_bounds__(256, 4) void out_mfma(const u16* __restrict__ outh, const u16* __restrict__ wT,
    const float* __restrict__ bo, const float* __restrict__ x, float* __restrict__ out) {
  __shared__ u16 As[128*40], Bs[128*40];
  f32x4 acc[4][4];
  #pragma unroll
  for (int i = 0; i < 4; i++)
    #pragma unroll
    for (int j = 0; j < 4; j++) acc[i][j] = (f32x4)0.f;
  int bI = blockIdx.x;
  int job = (bI & 7)*64 + (bI >> 3);
  int row0 = (job / 4) * 128, col0 = (job % 4) * 128;
  gemm128_pf(outh, wT, 512, 512, 512, row0, col0, As, Bs, acc);
  int t = threadIdx.x, lane = t & 63, wid = t >> 6, lr = lane & 15, lg = lane >> 4;
  int wr = (wid >> 1)*64, wc = (wid & 1)*64;
  #pragma unroll
  for (int i = 0; i < 4; i++)
    #pragma unroll
    for (int j = 0; j < 4; j++)
      #pragma unroll
      for (int r = 0; r < 4; r++) {
        int row = row0 + wr + i*16 + lg*4 + r;
        int col = col0 + wc + j*16 + lr;
        size_t idx = (size_t)row*512 + col;
        out[idx] = x[idx] + acc[i][j][r] + bo[col];
      }
}

// ---------------- pinv stage 1: P = a2 @ z ; write P, P^T, (7I-P)^T ----------------
__global__ __launch_bounds__(256) void pinv_s1(const u16* __restrict__ a2h, const u16* __restrict__ zcT,
    u16* __restrict__ xz, u16* __restrict__ xzT, u16* __restrict__ e1T) {
  __shared__ u16 As[64*72], Bs[64*72];
  size_t bb = (size_t)blockIdx.z << 16;
  f32x4 acc[2][2];
  #pragma unroll
  for (int i = 0; i < 2; i++) { acc[i][0] = (f32x4)0.f; acc[i][1] = (f32x4)0.f; }
  int row0 = blockIdx.y*64, col0 = blockIdx.x*64;
  gemm64_pf(a2h + bb, zcT + bb, row0, col0, As, Bs, acc);
  int t = threadIdx.x, lane = t & 63, wid = t >> 6, lr = lane & 15, lg = lane >> 4;
  int wr = (wid >> 1)*32, wc = (wid & 1)*32;
  #pragma unroll
  for (int i = 0; i < 2; i++)
    #pragma unroll
    for (int j = 0; j < 2; j++)
      #pragma unroll
      for (int r = 0; r < 4; r++) {
        int row = row0 + wr + i*16 + lg*4 + r;
        int col = col0 + wc + j*16 + lr;
        float c = acc[i][j][r];
        xz [bb + (size_t)row*256 + col] = f2b(c);
        xzT[bb + (size_t)col*256 + row] = f2b(c);
        e1T[bb + (size_t)col*256 + row] = f2b((row == col ? 7.f : 0.f) - c);
      }
}

// ---------------- pinv stage 2: z 0-31: e2T=(15I - P@e1)^T ; 32-63: W = z@P ----------------
__global__ __launch_bounds__(256) void pinv_s2(const u16* __restrict__ xz, const u16* __restrict__ e1T,
    const u16* __restrict__ zc, const u16* __restrict__ xzT,
    u16* __restrict__ e2T, u16* __restrict__ W) {
  __shared__ u16 As[64*72], Bs[64*72];
  int bz = blockIdx.z;
  bool isQ = bz < 32;
  size_t bb = (size_t)(isQ ? bz : bz - 32) << 16;
  const u16* Aptr = (isQ ? xz : zc) + bb;
  const u16* Bptr = (isQ ? e1T : xzT) + bb;
  f32x4 acc[2][2];
  #pragma unroll
  for (int i = 0; i < 2; i++) { acc[i][0] = (f32x4)0.f; acc[i][1] = (f32x4)0.f; }
  int row0 = blockIdx.y*64, col0 = blockIdx.x*64;
  gemm64_pf(Aptr, Bptr, row0, col0, As, Bs, acc);
  int t = threadIdx.x, lane = t & 63, wid = t >> 6, lr = lane & 15, lg = lane >> 4;
  int wr = (wid >> 1)*32, wc = (wid & 1)*32;
  #pragma unroll
  for (int i = 0; i < 2; i++)
    #pragma unroll
    for (int j = 0; j < 2; j++)
      #pragma unroll
      for (int r = 0; r < 4; r++) {
        int row = row0 + wr + i*16 + lg*4 + r;
        int col = col0 + wc + j*16 + lr;
        float c = acc[i][j][r];
        if (isQ) e2T[bb + (size_t)col*256 + row] = f2b((row == col ? 15.f : 0.f) - c);
        else     W  [bb + (size_t)row*256 + col] = f2b(c);
      }
}

// ---------------- pinv stage 3: zn = 3.25 z - 0.25 W@e2 ; write zn, zn^T ----------------
__global__ __launch_bounds__(256) void pinv_s3(const u16* __restrict__ W, const u16* __restrict__ e2T,
    const u16* __restrict__ zc, u16* __restrict__ zn, u16* __restrict__ znT) {
  __shared__ u16 As[64*72], Bs[64*72];
  size_t bb = (size_t)blockIdx.z << 16;
  f32x4 acc[2][2];
  #pragma unroll
  for (int i = 0; i < 2; i++) { acc[i][0] = (f32x4)0.f; acc[i][1] = (f32x4)0.f; }
  int row0 = blockIdx.y*64, col0 = blockIdx.x*64;
  gemm64_pf(W + bb, e2T + bb, row0, col0, As, Bs, acc);
  int t = threadIdx.x, lane = t & 63, wid = t >> 6, lr = lane & 15, lg = lane >> 4;
  int wr = (wid >> 1)*32, wc = (wid & 1)*32;
  #pragma unroll
  for (int i = 0; i < 2; i++)
    #pragma unroll
    for (int j = 0; j < 2; j++)
      #pragma unroll
      for (int r = 0; r < 4; r++) {
        int row = row0 + wr + i*16 + lg*4 + r;
        int col = col0 + wc + j*16 + lr;
        size_t idx = bb + (size_t)row*256 + col;
        float val = 3.25f*b2f(zc[idx]) - 0.25f*acc[i][j][r];
        zn [idx] = f2b(val);
        znT[bb + (size_t)col*256 + row] = f2b(val);
      }
}

// ---------------- batched 64x64-tile MFMA GEMM (final w2T), BK=32 prefetch ----------------
__global__ __launch_bounds__(256) void bmm64(const u16* __restrict__ A, const u16* __restrict__ BT,
    u16* __restrict__ CT, int M, int N, int K) {
  __shared__ u16 As[64*40], Bs[64*40];
  int batch = blockIdx.z;
  const u16* Ab = A  + (size_t)batch*M*K;
  const u16* Bb = BT + (size_t)batch*N*K;
  int row0 = blockIdx.y*64, col0 = blockIdx.x*64;
  int t = threadIdx.x, lane = t & 63, wid = t >> 6, lr = lane & 15, lg = lane >> 4;
  int wr = (wid >> 1)*32, wc = (wid & 1)*32;
  int sr = t >> 2, sc = (t & 3)*8;
  const u16* Arow = Ab + (size_t)(row0 + sr)*K + sc;
  const u16* Brow = Bb + (size_t)(col0 + sr)*K + sc;
  uint4 pa = *(const uint4*)Arow;
  uint4 pb = *(const uint4*)Brow;
  f32x4 acc[2][2];
  #pragma unroll
  for (int i = 0; i < 2; i++)
    #pragma unroll
    for (int j = 0; j < 2; j++) acc[i][j] = (f32x4)0.f;
  for (int k0 = 0; k0 < K; k0 += 32) {
    __syncthreads();
    *(uint4*)&As[sr*40 + sc] = pa;
    *(uint4*)&Bs[sr*40 + sc] = pb;
    __syncthreads();
    if (k0 + 32 < K) {
      pa = *(const uint4*)(Arow + k0 + 32);
      pb = *(const uint4*)(Brow + k0 + 32);
    }
    s16x8 af[2], bf[2];
    #pragma unroll
    for (int f = 0; f < 2; f++) {
      af[f] = *(s16x8*)&As[(wr + f*16 + lr)*40 + lg*8];
      bf[f] = *(s16x8*)&Bs[(wc + f*16 + lr)*40 + lg*8];
    }
    #pragma unroll
    for (int i = 0; i < 2; i++)
      #pragma unroll
      for (int j = 0; j < 2; j++)
        acc[i][j] = MFMA16(af[i], bf[j], acc[i][j]);
  }
  size_t cb = (size_t)batch*M*N;
  #pragma unroll
  for (int i = 0; i < 2; i++)
    #pragma unroll
    for (int j = 0; j < 2; j++)
      #pragma unroll
      for (int r = 0; r < 4; r++) {
        int row = row0 + wr + i*16 + lg*4 + r;
        int col = col0 + wc + j*16 + lr;
        CT[cb + (size_t)col*M + row] = f2b(acc[i][j][r]);
      }
}

// ---------------- landmarks ----------------
__global__ void landmark_kernel(const u16* __restrict__ q, const u16* __restrict__ k,
                                u16* __restrict__ ql, u16* __restrict__ kl) {
  int idx = blockIdx.x;
  int d = threadIdx.x;
  size_t base = ((size_t)idx * 16) * 64 + d;
  float sq = 0.f, sk = 0.f;
  #pragma unroll
  for (int j = 0; j < 16; j++) { sq += b2f(q[base + (size_t)j*64]); sk += b2f(k[base + (size_t)j*64]); }
  ql[(size_t)idx*64 + d] = f2b(sq * (1.f/16.f));
  kl[(size_t)idx*64 + d] = f2b(sk * (1.f/16.f));
}

// ---------------- sim2 (split): rows rq*64..+64 of one bh; partial colsums to pcs ----------------
__global__ __launch_bounds__(256, 4) void sim2_mfma(const u16* __restrict__ ql, const u16* __restrict__ kl,
    float* __restrict__ a2, u16* __restrict__ a2h, float* __restrict__ pcs) {
  __shared__ u16 Qs[64*72];
  __shared__ u16 Ks2[256*72];
  __shared__ float wcol[4*256];
  int rq = blockIdx.x, bh = blockIdx.y;
  int t = threadIdx.x, lane = t & 63, wid = t >> 6, lr = lane & 15, lg = lane >> 4;
  #pragma unroll
  for (int p = 0; p < 2; p++) {
    int c = t + p*256;
    int r = c >> 3, col = (c & 7)*8;
    *(uint4*)&Qs[r*72 + col] = *(const uint4*)&ql[((size_t)bh*256 + rq*64 + r)*64 + col];
  }
  #pragma unroll
  for (int p = 0; p < 8; p++) {
    int c = t + p*256;
    int r = c >> 3, col = (c & 7)*8;
    *(uint4*)&Ks2[r*72 + col] = *(const uint4*)&kl[((size_t)bh*256 + r)*64 + col];
  }
  __syncthreads();
  float colp[16];
  #pragma unroll
  for (int cf = 0; cf < 16; cf++) colp[cf] = 0.f;
  int rbase = wid*16;
  s16x8 a0 = *(s16x8*)&Qs[(rbase + lr)*72 + lg*8];
  s16x8 a1 = *(s16x8*)&Qs[(rbase + lr)*72 + 32 + lg*8];
  f32x4 sf[16];
  #pragma unroll
  for (int cf = 0; cf < 16; cf++) {
    s16x8 b0 = *(s16x8*)&Ks2[(cf*16 + lr)*72 + lg*8];
    s16x8 b1 = *(s16x8*)&Ks2[(cf*16 + lr)*72 + 32 + lg*8];
    sf[cf] = MFMA16(a1, b1, MFMA16(a0, b0, (f32x4)0.f));
  }
  #pragma unroll
  for (int r = 0; r < 4; r++) {
    float mx = -3e38f;
    #pragma unroll
    for (int cf = 0; cf < 16; cf++) mx = fmaxf(mx, sf[cf][r]);
    #pragma unroll
    for (int o = 1; o < 16; o <<= 1) mx = fmaxf(mx, __shfl_xor(mx, o));
    float sum = 0.f;
    #pragma unroll
    for (int cf = 0; cf < 16; cf++) { sf[cf][r] = __expf(sf[cf][r] - mx); sum += sf[cf][r]; }
    #pragma unroll
    for (int o = 1; o < 16; o <<= 1) sum += __shfl_xor(sum, o);
    float inv = 1.f / sum;
    int row = rq*64 + rbase + lg*4 + r;
    size_t base = (size_t)bh*65536 + (size_t)row*256;
    #pragma unroll
    for (int cf = 0; cf < 16; cf++) {
      float pp = sf[cf][r] * inv;
      a2[base + cf*16 + lr] = pp;
      a2h[base + cf*16 + lr] = f2b(pp);
      colp[cf] += pp;
    }
  }
  #pragma unroll
  for (int cf = 0; cf < 16; cf++) {
    colp[cf] += __shfl_xor(colp[cf], 16);
    colp[cf] += __shfl_xor(colp[cf], 32);
  }
  if (lg == 0) {
    #pragma unroll
    for (int cf = 0; cf < 16; cf++) wcol[wid*256 + cf*16 + lr] = colp[cf];
  }
  __syncthreads();
  pcs[((size_t)bh*4 + rq)*256 + t] = wcol[t] + wcol[256 + t] + wcol[512 + t] + wcol[768 + t];
}

// ---------------- colmax: max over column sums ----------------
__global__ __launch_bounds__(256) void colmax_kernel(const float* __restrict__ pcs, unsigned* __restrict__ scal) {
  __shared__ float red[256];
  int bh = blockIdx.x, t = threadIdx.x;
  size_t b4 = (size_t)bh*4*256;
  red[t] = pcs[b4 + t] + pcs[b4 + 256 + t] + pcs[b4 + 512 + t] + pcs[b4 + 768 + t];
  __syncthreads();
  for (int o = 128; o > 0; o >>= 1) {
    if (t < o) red[t] = fmaxf(red[t], red[t+o]);
    __syncthreads();
  }
  if (t == 0) atomicMax(scal + 1, __float_as_uint(red[0]));
}

// ---------------- z0 = a2^T / colmax ----------------
__global__ void z0_kernel(const float* __restrict__ a2, const unsigned* __restrict__ scal,
                          u16* __restrict__ zA, u16* __restrict__ zAT) {
  size_t idx = (size_t)blockIdx.x*256 + threadIdx.x;
  float inv = 1.f / __uint_as_float(scal[1]);
  size_t bh = idx >> 16; int rem = (int)(idx & 65535); int i = rem >> 8, j = rem & 255;
  zA[idx]  = f2b(a2[(bh<<16) + ((size_t)j<<8) + i] * inv);
  zAT[idx] = f2b(a2[idx] * inv);
}

// ---------------- split-K flash partials: 2 q-tiles per block, 8 chunks of 512 keys ----------------
// po layout: packed uint2, stored col s = lr*4 + df  (original col c = df*16 + lr)
__global__ __launch_bounds__(256) void flash_part(const u16* __restrict__ Q, const u16* __restrict__ Kg,
    const u16* __restrict__ VT, u16* __restrict__ po, float* __restrict__ pm, float* __restrict__ pl) {
  __shared__ u16 Ks[64*72];
  __shared__ u16 Vs[64*72];
  __shared__ u16 Ps[4*16*72];
  int qg = blockIdx.x, ch = blockIdx.y, bh = blockIdx.z;
  int t = threadIdx.x, lane = t & 63, wid = t >> 6, lr = lane & 15, lg = lane >> 4;
  const u16* Qb  = Q  + ((size_t)bh*256)*64;
  const u16* Kb  = Kg + ((size_t)bh*4096 + ch*512)*64;
  const u16* VTb = VT + ((size_t)bh*64)*4096 + ch*512;
  s16x8 aq[2][2];
  #pragma unroll
  for (int qq = 0; qq < 2; qq++) {
    int qrow = (qg*2 + qq)*64 + wid*16 + lr;
    aq[qq][0] = *(const s16x8*)&Qb[(size_t)qrow*64 + lg*8];
    aq[qq][1] = *(const s16x8*)&Qb[(size_t)qrow*64 + 32 + lg*8];
  }
  f32x4 oacc[2][4];
  float m_[2][4], l_[2][4];
  #pragma unroll
  for (int qq = 0; qq < 2; qq++)
    #pragma unroll
    for (int f = 0; f < 4; f++) {
      oacc[qq][f] = (f32x4)0.f;
      m_[qq][f] = -3e38f;
      l_[qq][f] = 0.f;
    }
  u16* Pw = Ps + wid*16*72;
  uint4 pk[2], pv[2];
  #pragma unroll
  for (int p = 0; p < 2; p++) {
    int c = t + p*256; int r = c >> 3, cc = (c & 7)*8;
    pk[p] = *(const uint4*)&Kb[(size_t)r*64 + cc];
    pv[p] = *(const uint4*)&VTb[(size_t)r*4096 + cc];
  }
  for (int k0 = 0; k0 < 512; k0 += 64) {
    __syncthreads();
    #pragma unroll
    for (int p = 0; p < 2; p++) {
      int c = t + p*256; int r = c >> 3, cc = (c & 7)*8;
      *(uint4*)&Ks[r*72 + cc] = pk[p];
      *(uint4*)&Vs[r*72 + cc] = pv[p];
    }
    __syncthreads();
    if (k0 + 64 < 512) {
      #pragma unroll
      for (int p = 0; p < 2; p++) {
        int c = t + p*256; int r = c >> 3, cc = (c & 7)*8;
        pk[p] = *(const uint4*)&Kb[(size_t)(k0 + 64 + r)*64 + cc];
        pv[p] = *(const uint4*)&VTb[(size_t)r*4096 + k0 + 64 + cc];
      }
    }
    #pragma unroll
    for (int qq = 0; qq < 2; qq++) {
      f32x4 sf[4];
      #pragma unroll
      for (int f = 0; f < 4; f++) {
        s16x8 b0 = *(s16x8*)&Ks[(f*16 + lr)*72 + lg*8];
        s16x8 b1 = *(s16x8*)&Ks[(f*16 + lr)*72 + 32 + lg*8];
        f32x4 s = (f32x4)0.f;
        s = MFMA16(aq[qq][0], b0, s);
        s = MFMA16(aq[qq][1], b1, s);
        sf[f] = s;
      }
      #pragma unroll
      for (int r = 0; r < 4; r++) {
        float mx = fmaxf(fmaxf(sf[0][r], sf[1][r]), fmaxf(sf[2][r], sf[3][r]));
        #pragma unroll
        for (int o = 1; o < 16; o <<= 1) mx = fmaxf(mx, __shfl_xor(mx, o));
        float mn = fmaxf(m_[qq][r], mx);
        float sum = 0.f;
        #pragma unroll
        for (int f = 0; f < 4; f++) {
          float pv2 = __expf(sf[f][r] - mn);
          sum += pv2;
          Pw[(lg*4 + r)*72 + f*16 + lr] = f2b(pv2);
        }
        #pragma unroll
        for (int o = 1; o < 16; o <<= 1) sum += __shfl_xor(sum, o);
        float sc = __expf(m_[qq][r] - mn);
        l_[qq][r] = l_[qq][r]*sc + sum;
        m_[qq][r] = mn;
        #pragma unroll
        for (int f = 0; f < 4; f++) oacc[qq][f][r] *= sc;
      }
      #pragma unroll
      for (int ks = 0; ks < 2; ks++) {
        s16x8 ap = *(s16x8*)&Pw[lr*72 + ks*32 + lg*8];
        #pragma unroll
        for (int df = 0; df < 4; df++) {
          s16x8 bv = *(s16x8*)&Vs[(df*16 + lr)*72 + ks*32 + lg*8];
          oacc[qq][df] = MFMA16(ap, bv, oacc[qq][df]);
        }
      }
    }
  }
  #pragma unroll
  for (int qq = 0; qq < 2; qq++) {
    int pidx = (bh*4 + qg*2 + qq)*8 + ch;
    #pragma unroll
    for (int r = 0; r < 4; r++) {
      int lrow = wid*16 + lg*4 + r;
      if (lr == 0) { pm[pidx*64 + lrow] = m_[qq][r]; pl[pidx*64 + lrow] = l_[qq][r]; }
      uint2 pw2;
      pw2.x = (unsigned)f2b(oacc[qq][0][r]) | ((unsigned)f2b(oacc[qq][1][r]) << 16);
      pw2.y = (unsigned)f2b(oacc[qq][2][r]) | ((unsigned)f2b(oacc[qq][3][r]) << 16);
      *(uint2*)&po[((size_t)pidx*64 + lrow)*64 + lr*4] = pw2;
    }
  }
}

// ---------------- merge 8 partials (permuted bf16 po, LDS transpose, coalesced out) ----------------
__global__ __launch_bounds__(256) void flash_merge(const u16* __restrict__ po, const float* __restrict__ pm,
    const float* __restrict__ pl, u16* __restrict__ a3vT) {
  __shared__ u16 tile[64*72];
  int qt = blockIdx.x, bh = blockIdx.y;
  int t = threadIdx.x;
  int lrow = t & 63, dg = t >> 6;   // dg in [0,4): stored cols [dg*16, dg*16+16)
  int pbase = (bh*4 + qt)*8;
  float m = -3e38f;
  #pragma unroll
  for (int ch = 0; ch < 8; ch++) m = fmaxf(m, pm[(pbase+ch)*64 + lrow]);
  float w[8];
  float L = 0.f;
  #pragma unroll
  for (int ch = 0; ch < 8; ch++) {
    w[ch] = __expf(pm[(pbase+ch)*64 + lrow] - m);
    L += w[ch] * pl[(pbase+ch)*64 + lrow];
  }
  float Oacc[16];
  #pragma unroll
  for (int ss = 0; ss < 16; ss++) Oacc[ss] = 0.f;
  #pragma unroll
  for (int ch = 0; ch < 8; ch++) {
    const u16* pr = &po[(((size_t)(pbase+ch)*64 + lrow)*64) + dg*16];
    uint4 v0 = *(const uint4*)pr;
    uint4 v1 = *(const uint4*)(pr + 8);
    float wc = w[ch];
    unsigned arr[8] = {v0.x, v0.y, v0.z, v0.w, v1.x, v1.y, v1.z, v1.w};
    #pragma unroll
    for (int jj = 0; jj < 8; jj++) {
      Oacc[jj*2]   += wc * b2f((u16)(arr[jj] & 0xffff));
      Oacc[jj*2+1] += wc * b2f((u16)(arr[jj] >> 16));
    }
  }
  float Linv = 1.f / L;
  #pragma unroll
  for (int ss = 0; ss < 16; ss++) {
    int s = dg*16 + ss;
    int c = ((s & 3) << 4) | (s >> 2);   // original column (the d index)
    tile[c*72 + lrow] = f2b(Oacc[ss] * Linv);
  }
  __syncthreads();
  #pragma unroll
  for (int p = 0; p < 2; p++) {
    int idx = t + p*256;
    int d = idx >> 3, seg = idx & 7;
    u16 tmp[8];
    #pragma unroll
    for (int j = 0; j < 8; j++) tmp[j] = tile[d*72 + seg*8 + j];
    *(uint4*)&a3vT[((size_t)bh*64 + d)*256 + qt*64 + seg*8] = *(uint4*)tmp;
  }
}

// ---------------- exact-softmax flash: outh = softmax(q @ kl^T) @ w2 ----------------
__global__ __launch_bounds__(256, 4) void flash_a1(const u16* __restrict__ Q, const u16* __restrict__ Kl,
    const u16* __restrict__ W2T, u16* __restrict__ outh) {
  __shared__ u16 Ks[64*72];
  __shared__ u16 Vs[64*264];
  __shared__ u16 Ps[4*16*264];
  int bh = blockIdx.y;
  int q0 = blockIdx.x * 64;
  int t = threadIdx.x, lane = t & 63, wid = t >> 6, lr = lane & 15, lg = lane >> 4;
  const u16* Qb = Q + ((size_t)bh*4096)*64;
  #pragma unroll
  for (int p = 0; p < 8; p++) {
    int c = t + p*256; int r = c >> 5, col = (c & 31)*8;
    *(uint4*)&Vs[r*264 + col] = *(const uint4*)&W2T[((size_t)bh*64 + r)*256 + col];
  }
  int qrow = q0 + wid*16 + lr;
  s16x8 aq0 = *(const s16x8*)&Qb[(size_t)qrow*64 + lg*8];
  s16x8 aq1 = *(const s16x8*)&Qb[(size_t)qrow*64 + 32 + lg*8];
  f32x4 sf[16];
  #pragma unroll
  for (int f = 0; f < 16; f++) sf[f] = (f32x4)0.f;
  #pragma unroll
  for (int kt = 0; kt < 4; kt++) {
    __syncthreads();
    #pragma unroll
    for (int p = 0; p < 2; p++) {
      int c = t + p*256; int r = c >> 3, cc = (c & 7)*8;
      *(uint4*)&Ks[r*72 + cc] = *(const uint4*)&Kl[((size_t)bh*256 + kt*64 + r)*64 + cc];
    }
    __syncthreads();
    #pragma unroll
    for (int f2 = 0; f2 < 4; f2++) {
      s16x8 b0 = *(s16x8*)&Ks[(f2*16 + lr)*72 + lg*8];
      s16x8 b1 = *(s16x8*)&Ks[(f2*16 + lr)*72 + 32 + lg*8];
      sf[kt*4 + f2] = MFMA16(aq1, b1, MFMA16(aq0, b0, sf[kt*4 + f2]));
    }
  }
  u16* Pw = Ps + wid*16*264;
  float linv[4];
  #pragma unroll
  for (int r = 0; r < 4; r++) {
    float mx = -3e38f;
    #pragma unroll
    for (int f = 0; f < 16; f++) mx = fmaxf(mx, sf[f][r]);
    #pragma unroll
    for (int o = 1; o < 16; o <<= 1) mx = fmaxf(mx, __shfl_xor(mx, o));
    float sum = 0.f;
    #pragma unroll
    for (int f = 0; f < 16; f++) {
      float pv = __expf(sf[f][r] - mx);
      sum += pv;
      Pw[(lg*4 + r)*264 + f*16 + lr] = f2b(pv);
    }
    #pragma unroll
    for (int o = 1; o < 16; o <<= 1) sum += __shfl_xor(sum, o);
    linv[r] = 1.f / sum;
  }
  f32x4 oacc[4];
  #pragma unroll
  for (int f = 0; f < 4; f++) oacc[f] = (f32x4)0.f;
  #pragma unroll
  for (int ks = 0; ks < 8; ks++) {
    s16x8 ap = *(s16x8*)&Pw[lr*264 + ks*32 + lg*8];
    #pragma unroll
    for (int df = 0; df < 4; df++) {
      s16x8 bv = *(s16x8*)&Vs[(df*16 + lr)*264 + ks*32 + lg*8];
      oacc[df] = MFMA16(ap, bv, oacc[df]);
    }
  }
  int b = bh >> 3, h = bh & 7;
  #pragma unroll
  for (int df = 0; df < 4; df++)
    #pragma unroll
    for (int r = 0; r < 4; r++) {
      int lrow = wid*16 + lg*4 + r;
      int col = df*16 + lr;
      outh[((size_t)(b*4096 + q0 + lrow))*512 + h*64 + col] = f2b(oacc[df][r] * linv[r]);
    }
}

// ---------------- LDS-tiled residual depthwise conv ----------------
__global__ __launch_bounds__(256) void conv_lds(const u16* __restrict__ v, const float* __restrict__ rw,
                                                u16* __restrict__ outh) {
  __shared__ u16 tile[160*72];
  __shared__ float wsm[33];
  int bh = blockIdx.y;
  int n0 = blockIdx.x * 128;
  int b = bh >> 3, h = bh & 7;
  int t = threadIdx.x;
  if (t < 33) wsm[t] = rw[h*33 + t];
  const u16* vb = v + ((size_t)bh*4096)*64;
  #pragma unroll
  for (int p = 0; p < 5; p++) {
    int c = t + p*256;
    int r = c >> 3, col = (c & 7)*8;
    int nn = n0 - 16 + r;
    uint4 val = make_uint4(0u,0u,0u,0u);
    if (nn >= 0 && nn < 4096) val = *(const uint4*)&vb[(size_t)nn*64 + col];
    *(uint4*)&tile[r*72 + col] = val;
  }
  __syncthreads();
  int d8 = (t & 7) * 8;
  int r0 = t >> 3;
  #pragma unroll
  for (int pass = 0; pass < 4; pass++) {
    int lrow = pass*32 + r0;
    float acc[8] = {};
    #pragma unroll
    for (int j = 0; j < 33; j++) {
      uint4 vv = *(uint4*)&tile[(lrow + j)*72 + d8];
      float w = wsm[j];
      acc[0] += b2f((u16)(vv.x & 0xffff)) * w;
      acc[1] += b2f((u16)(vv.x >> 16))    * w;
      acc[2] += b2f((u16)(vv.y & 0xffff)) * w;
      acc[3] += b2f((u16)(vv.y >> 16))    * w;
      acc[4] += b2f((u16)(vv.z & 0xffff)) * w;
      acc[5] += b2f((u16)(vv.z >> 16))    * w;
      acc[6] += b2f((u16)(vv.w & 0xffff)) * w;
      acc[7] += b2f((u16)(vv.w >> 16))    * w;
    }
    size_t oi = ((size_t)(b*4096 + n0 + lrow))*512 + h*64 + d8;
    uint4 ov = *(uint4*)&outh[oi];
    uint4 nv;
    nv.x = (unsigned)f2b(b2f((u16)(ov.x & 0xffff)) + acc[0]) | ((unsigned)f2b(b2f((u16)(ov.x >> 16)) + acc[1]) << 16);
    nv.y = (unsigned)f2b(b2f((u16)(ov.y & 0xffff)) + acc[2]) | ((unsigned)f2b(b2f((u16)(ov.y >> 16)) + acc[3]) << 16);
    nv.z = (unsigned)f2b(b2f((u16)(ov.z & 0xffff)) + acc[4]) | ((unsigned)f2b(b2f((u16)(ov.z >> 16)) + acc[5]) << 16);
    nv.w = (unsigned)f2b(b2f((u16)(ov.w & 0xffff)) + acc[6]) | ((unsigned)f2b(b2f((u16)(ov.w >> 16)) + acc[7]) << 16);
    *(uint4*)&outh[oi] = nv;
  }
}

extern "C" void kernel_launch(void* const* d_in, const int* in_sizes, int n_in,
                              void* d_out, int out_size, void* d_ws, size_t ws_size,
                              hipStream_t stream) {
  const float* x      = (const float*)d_in[0];
  const float* norm_w = (const float*)d_in[1];
  const float* norm_b = (const float*)d_in[2];
  const float* w_qkv  = (const float*)d_in[3];
  const float* w_out  = (const float*)d_in[4];
  const float* b_out  = (const float*)d_in[5];
  const float* res_w  = (const float*)d_in[6];
  float* out = (float*)d_out;
  char* ws = (char*)d_ws;

  size_t off = 0;
  u16* xn    = (u16*)(ws + off); off += 16777216;
  u16* q     = (u16*)(ws + off); off += 16777216;
  u16* k     = (u16*)(ws + off); off += 16777216;
  u16* v     = (u16*)(ws + off); off += 16777216;
  u16* vT    = (u16*)(ws + off); off += 16777216;
  u16* ql    = (u16*)(ws + off); off += 1048576;
  u16* kl    = (u16*)(ws + off); off += 1048576;
  float* a2  = (float*)(ws + off); off += 8388608;
  u16* a2h   = (u16*)(ws + off); off += 4194304;
  u16* zA    = (u16*)(ws + off); off += 4194304;
  u16* zAT   = (u16*)(ws + off); off += 4194304;
  u16* zB    = (u16*)(ws + off); off += 4194304;
  u16* zBT   = (u16*)(ws + off); off += 4194304;
  u16* xz    = (u16*)(ws + off); off += 4194304;
  u16* xzT   = (u16*)(ws + off); off += 4194304;
  u16* e1T   = (u16*)(ws + off); off += 4194304;
  u16* e2T   = (u16*)(ws + off); off += 4194304;
  u16* Wm    = (u16*)(ws + off); off += 4194304;
  u16* a3vT  = (u16*)(ws + off); off += 1048576;
  u16* w2T   = (u16*)(ws + off); off += 1048576;
  u16* wqkvT = (u16*)(ws + off); off += 1572864;
  u16* woutT = (u16*)(ws + off); off += 524288;
  u16* outh  = (u16*)(ws + off); off += 16777216;
  u16* po    = (u16*)(ws + off); off += 8388608;    // 1024 pidx x 64 x 64 bf16 (permuted cols)
  float* pm  = (float*)(ws + off); off += 262144;
  float* pl  = (float*)(ws + off); off += 262144;
  float* pcs = (float*)(ws + off); off += 131072;
  unsigned* scal = (unsigned*)(ws + off); off += 8;

  ln_kernel<<<16384, 256, 0, stream>>>(x, norm_w, norm_b, xn);
  wcast_T<<<3072, 256, 0, stream>>>(w_qkv, wqkvT, 512, 1536);
  wcast_T<<<1024, 256, 0, stream>>>(w_out, woutT, 512, 512);
  qkv_mfma<<<1536, 256, 0, stream>>>(xn, wqkvT, q, k, v);
  vtrans<<<dim3(64, 32), 256, 0, stream>>>(v, vT);
  landmark_kernel<<<8192, 64, 0, stream>>>(q, k, ql, kl);
  hipMemsetAsync(scal, 0, 8, stream);
  sim2_mfma<<<dim3(4, 32), 256, 0, stream>>>(ql, kl, a2, a2h, pcs);
  colmax_kernel<<<32, 256, 0, stream>>>(pcs, scal);
  flash_part<<<dim3(2, 8, 32), 256, 0, stream>>>(ql, k, vT, po, pm, pl);
  flash_merge<<<dim3(4, 32), 256, 0, stream>>>(po, pm, pl, a3vT);
  z0_kernel<<<8192, 256, 0, stream>>>(a2, scal, zA, zAT);

  u16 *zc = zA, *zcT = zAT, *zn = zB, *znT = zBT;
  for (int it = 0; it < 6; it++) {
    pinv_s1<<<dim3(4,4,32), 256, 0, stream>>>(a2h, zcT, xz, xzT, e1T);
    pinv_s2<<<dim3(4,4,64), 256, 0, stream>>>(xz, e1T, zc, xzT, e2T, Wm);
    pinv_s3<<<dim3(4,4,32), 256, 0, stream>>>(Wm, e2T, zc, zn, znT);
    u16* tp;
    tp = zc; zc = zn; zn = tp;
    tp = zcT; zcT = znT; znT = tp;
  }

  bmm64<<<dim3(1,4,32), 256, 0, stream>>>(zc, a3vT, w2T, 256, 64, 256);
  flash_a1<<<dim3(64, 32), 256, 0, stream>>>(q, kl, w2T, outh);
  conv_lds<<<dim3(32, 32), 256, 0, stream>>>(v, res_w, outh);
  out_mfma<<<512, 256, 0, stream>>>(outh, woutT, b_out, x, out);
}